// Round 6
// baseline (210.923 us; speedup 1.0000x reference)
//
#include <hip/hip_runtime.h>
#include <math.h>

#define BNS 0.99999500003749981f  // 1/sqrt(1+1e-5)

typedef short          bf16x8  __attribute__((ext_vector_type(8)));
typedef float          f32x4   __attribute__((ext_vector_type(4)));
typedef unsigned short u16x8   __attribute__((ext_vector_type(8)));
typedef unsigned short u16x4   __attribute__((ext_vector_type(4)));
typedef unsigned short ushort_t;

__device__ inline ushort_t f2b(float f) {
    union { float f; unsigned int u; } x; x.f = f;
    unsigned int u = x.u;
    unsigned int r = (u + 0x7FFFu + ((u >> 16) & 1u)) >> 16;   // RNE
    return (ushort_t)r;
}
__device__ inline float b2f(ushort_t s) {
    union { unsigned int u; float f; } x; x.u = ((unsigned int)s) << 16;
    return x.f;
}

// async global->LDS, 16B per lane; LDS dest is wave-uniform base (+lane*16 by HW)
__device__ inline void glds16(const ushort_t* gp, void* lp) {
    __builtin_amdgcn_global_load_lds(
        (const __attribute__((address_space(1))) unsigned int*)gp,
        (__attribute__((address_space(3))) unsigned int*)lp, 16, 0, 0);
}

// ---------------- workspace element offsets (ushort units) ----------------
#define E_BWR   0u
#define E_BW1   147456u
#define E_BW2   163840u
#define E_BWE   172032u
#define E_BWO1  208896u
#define E_BWO2  430080u
#define E_ZP    446464u      // 64KB zero page (32768 el)
#define OFF_R1  524288u      // 8MB region   (byte 1048576)
#define OFF_R4  4718592u     // 8MB          (byte 9437184)
#define OFF_R2  8912896u     // 2MB          (byte 17825792)
#define OFF_R3  9961472u     // 2MB          (byte 19922944)
#define OFF_R6  11010048u    // 4MB          (byte 22020096)
#define OFF_R5  13107200u    // 16MB         (byte 26214400) end byte 42991616

// T16 activation layout: element (px, ci) of a CI-channel tensor lives at
//   (px>>4)*(CI*16) + (ci>>3)*128 + (px&15)*8 + (ci&7)
// -> a (16px x 32ci) staging chunk is 1KB contiguous.

// ============================================================================
// Weight prep: OIHW f32 -> [kt][ci_oct(4)][co][8] bf16.  kt = tap*KCT + j
// (j runs A-source 32ci chunks then B-source).
// ============================================================================
__device__ inline void wseg3(int idx, const float* src, ushort_t* dst,
                             int TAPS, int COT, int CIT, int CO_real) {
    int kt  = idx / (COT * 32);
    int r   = idx - kt * (COT * 32);
    int q   = r / (COT * 8);
    int r2  = r - q * (COT * 8);
    int co  = r2 >> 3;
    int e   = r2 & 7;
    int KCT = CIT >> 5;
    int tap = kt / KCT, j = kt - tap * KCT;
    int ci  = j * 32 + q * 8 + e;
    float v = (co < CO_real) ? src[((size_t)co * CIT + ci) * TAPS + tap] : 0.f;
    dst[idx] = f2b(v);
}

__global__ __launch_bounds__(256)
void prep_weights(const float* wr, const float* w1, const float* w2,
                  const float* we, const float* wo1, const float* wo2,
                  ushort_t* ws0)
{
    int idx = blockIdx.x * 256 + threadIdx.x;
    const int n0 = 9*64*256;    // reduce   147456
    const int n1 = 64*256;      // w1        16384
    const int n2 = 64*128;      // w2         8192
    const int n3 = 9*32*128;    // enc       36864
    const int n4 = 9*128*192;   // out1     221184
    const int n5 = 128*128;     // out2      16384
    if (idx < n0) { wseg3(idx, wr,  ws0 + E_BWR,  9, 64, 256, 64);  return; } idx -= n0;
    if (idx < n1) { wseg3(idx, w1,  ws0 + E_BW1,  1, 64, 256, 64);  return; } idx -= n1;
    if (idx < n2) { wseg3(idx, w2,  ws0 + E_BW2,  1, 64, 128, 64);  return; } idx -= n2;
    if (idx < n3) { wseg3(idx, we,  ws0 + E_BWE,  9, 32, 128, 25);  return; } idx -= n3;
    if (idx < n4) { wseg3(idx, wo1, ws0 + E_BWO1, 9, 128, 192, 128); return; } idx -= n4;
    if (idx < n5) { wseg3(idx, wo2, ws0 + E_BWO2, 1, 128, 128, 128); return; } idx -= n5;
    if (idx < 32768) ws0[E_ZP + idx] = 0;   // zero page
}

// ============================================================================
// NCHW f32 -> T16 bf16
// ============================================================================
__global__ __launch_bounds__(256)
void nchw2t16(const float* __restrict__ in, ushort_t* __restrict__ out,
              int C, int LHW, int npx)
{
    int px = blockIdx.x * 256 + threadIdx.x;
    if (px >= npx) return;
    int HW = 1 << LHW;
    int b = px >> LHW, phw = px & (HW - 1);
    const float* src = in + (size_t)b * C * HW + phw;
    unsigned base = (unsigned)(px >> 4) * (C * 16) + (unsigned)(px & 15) * 8;
    for (int c0 = 0; c0 < C; c0 += 8) {
        u16x8 o;
#pragma unroll
        for (int j = 0; j < 8; j++) o[j] = f2b(src[(size_t)(c0 + j) * HW]);
        *reinterpret_cast<u16x8*>(out + base + (c0 >> 3) * 128) = o;
    }
}

// ============================================================================
// LDS-staged implicit-GEMM conv, 2-phase double-buffered pipeline:
//   prologue: stage(buf0, kt=0); barrier
//   kt loop : stage(buf^1, kt+1); ds_read(buf, kt); MFMA; barrier
// One barrier per K-step; next-step loads in flight across the compute.
// Block = one image row (BM=W px) x BN co (co_blk = swizzled y * BN).
// Borders: dy -> whole-tap redirect to global zero page (uniform);
//          dx -> per-lane ds_read select to a per-buffer 16B LDS zero slot.
// ============================================================================
template<int TAPS, int BM, int CIA, int CIB, int COT, int BN, int GY, int EPI>
__global__ __launch_bounds__(256)
void conv_lds(const ushort_t* __restrict__ ws0,
              unsigned offA, unsigned offB, unsigned offW,
              const float* __restrict__ g, const float* __restrict__ bia,
              int COclamp, void* __restrict__ outp,
              int H, int LHW, int relu)
{
    constexpr int KCA = CIA / 32, KCB = CIB / 32;
    constexpr int KCT = KCA + KCB;
    constexpr int KT  = TAPS * KCT;
    constexpr int MF = BM / 32, NF = BN / 32;      // per-wave fragments
    constexpr int ACHUNK = BM / 16;                // 1KB act chunks
    constexpr int WUNIT  = BN / 16;                // 1KB weight units
    constexpr int WOFF = BM * 64;                  // bytes: act region size
    constexpr int ZS   = BM * 64 + BN * 64;        // per-buffer zero slot
    constexpr int BUF  = ZS + 16;                  // bytes per buffer
    constexpr int LBN3 = (BN == 128) ? 10 : (BN == 64) ? 9 : 8;  // log2(BN*8)
    __shared__ char lds[2 * BUF];

    // bijective XCD-chunked swizzle over the flattened (x,y) grid, y-fastest
    const unsigned nwg  = gridDim.x * GY;
    const unsigned orig = blockIdx.x * GY + blockIdx.y;
    const unsigned qq = nwg >> 3, r8 = nwg & 7, xc = orig & 7, k0 = orig >> 3;
    const unsigned logical = (xc < r8 ? xc * (qq + 1)
                                      : r8 * (qq + 1) + (xc - r8) * qq) + k0;
    const unsigned bx = logical / GY;
    const int co_blk = (int)(logical - bx * GY) * BN;

    const int tid = threadIdx.x, w = tid >> 6, lane = tid & 63;
    const int l15 = lane & 15, lhi = lane >> 4;
    const int wpx = (w & 1) * (BM / 2), cw0 = (w >> 1) * (BN / 2);
    const int yb = (int)(bx & (unsigned)(H - 1));      // BM == W: block = row yb
    const unsigned pxc0 = bx * ACHUNK;

    // per-buffer zero slots
    if (tid < 8) *(unsigned*)(lds + (tid >> 2) * BUF + ZS + (tid & 3) * 4) = 0u;

    // act fragment LDS offsets per dx (within a buffer)
    int aA[3][MF];
#pragma unroll
    for (int dxi = 0; dxi < 3; ++dxi) {
        const int dx = dxi - 1;
#pragma unroll
        for (int mf = 0; mf < MF; ++mf) {
            int pr = wpx + mf * 16 + l15 + dx;
            bool ok = (TAPS == 1) ? true : (pr >= 0 && pr < BM);
            aA[dxi][mf] = ok ? (((pr >> 4) << 10) + (lhi << 8) + ((pr & 15) << 4)) : ZS;
        }
    }
    int wA[NF];
#pragma unroll
    for (int nf = 0; nf < NF; ++nf)
        wA[nf] = WOFF + (lhi * BN + cw0 + nf * 16 + l15) * 16;

    f32x4 acc[NF][MF];
#pragma unroll
    for (int nf = 0; nf < NF; ++nf)
#pragma unroll
        for (int mf = 0; mf < MF; ++mf)
            acc[nf][mf] = (f32x4){0.f, 0.f, 0.f, 0.f};

    auto stage = [&](int kt, int bsel) {
        const int tap = kt / KCT;
        const int j   = kt - tap * KCT;
        const bool isA = (j < KCA);
        const int kc  = isA ? j : (j - KCA);
        const int dy  = (TAPS == 9) ? tap / 3 - 1 : 0;
        const int CI  = isA ? CIA : CIB;
        const unsigned offS = isA ? offA : offB;
        const bool rowv = (TAPS == 1) || ((yb + dy >= 0) && (yb + dy < H));
        char* lb = lds + bsel * BUF;
        // act (BM x 32ci)
#pragma unroll
        for (int i = 0; i < ACHUNK / 4; ++i) {
            int u = i * 4 + w;
            unsigned s = rowv
                ? offS + (unsigned)((int)pxc0 + dy * ACHUNK + u) * (unsigned)(CI * 16)
                       + (unsigned)(kc * 512) + (unsigned)(lane * 8)
                : E_ZP + (unsigned)(lane * 8);
            glds16(ws0 + s, lb + u * 1024);
        }
        // weights (BN x 32ci), layout [q][co][8] within the kt tile
        const unsigned wsrc = offW + (unsigned)kt * (unsigned)(COT * 32);
#pragma unroll
        for (int i = 0; i < (WUNIT + 3) / 4; ++i) {
            int u = i * 4 + w;
            if (WUNIT >= 4 || w < WUNIT) {
                int el  = u * 512 + lane * 8;
                int q   = el >> LBN3;
                int col = (el & ((1 << LBN3) - 1)) >> 3;
                glds16(ws0 + wsrc + q * (COT * 8) + (co_blk + col) * 8,
                       lb + WOFF + u * 1024);
            }
        }
    };

    auto step = [&](int kt, int bsel) {
        const int tap = kt / KCT;
        const int dxi = (TAPS == 9) ? (tap - (tap / 3) * 3) : 1;
        const char* lb = lds + bsel * BUF;
        bf16x8 af[MF], wf[NF];
#pragma unroll
        for (int mf = 0; mf < MF; ++mf)
            af[mf] = *reinterpret_cast<const bf16x8*>(lb + aA[dxi][mf]);
#pragma unroll
        for (int nf = 0; nf < NF; ++nf)
            wf[nf] = *reinterpret_cast<const bf16x8*>(lb + wA[nf]);
#pragma unroll
        for (int nf = 0; nf < NF; ++nf)
#pragma unroll
            for (int mf = 0; mf < MF; ++mf)
                acc[nf][mf] = __builtin_amdgcn_mfma_f32_16x16x32_bf16(
                    wf[nf], af[mf], acc[nf][mf], 0, 0, 0);
    };

    stage(0, 0);
    __syncthreads();                       // vmcnt(0) drain + barrier
#pragma unroll
    for (int kt = 0; kt < KT; ++kt) {
        if (kt + 1 < KT) stage(kt + 1, (kt + 1) & 1);  // next tile in flight
        step(kt, kt & 1);                               // compute current
        __syncthreads();                                // next tile ready
    }

    // ---------------- epilogue ----------------
    if (EPI == 0) {
        ushort_t* o1 = (ushort_t*)outp;
#pragma unroll
        for (int nf = 0; nf < NF; ++nf) {
            const int cg = co_blk + cw0 + nf * 16 + (lhi << 2);  // first of 4 co
            float sc[4], bi[4];
#pragma unroll
            for (int r = 0; r < 4; r++) {
                int c = min(cg + r, COclamp - 1);
                sc[r] = g[c] * BNS; bi[r] = bia[c];
            }
#pragma unroll
            for (int mf = 0; mf < MF; ++mf) {
                f32x4 a = acc[nf][mf];
                u16x4 ov;
#pragma unroll
                for (int r = 0; r < 4; r++) {
                    float v = fmaf(a[r], sc[r], bi[r]);
                    if (relu) v = fmaxf(v, 0.f);
                    ov[r] = f2b(v);
                }
                int px = (int)bx * BM + wpx + mf * 16 + l15;
                unsigned off = (unsigned)(px >> 4) * (COT * 16)
                             + (unsigned)(cg >> 3) * 128
                             + (unsigned)(px & 15) * 8 + (unsigned)(cg & 7);
                *reinterpret_cast<u16x4*>(o1 + off) = ov;
            }
        }
    } else {
        float* o1 = (float*)outp;
        const int HW = 1 << LHW;
#pragma unroll
        for (int nf = 0; nf < NF; ++nf) {
            const int cg = co_blk + cw0 + nf * 16 + (lhi << 2);
            float sc[4], bi[4];
#pragma unroll
            for (int r = 0; r < 4; r++) {
                int c = min(cg + r, COclamp - 1);
                sc[r] = g[c] * BNS; bi[r] = bia[c];
            }
#pragma unroll
            for (int mf = 0; mf < MF; ++mf) {
                int px = (int)bx * BM + wpx + mf * 16 + l15;
                int b = px >> LHW, phw = px & (HW - 1);
#pragma unroll
                for (int r = 0; r < 4; r++) {
                    float v = fmaf(acc[nf][mf][r], sc[r], bi[r]);
                    if (relu) v = fmaxf(v, 0.f);
                    o1[((size_t)(b * COT + cg + r)) * HW + phw] = v;
                }
            }
        }
    }
}

// ============================================================================
// 2x bilinear resize (align-corners linspace), T16 bf16, C=64, 64x64 -> 128x128
// ============================================================================
__global__ __launch_bounds__(256)
void resize2x_t16(const ushort_t* __restrict__ in, ushort_t* __restrict__ out)
{
    int t = blockIdx.x * 256 + threadIdx.x;
    int cg = t & 7;
    int opx = t >> 3;
    int xo = opx & 127;
    int rest = opx >> 7;
    int yo = rest & 127;
    int b  = rest >> 7;
    float fy = (float)yo * 63.f / 127.f;
    float fx = (float)xo * 63.f / 127.f;
    int y0 = (int)fy, x0 = (int)fx;
    float wy = fy - (float)y0, wx = fx - (float)x0;
    int y1 = min(y0 + 1, 63), x1 = min(x0 + 1, 63);
    int qb = b * 4096;
#define RD(Y, X) (*reinterpret_cast<const bf16x8*>(in + \
    (unsigned)(((qb + (Y) * 64 + (X)) >> 4) * 1024) + cg * 128 + ((qb + (Y) * 64 + (X)) & 15) * 8))
    bf16x8 v00 = RD(y0, x0), v01 = RD(y0, x1), v10 = RD(y1, x0), v11 = RD(y1, x1);
#undef RD
    u16x8 o;
#pragma unroll
    for (int k = 0; k < 8; k++) {
        float l = b2f((ushort_t)v00[k]) * (1.f - wy) + b2f((ushort_t)v10[k]) * wy;
        float r = b2f((ushort_t)v01[k]) * (1.f - wy) + b2f((ushort_t)v11[k]) * wy;
        o[k] = f2b(l * (1.f - wx) + r * wx);
    }
    *reinterpret_cast<u16x8*>(out + (unsigned)(opx >> 4) * 1024 + cg * 128 + (opx & 15) * 8) = o;
}

// ============================================================================
// softmax over 25 channels, T16 (CO tile 32), in place
// ============================================================================
__global__ __launch_bounds__(256)
void softmax25(ushort_t* __restrict__ wm, int npx)
{
    int px = blockIdx.x * 256 + threadIdx.x;
    if (px >= npx) return;
    ushort_t* p = wm + (unsigned)(px >> 4) * 512 + (px & 15) * 8;
    u16x8 r0 = *reinterpret_cast<u16x8*>(p);
    u16x8 r1 = *reinterpret_cast<u16x8*>(p + 128);
    u16x8 r2 = *reinterpret_cast<u16x8*>(p + 256);
    float v[25];
#pragma unroll
    for (int k = 0; k < 8; k++) v[k]      = b2f(r0[k]);
#pragma unroll
    for (int k = 0; k < 8; k++) v[8 + k]  = b2f(r1[k]);
#pragma unroll
    for (int k = 0; k < 8; k++) v[16 + k] = b2f(r2[k]);
    v[24] = b2f(p[384]);
    float m = v[0];
#pragma unroll
    for (int c = 1; c < 25; c++) m = fmaxf(m, v[c]);
    float s = 0.f;
#pragma unroll
    for (int c = 0; c < 25; c++) { v[c] = __expf(v[c] - m); s += v[c]; }
    float inv = 1.f / s;
    u16x8 o0, o1, o2;
#pragma unroll
    for (int k = 0; k < 8; k++) o0[k] = f2b(v[k] * inv);
#pragma unroll
    for (int k = 0; k < 8; k++) o1[k] = f2b(v[8 + k] * inv);
#pragma unroll
    for (int k = 0; k < 8; k++) o2[k] = f2b(v[16 + k] * inv);
    *reinterpret_cast<u16x8*>(p)       = o0;
    *reinterpret_cast<u16x8*>(p + 128) = o1;
    *reinterpret_cast<u16x8*>(p + 256) = o2;
    p[384] = f2b(v[24] * inv);
}

// ============================================================================
// CARAFE combine (T16 bf16, C=64, H=W=128)
// ============================================================================
__global__ __launch_bounds__(256)
void carafe25(const ushort_t* __restrict__ wm, const ushort_t* __restrict__ xu,
              ushort_t* __restrict__ out)
{
    int t = blockIdx.x * 256 + threadIdx.x;
    int cg = t & 7;
    int px = t >> 3;
    int x = px & 127;
    int y = (px >> 7) & 127;
    const ushort_t* wp = wm + (unsigned)(px >> 4) * 512 + (px & 15) * 8;
    u16x8 r0 = *reinterpret_cast<const u16x8*>(wp);
    u16x8 r1 = *reinterpret_cast<const u16x8*>(wp + 128);
    u16x8 r2 = *reinterpret_cast<const u16x8*>(wp + 256);
    float v[25];
#pragma unroll
    for (int k = 0; k < 8; k++) v[k]      = b2f(r0[k]);
#pragma unroll
    for (int k = 0; k < 8; k++) v[8 + k]  = b2f(r1[k]);
#pragma unroll
    for (int k = 0; k < 8; k++) v[16 + k] = b2f(r2[k]);
    v[24] = b2f(wp[384]);

    float acc[8];
#pragma unroll
    for (int k = 0; k < 8; k++) acc[k] = 0.f;
#pragma unroll
    for (int i = 0; i < 5; i++) {
        int yy = y + 2 * i - 4;
#pragma unroll
        for (int j = 0; j < 5; j++) {
            int xx = x + 2 * j - 4;
            if (yy >= 0 && yy < 128 && xx >= 0 && xx < 128) {
                int q = px + (2 * i - 4) * 128 + (2 * j - 4);
                bf16x8 xv = *reinterpret_cast<const bf16x8*>(
                    xu + (unsigned)(q >> 4) * 1024 + cg * 128 + (q & 15) * 8);
                float wv = v[i * 5 + j];
#pragma unroll
                for (int k = 0; k < 8; k++)
                    acc[k] = fmaf(wv, b2f((ushort_t)xv[k]), acc[k]);
            }
        }
    }
    u16x8 o;
#pragma unroll
    for (int k = 0; k < 8; k++) o[k] = f2b(acc[k]);
    *reinterpret_cast<u16x8*>(out + (unsigned)(px >> 4) * 1024 + cg * 128 + (px & 15) * 8) = o;
}

// ============================================================================
extern "C" void kernel_launch(void* const* d_in, const int* in_sizes, int n_in,
                              void* d_out, int out_size, void* d_ws, size_t ws_size,
                              hipStream_t stream)
{
    const float* x_h      = (const float*)d_in[0];
    const float* x_l      = (const float*)d_in[1];
    const float* w_reduce = (const float*)d_in[2];
    const float* g_reduce = (const float*)d_in[3];
    const float* b_reduce = (const float*)d_in[4];
    const float* w1       = (const float*)d_in[5];
    const float* g1       = (const float*)d_in[6];
    const float* b1       = (const float*)d_in[7];
    const float* w2       = (const float*)d_in[8];
    const float* g2       = (const float*)d_in[9];
    const float* b2       = (const float*)d_in[10];
    const float* w_enc    = (const float*)d_in[11];
    const float* g_enc    = (const float*)d_in[12];
    const float* b_enc    = (const float*)d_in[13];
    const float* w_out1   = (const float*)d_in[14];
    const float* g_out1   = (const float*)d_in[15];
    const float* b_out1   = (const float*)d_in[16];
    const float* w_out2   = (const float*)d_in[17];
    const float* g_out2   = (const float*)d_in[18];
    const float* b_out2   = (const float*)d_in[19];

    ushort_t* ws0 = (ushort_t*)d_ws;

    const unsigned oXHC = OFF_R1;   // (16384, 256) T16
    const unsigned oC1  = OFF_R2;   // (16384, 64)
    const unsigned oXR  = OFF_R3;   // (16384, 64)
    const unsigned oX1  = OFF_R4;   // (65536, 64)
    const unsigned oXLC = OFF_R5;   // (65536, 128)
    const unsigned oX2  = OFF_R1;   // (65536, 64)   xh_c dead
    const unsigned oWM  = OFF_R6;   // (65536, 32)
    const unsigned oXU  = OFF_R4;   // (65536, 64)   x1 dead
    const unsigned oXB  = OFF_R1;   // (65536, 64)   x2 dead
    const unsigned oY1  = OFF_R4;   // (65536, 128)

    // 0) weights -> bf16 [kt][ci_oct][co][8] + zero page
    prep_weights<<<1872, 256, 0, stream>>>(w_reduce, w1, w2, w_enc, w_out1, w_out2, ws0);
    // 1) x_h -> T16 bf16
    nchw2t16<<<64, 256, 0, stream>>>(x_h, ws0 + oXHC, 256, 12, 16384);
    // 2) c1 = cbr1x1(xh_c, w1): M=16384 K=256 CO=64
    conv_lds<1, 64, 256, 0, 64, 32, 2, 0><<<dim3(256, 2), 256, 0, stream>>>(
        ws0, oXHC, 0u, E_BW1, g1, b1, 64, ws0 + oC1, 64, 12, 1);
    // 3) xr = cbr3x3(xh_c, w_reduce): M=16384 K=2304 CO=64
    conv_lds<9, 64, 256, 0, 64, 32, 2, 0><<<dim3(256, 2), 256, 0, stream>>>(
        ws0, oXHC, 0u, E_BWR, g_reduce, b_reduce, 64, ws0 + oXR, 64, 12, 1);
    // 4) x1 = resize2x(c1)
    resize2x_t16<<<2048, 256, 0, stream>>>(ws0 + oC1, ws0 + oX1);
    // 5) x_l -> T16 bf16
    nchw2t16<<<256, 256, 0, stream>>>(x_l, ws0 + oXLC, 128, 14, 65536);
    // 6) x2 = cbr1x1(xl_c, w2): M=65536 K=128 CO=64
    conv_lds<1, 128, 128, 0, 64, 32, 2, 0><<<dim3(512, 2), 256, 0, stream>>>(
        ws0, oXLC, 0u, E_BW2, g2, b2, 64, ws0 + oX2, 128, 14, 1);
    // 7) wm = conv3x3(concat(x1,x2), w_enc), no relu: CO=32 (25 real)
    conv_lds<9, 128, 64, 64, 32, 32, 1, 0><<<dim3(512, 1), 256, 0, stream>>>(
        ws0, oX1, oX2, E_BWE, g_enc, b_enc, 25, ws0 + oWM, 128, 14, 0);
    // 8) softmax over 25 mask channels (in place)
    softmax25<<<256, 256, 0, stream>>>(ws0 + oWM, 65536);
    // 9) xu = resize2x(xr)
    resize2x_t16<<<2048, 256, 0, stream>>>(ws0 + oXR, ws0 + oXU);
    // 10) X = carafe(wm, xu)
    carafe25<<<2048, 256, 0, stream>>>(ws0 + oWM, ws0 + oXU, ws0 + oXB);
    // 11) y1 = cbr3x3(concat(X, xl_c), w_out1): CO=128, co split across grid.y
    conv_lds<9, 128, 64, 128, 128, 64, 2, 0><<<dim3(512, 2), 256, 0, stream>>>(
        ws0, oXB, oXLC, E_BWO1, g_out1, b_out1, 128, ws0 + oY1, 128, 14, 1);
    // 12) out = cbr1x1(y1, w_out2) -> d_out NCHW f32, co split across grid.y
    conv_lds<1, 128, 128, 0, 128, 64, 2, 1><<<dim3(512, 2), 256, 0, stream>>>(
        ws0, oY1, 0u, E_BWO2, g_out2, b_out2, 128, d_out, 128, 14, 1);
}

// Round 7
// 166.268 us; speedup vs baseline: 1.2686x; 1.2686x over previous
//
#include <hip/hip_runtime.h>
#include <math.h>

#define BNS 0.99999500003749981f  // 1/sqrt(1+1e-5)

typedef short          bf16x8  __attribute__((ext_vector_type(8)));
typedef float          f32x4   __attribute__((ext_vector_type(4)));
typedef unsigned short u16x8   __attribute__((ext_vector_type(8)));
typedef unsigned short u16x4   __attribute__((ext_vector_type(4)));
typedef unsigned short ushort_t;

__device__ inline ushort_t f2b(float f) {
    union { float f; unsigned int u; } x; x.f = f;
    unsigned int u = x.u;
    unsigned int r = (u + 0x7FFFu + ((u >> 16) & 1u)) >> 16;   // RNE
    return (ushort_t)r;
}
__device__ inline float b2f(ushort_t s) {
    union { unsigned int u; float f; } x; x.u = ((unsigned int)s) << 16;
    return x.f;
}

// async global->LDS, 16B per lane; LDS dest is wave-uniform base (+lane*16 by HW)
__device__ inline void glds16(const ushort_t* gp, void* lp) {
    __builtin_amdgcn_global_load_lds(
        (const __attribute__((address_space(1))) unsigned int*)gp,
        (__attribute__((address_space(3))) unsigned int*)lp, 16, 0, 0);
}

// counted waitcnt (T4): wait until <=N vmem outstanding; optional lgkm drain
template<int N, bool LG0>
__device__ __forceinline__ void wait_v() {
    if constexpr (LG0) {
        if constexpr (N == 0)      asm volatile("s_waitcnt vmcnt(0) lgkmcnt(0)" ::: "memory");
        else if constexpr (N == 2) asm volatile("s_waitcnt vmcnt(2) lgkmcnt(0)" ::: "memory");
        else                       asm volatile("s_waitcnt vmcnt(3) lgkmcnt(0)" ::: "memory");
    } else {
        if constexpr (N == 0)      asm volatile("s_waitcnt vmcnt(0)" ::: "memory");
        else if constexpr (N == 2) asm volatile("s_waitcnt vmcnt(2)" ::: "memory");
        else                       asm volatile("s_waitcnt vmcnt(3)" ::: "memory");
    }
}

// ---------------- workspace element offsets (ushort units) ----------------
#define E_BWR   0u
#define E_BW1   147456u
#define E_BW2   163840u
#define E_BWE   172032u
#define E_BWO1  208896u
#define E_BWO2  430080u
#define E_ZP    446464u      // 64KB zero page (32768 el)
#define OFF_R1  524288u      // 8MB region   (byte 1048576)
#define OFF_R4  4718592u     // 8MB          (byte 9437184)
#define OFF_R2  8912896u     // 2MB          (byte 17825792)
#define OFF_R3  9961472u     // 2MB          (byte 19922944)
#define OFF_R6  11010048u    // 4MB          (byte 22020096)
#define OFF_R5  13107200u    // 16MB         (byte 26214400) end byte 42991616

// T16 activation layout: element (px, ci) of a CI-channel tensor lives at
//   (px>>4)*(CI*16) + (ci>>3)*128 + (px&15)*8 + (ci&7)

// ============================================================================
// Weight prep: OIHW f32 -> [kt][ci_oct(4)][co][8] bf16.
// ============================================================================
__device__ inline void wseg3(int idx, const float* src, ushort_t* dst,
                             int TAPS, int COT, int CIT, int CO_real) {
    int kt  = idx / (COT * 32);
    int r   = idx - kt * (COT * 32);
    int q   = r / (COT * 8);
    int r2  = r - q * (COT * 8);
    int co  = r2 >> 3;
    int e   = r2 & 7;
    int KCT = CIT >> 5;
    int tap = kt / KCT, j = kt - tap * KCT;
    int ci  = j * 32 + q * 8 + e;
    float v = (co < CO_real) ? src[((size_t)co * CIT + ci) * TAPS + tap] : 0.f;
    dst[idx] = f2b(v);
}

__global__ __launch_bounds__(256)
void prep_weights(const float* wr, const float* w1, const float* w2,
                  const float* we, const float* wo1, const float* wo2,
                  ushort_t* ws0)
{
    int idx = blockIdx.x * 256 + threadIdx.x;
    const int n0 = 9*64*256;    // reduce   147456
    const int n1 = 64*256;      // w1        16384
    const int n2 = 64*128;      // w2         8192
    const int n3 = 9*32*128;    // enc       36864
    const int n4 = 9*128*192;   // out1     221184
    const int n5 = 128*128;     // out2      16384
    if (idx < n0) { wseg3(idx, wr,  ws0 + E_BWR,  9, 64, 256, 64);  return; } idx -= n0;
    if (idx < n1) { wseg3(idx, w1,  ws0 + E_BW1,  1, 64, 256, 64);  return; } idx -= n1;
    if (idx < n2) { wseg3(idx, w2,  ws0 + E_BW2,  1, 64, 128, 64);  return; } idx -= n2;
    if (idx < n3) { wseg3(idx, we,  ws0 + E_BWE,  9, 32, 128, 25);  return; } idx -= n3;
    if (idx < n4) { wseg3(idx, wo1, ws0 + E_BWO1, 9, 128, 192, 128); return; } idx -= n4;
    if (idx < n5) { wseg3(idx, wo2, ws0 + E_BWO2, 1, 128, 128, 128); return; } idx -= n5;
    if (idx < 32768) ws0[E_ZP + idx] = 0;   // zero page
}

// ============================================================================
// NCHW f32 -> T16 bf16
// ============================================================================
__global__ __launch_bounds__(256)
void nchw2t16(const float* __restrict__ in, ushort_t* __restrict__ out,
              int C, int LHW, int npx)
{
    int px = blockIdx.x * 256 + threadIdx.x;
    if (px >= npx) return;
    int HW = 1 << LHW;
    int b = px >> LHW, phw = px & (HW - 1);
    const float* src = in + (size_t)b * C * HW + phw;
    unsigned base = (unsigned)(px >> 4) * (C * 16) + (unsigned)(px & 15) * 8;
    for (int c0 = 0; c0 < C; c0 += 8) {
        u16x8 o;
#pragma unroll
        for (int j = 0; j < 8; j++) o[j] = f2b(src[(size_t)(c0 + j) * HW]);
        *reinterpret_cast<u16x8*>(out + base + (c0 >> 3) * 128) = o;
    }
}

// ============================================================================
// LDS-staged implicit-GEMM conv, counted-vmcnt double-buffered pipeline (T4):
//   stage(0); loop kt: { stage(kt+1); s_waitcnt vmcnt(S); s_barrier;
//                        ds_read+MFMA(kt); s_barrier }
// kt+1's loads stay in flight across the barriers (never drained to 0 in-loop).
// Every wave issues exactly S global_load_lds per stage (weight units are
// duplicated across waves when BN is small -> identical writes, uniform count).
// Block = one image row (BM=W px) x BN co.  XCD swizzle over blockIdx.x only
// (gridDim.x % 8 == 0 so bIdx.x % 8 == real XCD).
// EPI: 0 = T16 bf16 out, 1 = NCHW f32 out, 2 = T16 bf16 + fused softmax-25.
// ============================================================================
template<int TAPS, int BM, int CIA, int CIB, int COT, int BN, int EPI>
__global__ __launch_bounds__(256)
void conv_lds(const ushort_t* __restrict__ ws0,
              unsigned offA, unsigned offB, unsigned offW,
              const float* __restrict__ g, const float* __restrict__ bia,
              int COclamp, void* __restrict__ outp,
              int H, int LHW, int relu)
{
    constexpr int KCA = CIA / 32, KCB = CIB / 32;
    constexpr int KCT = KCA + KCB;
    constexpr int KT  = TAPS * KCT;
    constexpr int MF = BM / 32, NF = BN / 32;      // per-wave fragments
    constexpr int ACHUNK = BM / 16;                // 1KB act chunks
    constexpr int WUNIT  = BN / 16;                // 1KB weight units
    constexpr int A4 = ACHUNK / 4;                 // act loads per wave
    constexpr int W4 = (WUNIT + 3) / 4;            // wt loads per wave
    constexpr int SS = A4 + W4;                    // uniform loads/wave/stage
    static_assert(SS == 2 || SS == 3, "vmcnt literal table");
    constexpr int WOFF = BM * 64;                  // bytes: act region size
    constexpr int ZS   = BM * 64 + BN * 64;        // per-buffer zero slot
    constexpr int BUF  = ZS + 16;                  // bytes per buffer
    constexpr int LBN3 = (BN == 128) ? 10 : (BN == 64) ? 9 : 8;  // log2(BN*8)
    __shared__ __align__(16) char lds[2 * BUF];

    // XCD-chunked swizzle: real XCD = blockIdx.x % 8 (gridDim.x % 8 == 0,
    // y*gridDim.x vanishes mod 8). co-splits (same x) share the XCD + row.
    const unsigned nx = gridDim.x, ox = blockIdx.x;
    const unsigned qq = nx >> 3, xcd = ox & 7, k0 = ox >> 3;
    const unsigned bx = xcd * qq + k0;
    const int co_blk = blockIdx.y * BN;

    const int tid = threadIdx.x, w = tid >> 6, lane = tid & 63;
    const int l15 = lane & 15, lhi = lane >> 4;
    const int wpx = (w & 1) * (BM / 2), cw0 = (w >> 1) * (BN / 2);
    const int yb = (int)(bx & (unsigned)(H - 1));      // BM == W: block = row yb
    const unsigned pxc0 = bx * ACHUNK;

    // per-buffer zero slots (drained by iter-0's lgkmcnt(0))
    if (tid < 8) *(unsigned*)(lds + (tid >> 2) * BUF + ZS + (tid & 3) * 4) = 0u;

    // act fragment LDS offsets per dx (within a buffer)
    int aA[3][MF];
#pragma unroll
    for (int dxi = 0; dxi < 3; ++dxi) {
        const int dx = dxi - 1;
#pragma unroll
        for (int mf = 0; mf < MF; ++mf) {
            int pr = wpx + mf * 16 + l15 + dx;
            bool ok = (TAPS == 1) ? true : (pr >= 0 && pr < BM);
            aA[dxi][mf] = ok ? (((pr >> 4) << 10) + (lhi << 8) + ((pr & 15) << 4)) : ZS;
        }
    }
    int wA[NF];
#pragma unroll
    for (int nf = 0; nf < NF; ++nf)
        wA[nf] = WOFF + (lhi * BN + cw0 + nf * 16 + l15) * 16;

    f32x4 acc[NF][MF];
#pragma unroll
    for (int nf = 0; nf < NF; ++nf)
#pragma unroll
        for (int mf = 0; mf < MF; ++mf)
            acc[nf][mf] = (f32x4){0.f, 0.f, 0.f, 0.f};

    auto stage = [&](int kt, int bsel) {
        const int tap = kt / KCT;
        const int j   = kt - tap * KCT;
        const bool isA = (j < KCA);
        const int kc  = isA ? j : (j - KCA);
        const int dy  = (TAPS == 9) ? tap / 3 - 1 : 0;
        const int CI  = isA ? CIA : CIB;
        const unsigned offS = isA ? offA : offB;
        const bool rowv = (TAPS == 1) || ((yb + dy >= 0) && (yb + dy < H));
        char* lb = lds + bsel * BUF;
        // act (BM x 32ci): A4 loads per wave
#pragma unroll
        for (int i = 0; i < A4; ++i) {
            int u = i * 4 + w;
            unsigned s = rowv
                ? offS + (unsigned)((int)pxc0 + dy * ACHUNK + u) * (unsigned)(CI * 16)
                       + (unsigned)(kc * 512) + (unsigned)(lane * 8)
                : E_ZP + (unsigned)(lane * 8);
            glds16(ws0 + s, lb + u * 1024);
        }
        // weights (BN x 32ci): W4 loads per wave; units duplicated across
        // waves when WUNIT < 4 (identical data -> benign double-write).
        const unsigned wsrc = offW + (unsigned)kt * (unsigned)(COT * 32);
#pragma unroll
        for (int i = 0; i < W4; ++i) {
            int u = (i * 4 + w) % WUNIT;
            int el  = u * 512 + lane * 8;
            int q   = el >> LBN3;
            int col = (el & ((1 << LBN3) - 1)) >> 3;
            glds16(ws0 + wsrc + q * (COT * 8) + (co_blk + col) * 8,
                   lb + WOFF + u * 1024);
        }
    };

    auto step = [&](int kt, int bsel) {
        const int tap = kt / KCT;
        const int dxi = (TAPS == 9) ? (tap - (tap / 3) * 3) : 1;
        const char* lb = lds + bsel * BUF;
        bf16x8 af[MF], wf[NF];
#pragma unroll
        for (int mf = 0; mf < MF; ++mf)
            af[mf] = *reinterpret_cast<const bf16x8*>(lb + aA[dxi][mf]);
#pragma unroll
        for (int nf = 0; nf < NF; ++nf)
            wf[nf] = *reinterpret_cast<const bf16x8*>(lb + wA[nf]);
#pragma unroll
        for (int nf = 0; nf < NF; ++nf)
#pragma unroll
            for (int mf = 0; mf < MF; ++mf)
                acc[nf][mf] = __builtin_amdgcn_mfma_f32_16x16x32_bf16(
                    wf[nf], af[mf], acc[nf][mf], 0, 0, 0);
    };

    stage(0, 0);
#pragma unroll
    for (int kt = 0; kt < KT; ++kt) {
        if (kt + 1 < KT) stage(kt + 1, (kt + 1) & 1);   // keep SS loads in flight
        if (kt == 0) { if (kt + 1 < KT) wait_v<SS, true >(); else wait_v<0, true >(); }
        else         { if (kt + 1 < KT) wait_v<SS, false>(); else wait_v<0, false>(); }
        __builtin_amdgcn_s_barrier();
        __builtin_amdgcn_sched_barrier(0);   // no ds_read above the barrier
        step(kt, kt & 1);
        __builtin_amdgcn_sched_barrier(0);
        if (kt + 1 < KT) __builtin_amdgcn_s_barrier();  // buf[kt] free to restage
    }

    // ---------------- epilogue ----------------
    if constexpr (EPI == 0) {
        ushort_t* o1 = (ushort_t*)outp;
#pragma unroll
        for (int nf = 0; nf < NF; ++nf) {
            const int cg = co_blk + cw0 + nf * 16 + (lhi << 2);  // first of 4 co
            float sc[4], bi[4];
#pragma unroll
            for (int r = 0; r < 4; r++) {
                int c = min(cg + r, COclamp - 1);
                sc[r] = g[c] * BNS; bi[r] = bia[c];
            }
#pragma unroll
            for (int mf = 0; mf < MF; ++mf) {
                f32x4 a = acc[nf][mf];
                u16x4 ov;
#pragma unroll
                for (int r = 0; r < 4; r++) {
                    float v = fmaf(a[r], sc[r], bi[r]);
                    if (relu) v = fmaxf(v, 0.f);
                    ov[r] = f2b(v);
                }
                int px = (int)bx * BM + wpx + mf * 16 + l15;
                unsigned off = (unsigned)(px >> 4) * (COT * 16)
                             + (unsigned)(cg >> 3) * 128
                             + (unsigned)(px & 15) * 8 + (unsigned)(cg & 7);
                *reinterpret_cast<u16x4*>(o1 + off) = ov;
            }
        }
    } else if constexpr (EPI == 1) {
        float* o1 = (float*)outp;
        const int HW = 1 << LHW;
#pragma unroll
        for (int nf = 0; nf < NF; ++nf) {
            const int cg = co_blk + cw0 + nf * 16 + (lhi << 2);
            float sc[4], bi[4];
#pragma unroll
            for (int r = 0; r < 4; r++) {
                int c = min(cg + r, COclamp - 1);
                sc[r] = g[c] * BNS; bi[r] = bia[c];
            }
#pragma unroll
            for (int mf = 0; mf < MF; ++mf) {
                int px = (int)bx * BM + wpx + mf * 16 + l15;
                int b = px >> LHW, phw = px & (HW - 1);
#pragma unroll
                for (int r = 0; r < 4; r++) {
                    float v = fmaf(acc[nf][mf][r], sc[r], bi[r]);
                    if (relu) v = fmaxf(v, 0.f);
                    o1[((size_t)(b * COT + cg + r)) * HW + phw] = v;
                }
            }
        }
    } else {
        // EPI == 2: fused channel-25 softmax (BN == COT == 32, one block = row)
        __syncthreads();                     // all waves done with staging LDS
        float* sf = (float*)lds;             // [32 co][136 f32] (pad vs banks)
#pragma unroll
        for (int mf = 0; mf < MF; ++mf) {
            const int cg = cw0 + (lhi << 2);
            int pxl = wpx + mf * 16 + l15;
            f32x4 a = acc[0][mf];
#pragma unroll
            for (int r = 0; r < 4; r++) {
                int c = min(cg + r, COclamp - 1);
                sf[(cg + r) * 136 + pxl] = fmaf(a[r], g[c] * BNS, bia[c]);
            }
        }
        __syncthreads();
        if (tid < BM) {
            int gpx = (int)bx * BM + tid;
            float v[25];
#pragma unroll
            for (int c = 0; c < 25; ++c) v[c] = sf[c * 136 + tid];
            float m = v[0];
#pragma unroll
            for (int c = 1; c < 25; ++c) m = fmaxf(m, v[c]);
            float s = 0.f;
#pragma unroll
            for (int c = 0; c < 25; ++c) { v[c] = __expf(v[c] - m); s += v[c]; }
            float inv = 1.f / s;
            ushort_t* o1 = (ushort_t*)outp;
            unsigned base = (unsigned)(gpx >> 4) * (COT * 16) + (unsigned)(gpx & 15) * 8;
#pragma unroll
            for (int q = 0; q < 3; ++q) {
                u16x8 ov;
#pragma unroll
                for (int k = 0; k < 8; k++) ov[k] = f2b(v[q * 8 + k] * inv);
                *reinterpret_cast<u16x8*>(o1 + base + q * 128) = ov;
            }
            o1[base + 384] = f2b(v[24] * inv);
        }
    }
}

// ============================================================================
// 2x bilinear resize (align-corners linspace), T16 bf16, C=64, 64x64 -> 128x128
// ============================================================================
__global__ __launch_bounds__(256)
void resize2x_t16(const ushort_t* __restrict__ in, ushort_t* __restrict__ out)
{
    int t = blockIdx.x * 256 + threadIdx.x;
    int cg = t & 7;
    int opx = t >> 3;
    int xo = opx & 127;
    int rest = opx >> 7;
    int yo = rest & 127;
    int b  = rest >> 7;
    float fy = (float)yo * 63.f / 127.f;
    float fx = (float)xo * 63.f / 127.f;
    int y0 = (int)fy, x0 = (int)fx;
    float wy = fy - (float)y0, wx = fx - (float)x0;
    int y1 = min(y0 + 1, 63), x1 = min(x0 + 1, 63);
    int qb = b * 4096;
#define RD(Y, X) (*reinterpret_cast<const bf16x8*>(in + \
    (unsigned)(((qb + (Y) * 64 + (X)) >> 4) * 1024) + cg * 128 + ((qb + (Y) * 64 + (X)) & 15) * 8))
    bf16x8 v00 = RD(y0, x0), v01 = RD(y0, x1), v10 = RD(y1, x0), v11 = RD(y1, x1);
#undef RD
    u16x8 o;
#pragma unroll
    for (int k = 0; k < 8; k++) {
        float l = b2f((ushort_t)v00[k]) * (1.f - wy) + b2f((ushort_t)v10[k]) * wy;
        float r = b2f((ushort_t)v01[k]) * (1.f - wy) + b2f((ushort_t)v11[k]) * wy;
        o[k] = f2b(l * (1.f - wx) + r * wx);
    }
    *reinterpret_cast<u16x8*>(out + (unsigned)(opx >> 4) * 1024 + cg * 128 + (opx & 15) * 8) = o;
}

// ============================================================================
// CARAFE combine (T16 bf16, C=64, H=W=128)
// ============================================================================
__global__ __launch_bounds__(256)
void carafe25(const ushort_t* __restrict__ wm, const ushort_t* __restrict__ xu,
              ushort_t* __restrict__ out)
{
    int t = blockIdx.x * 256 + threadIdx.x;
    int cg = t & 7;
    int px = t >> 3;
    int x = px & 127;
    int y = (px >> 7) & 127;
    const ushort_t* wp = wm + (unsigned)(px >> 4) * 512 + (px & 15) * 8;
    u16x8 r0 = *reinterpret_cast<const u16x8*>(wp);
    u16x8 r1 = *reinterpret_cast<const u16x8*>(wp + 128);
    u16x8 r2 = *reinterpret_cast<const u16x8*>(wp + 256);
    float v[25];
#pragma unroll
    for (int k = 0; k < 8; k++) v[k]      = b2f(r0[k]);
#pragma unroll
    for (int k = 0; k < 8; k++) v[8 + k]  = b2f(r1[k]);
#pragma unroll
    for (int k = 0; k < 8; k++) v[16 + k] = b2f(r2[k]);
    v[24] = b2f(wp[384]);

    float acc[8];
#pragma unroll
    for (int k = 0; k < 8; k++) acc[k] = 0.f;
#pragma unroll
    for (int i = 0; i < 5; i++) {
        int yy = y + 2 * i - 4;
#pragma unroll
        for (int j = 0; j < 5; j++) {
            int xx = x + 2 * j - 4;
            if (yy >= 0 && yy < 128 && xx >= 0 && xx < 128) {
                int q = px + (2 * i - 4) * 128 + (2 * j - 4);
                bf16x8 xv = *reinterpret_cast<const bf16x8*>(
                    xu + (unsigned)(q >> 4) * 1024 + cg * 128 + (q & 15) * 8);
                float wv = v[i * 5 + j];
#pragma unroll
                for (int k = 0; k < 8; k++)
                    acc[k] = fmaf(wv, b2f((ushort_t)xv[k]), acc[k]);
            }
        }
    }
    u16x8 o;
#pragma unroll
    for (int k = 0; k < 8; k++) o[k] = f2b(acc[k]);
    *reinterpret_cast<u16x8*>(out + (unsigned)(px >> 4) * 1024 + cg * 128 + (px & 15) * 8) = o;
}

// ============================================================================
extern "C" void kernel_launch(void* const* d_in, const int* in_sizes, int n_in,
                              void* d_out, int out_size, void* d_ws, size_t ws_size,
                              hipStream_t stream)
{
    const float* x_h      = (const float*)d_in[0];
    const float* x_l      = (const float*)d_in[1];
    const float* w_reduce = (const float*)d_in[2];
    const float* g_reduce = (const float*)d_in[3];
    const float* b_reduce = (const float*)d_in[4];
    const float* w1       = (const float*)d_in[5];
    const float* g1       = (const float*)d_in[6];
    const float* b1       = (const float*)d_in[7];
    const float* w2       = (const float*)d_in[8];
    const float* g2       = (const float*)d_in[9];
    const float* b2       = (const float*)d_in[10];
    const float* w_enc    = (const float*)d_in[11];
    const float* g_enc    = (const float*)d_in[12];
    const float* b_enc    = (const float*)d_in[13];
    const float* w_out1   = (const float*)d_in[14];
    const float* g_out1   = (const float*)d_in[15];
    const float* b_out1   = (const float*)d_in[16];
    const float* w_out2   = (const float*)d_in[17];
    const float* g_out2   = (const float*)d_in[18];
    const float* b_out2   = (const float*)d_in[19];

    ushort_t* ws0 = (ushort_t*)d_ws;

    const unsigned oXHC = OFF_R1;   // (16384, 256) T16
    const unsigned oC1  = OFF_R2;   // (16384, 64)
    const unsigned oXR  = OFF_R3;   // (16384, 64)
    const unsigned oX1  = OFF_R4;   // (65536, 64)
    const unsigned oXLC = OFF_R5;   // (65536, 128)
    const unsigned oX2  = OFF_R1;   // (65536, 64)   xh_c dead
    const unsigned oWM  = OFF_R6;   // (65536, 32)
    const unsigned oXU  = OFF_R4;   // (65536, 64)   x1 dead
    const unsigned oXB  = OFF_R1;   // (65536, 64)   x2 dead
    const unsigned oY1  = OFF_R4;   // (65536, 128)

    // 0) weights -> bf16 [kt][ci_oct][co][8] + zero page
    prep_weights<<<1872, 256, 0, stream>>>(w_reduce, w1, w2, w_enc, w_out1, w_out2, ws0);
    // 1) x_h -> T16 bf16
    nchw2t16<<<64, 256, 0, stream>>>(x_h, ws0 + oXHC, 256, 12, 16384);
    // 2) c1 = cbr1x1(xh_c, w1): M=16384 K=256 CO=64
    conv_lds<1, 64, 256, 0, 64, 32, 0><<<dim3(256, 2), 256, 0, stream>>>(
        ws0, oXHC, 0u, E_BW1, g1, b1, 64, ws0 + oC1, 64, 12, 1);
    // 3) xr = cbr3x3(xh_c, w_reduce): M=16384 K=2304 CO=64
    conv_lds<9, 64, 256, 0, 64, 32, 0><<<dim3(256, 2), 256, 0, stream>>>(
        ws0, oXHC, 0u, E_BWR, g_reduce, b_reduce, 64, ws0 + oXR, 64, 12, 1);
    // 4) x1 = resize2x(c1)
    resize2x_t16<<<2048, 256, 0, stream>>>(ws0 + oC1, ws0 + oX1);
    // 5) x_l -> T16 bf16
    nchw2t16<<<256, 256, 0, stream>>>(x_l, ws0 + oXLC, 128, 14, 65536);
    // 6) x2 = cbr1x1(xl_c, w2): M=65536 K=128 CO=64
    conv_lds<1, 128, 128, 0, 64, 32, 0><<<dim3(512, 2), 256, 0, stream>>>(
        ws0, oXLC, 0u, E_BW2, g2, b2, 64, ws0 + oX2, 128, 14, 1);
    // 7) wm = conv3x3(concat(x1,x2), w_enc) + fused softmax-25 (EPI=2)
    conv_lds<9, 128, 64, 64, 32, 32, 2><<<dim3(512, 1), 256, 0, stream>>>(
        ws0, oX1, oX2, E_BWE, g_enc, b_enc, 25, ws0 + oWM, 128, 14, 0);
    // 8) xu = resize2x(xr)
    resize2x_t16<<<2048, 256, 0, stream>>>(ws0 + oXR, ws0 + oXU);
    // 9) X = carafe(wm, xu)
    carafe25<<<2048, 256, 0, stream>>>(ws0 + oWM, ws0 + oXU, ws0 + oXB);
    // 10) y1 = cbr3x3(concat(X, xl_c), w_out1): CO=128, co split across grid.y
    conv_lds<9, 128, 64, 128, 128, 64, 0><<<dim3(512, 2), 256, 0, stream>>>(
        ws0, oXB, oXLC, E_BWO1, g_out1, b_out1, 128, ws0 + oY1, 128, 14, 1);
    // 11) out = cbr1x1(y1, w_out2) -> d_out NCHW f32, co split across grid.y
    conv_lds<1, 128, 128, 0, 128, 64, 1><<<dim3(512, 2), 256, 0, stream>>>(
        ws0, oY1, 0u, E_BWO2, g_out2, b_out2, 128, d_out, 128, 14, 1);
}

// Round 8
// 155.358 us; speedup vs baseline: 1.3577x; 1.0702x over previous
//
#include <hip/hip_runtime.h>
#include <math.h>

#define BNS 0.99999500003749981f  // 1/sqrt(1+1e-5)

typedef short          bf16x8  __attribute__((ext_vector_type(8)));
typedef float          f32x4   __attribute__((ext_vector_type(4)));
typedef unsigned short u16x8   __attribute__((ext_vector_type(8)));
typedef unsigned short u16x4   __attribute__((ext_vector_type(4)));
typedef unsigned short ushort_t;

__device__ inline ushort_t f2b(float f) {
    union { float f; unsigned int u; } x; x.f = f;
    unsigned int u = x.u;
    unsigned int r = (u + 0x7FFFu + ((u >> 16) & 1u)) >> 16;   // RNE
    return (ushort_t)r;
}
__device__ inline float b2f(ushort_t s) {
    union { unsigned int u; float f; } x; x.u = ((unsigned int)s) << 16;
    return x.f;
}

// async global->LDS, 16B per lane; LDS dest is wave-uniform base (+lane*16 by HW)
__device__ inline void glds16(const ushort_t* gp, void* lp) {
    __builtin_amdgcn_global_load_lds(
        (const __attribute__((address_space(1))) unsigned int*)gp,
        (__attribute__((address_space(3))) unsigned int*)lp, 16, 0, 0);
}

// counted waitcnt (T4): wait until <=N vmem outstanding; optional lgkm drain
template<int N, bool LG0>
__device__ __forceinline__ void wait_v() {
    if constexpr (LG0) {
        if constexpr (N == 0) asm volatile("s_waitcnt vmcnt(0) lgkmcnt(0)" ::: "memory");
        if constexpr (N == 3) asm volatile("s_waitcnt vmcnt(3) lgkmcnt(0)" ::: "memory");
        if constexpr (N == 4) asm volatile("s_waitcnt vmcnt(4) lgkmcnt(0)" ::: "memory");
        if constexpr (N == 5) asm volatile("s_waitcnt vmcnt(5) lgkmcnt(0)" ::: "memory");
        if constexpr (N == 6) asm volatile("s_waitcnt vmcnt(6) lgkmcnt(0)" ::: "memory");
    } else {
        if constexpr (N == 0) asm volatile("s_waitcnt vmcnt(0)" ::: "memory");
        if constexpr (N == 3) asm volatile("s_waitcnt vmcnt(3)" ::: "memory");
        if constexpr (N == 4) asm volatile("s_waitcnt vmcnt(4)" ::: "memory");
        if constexpr (N == 5) asm volatile("s_waitcnt vmcnt(5)" ::: "memory");
        if constexpr (N == 6) asm volatile("s_waitcnt vmcnt(6)" ::: "memory");
    }
}

// ---------------- workspace element offsets (ushort units) ----------------
#define E_BWR   0u
#define E_BW1   147456u
#define E_BW2   163840u
#define E_BWE   172032u
#define E_BWO1  208896u
#define E_BWO2  430080u
#define E_ZP    446464u      // 64KB zero page (32768 el)
#define OFF_R1  524288u      // 8MB region   (byte 1048576)
#define OFF_R4  4718592u     // 8MB          (byte 9437184)
#define OFF_R2  8912896u     // 2MB          (byte 17825792)
#define OFF_R3  9961472u     // 2MB          (byte 19922944)
#define OFF_R6  11010048u    // 4MB          (byte 22020096)
#define OFF_R5  13107200u    // 16MB         (byte 26214400) end byte 42991616

// T16 activation layout: element (px, ci) of a CI-channel tensor lives at
//   (px>>4)*(CI*16) + (ci>>3)*128 + (px&15)*8 + (ci&7)

// ============================================================================
// Weight prep: OIHW f32 -> [kt][ci_oct(4)][co][8] bf16.
// ============================================================================
__device__ inline void wseg3(int idx, const float* src, ushort_t* dst,
                             int TAPS, int COT, int CIT, int CO_real) {
    int kt  = idx / (COT * 32);
    int r   = idx - kt * (COT * 32);
    int q   = r / (COT * 8);
    int r2  = r - q * (COT * 8);
    int co  = r2 >> 3;
    int e   = r2 & 7;
    int KCT = CIT >> 5;
    int tap = kt / KCT, j = kt - tap * KCT;
    int ci  = j * 32 + q * 8 + e;
    float v = (co < CO_real) ? src[((size_t)co * CIT + ci) * TAPS + tap] : 0.f;
    dst[idx] = f2b(v);
}

__global__ __launch_bounds__(256)
void prep_weights(const float* wr, const float* w1, const float* w2,
                  const float* we, const float* wo1, const float* wo2,
                  ushort_t* ws0)
{
    int idx = blockIdx.x * 256 + threadIdx.x;
    const int n0 = 9*64*256;    // reduce   147456
    const int n1 = 64*256;      // w1        16384
    const int n2 = 64*128;      // w2         8192
    const int n3 = 9*32*128;    // enc       36864
    const int n4 = 9*128*192;   // out1     221184
    const int n5 = 128*128;     // out2      16384
    if (idx < n0) { wseg3(idx, wr,  ws0 + E_BWR,  9, 64, 256, 64);  return; } idx -= n0;
    if (idx < n1) { wseg3(idx, w1,  ws0 + E_BW1,  1, 64, 256, 64);  return; } idx -= n1;
    if (idx < n2) { wseg3(idx, w2,  ws0 + E_BW2,  1, 64, 128, 64);  return; } idx -= n2;
    if (idx < n3) { wseg3(idx, we,  ws0 + E_BWE,  9, 32, 128, 25);  return; } idx -= n3;
    if (idx < n4) { wseg3(idx, wo1, ws0 + E_BWO1, 9, 128, 192, 128); return; } idx -= n4;
    if (idx < n5) { wseg3(idx, wo2, ws0 + E_BWO2, 1, 128, 128, 128); return; } idx -= n5;
    if (idx < 32768) ws0[E_ZP + idx] = 0;   // zero page
}

// ============================================================================
// NCHW f32 -> T16 bf16
// ============================================================================
__global__ __launch_bounds__(256)
void nchw2t16(const float* __restrict__ in, ushort_t* __restrict__ out,
              int C, int LHW, int npx)
{
    int px = blockIdx.x * 256 + threadIdx.x;
    if (px >= npx) return;
    int HW = 1 << LHW;
    int b = px >> LHW, phw = px & (HW - 1);
    const float* src = in + (size_t)b * C * HW + phw;
    unsigned base = (unsigned)(px >> 4) * (C * 16) + (unsigned)(px & 15) * 8;
    for (int c0 = 0; c0 < C; c0 += 8) {
        u16x8 o;
#pragma unroll
        for (int j = 0; j < 8; j++) o[j] = f2b(src[(size_t)(c0 + j) * HW]);
        *reinterpret_cast<u16x8*>(out + base + (c0 >> 3) * 128) = o;
    }
}

// ============================================================================
// LDS-staged implicit-GEMM conv, counted-vmcnt double-buffer (T4) with
// dy-major phases:
//  3x3: phase = (dy, 32ci-chunk). Stage ONE act row-chunk + the 3 dx weight
//       tiles; compute all 3 dx taps from it (dx = ds_read lane shift).
//       -> act staging /3, barrier pairs /3, 3x MFMA per phase.
//  1x1: phase = G consecutive 32ci-chunks (act + wt), G sub-steps per phase.
// Pipeline: stage(0); loop p { stage(p+1); s_waitcnt vmcnt(SS); s_barrier;
//                              MFMA(p); s_barrier }  (never drains in-loop)
// Block = one image row (BM=W px) x BN co.  XCD swizzle over blockIdx.x only.
// EPI: 0 = T16 bf16 out, 1 = NCHW f32 out, 2 = T16 bf16 + fused softmax-25.
// ============================================================================
template<int TAPS, int BM, int CIA, int CIB, int COT, int BN, int G, int EPI>
__global__ __launch_bounds__(256)
void conv_lds(const ushort_t* __restrict__ ws0,
              unsigned offA, unsigned offB, unsigned offW,
              const float* __restrict__ g, const float* __restrict__ bia,
              int COclamp, void* __restrict__ outp,
              int H, int LHW, int relu)
{
    constexpr int KCA = CIA / 32, KCB = CIB / 32;
    constexpr int KCT = KCA + KCB;
    constexpr int NW  = (TAPS == 9) ? 3 : G;       // weight tiles per phase
    constexpr int ACP = (TAPS == 9) ? 1 : G;       // act 32ci-chunks per phase
    constexpr int NPH = (TAPS == 9) ? 3 * KCT : KCT / G;
    constexpr int MF = BM / 32, NF = BN / 32;      // per-wave fragments
    constexpr int ACHUNK = BM / 16;                // 1KB units per act chunk
    constexpr int A4 = ACP * ACHUNK / 4;           // act loads per wave/phase
    constexpr int WUNIT = BN / 16;                 // 1KB units per wt tile
    constexpr int TWU = NW * WUNIT;
    constexpr int W4 = (TWU + 3) / 4;              // wt loads per wave/phase
    constexpr int SS = A4 + W4;                    // uniform loads/wave/phase
    constexpr int WOFF = ACP * BM * 64;            // bytes: act region size
    constexpr int ZS   = WOFF + NW * BN * 64;      // per-buffer zero slot
    constexpr int BUF  = ZS + 16;
    constexpr int LBN3 = (BN == 128) ? 10 : (BN == 64) ? 9 : 8;  // log2(BN*8)
    __shared__ __align__(16) char lds[2 * BUF];

    // XCD-chunked swizzle: real XCD = blockIdx.x % 8 (gridDim.x % 8 == 0).
    const unsigned nx = gridDim.x, ox = blockIdx.x;
    const unsigned qq = nx >> 3, xcd = ox & 7, k0 = ox >> 3;
    const unsigned bx = xcd * qq + k0;
    const int co_blk = blockIdx.y * BN;

    const int tid = threadIdx.x, w = tid >> 6, lane = tid & 63;
    const int l15 = lane & 15, lhi = lane >> 4;
    const int wpx = (w & 1) * (BM / 2), cw0 = (w >> 1) * (BN / 2);
    const int yb = (int)(bx & (unsigned)(H - 1));      // BM == W: block = row yb
    const unsigned pxc0 = bx * ACHUNK;

    // per-buffer zero slots (drained by phase-0's lgkmcnt(0))
    if (tid < 8) *(unsigned*)(lds + (tid >> 2) * BUF + ZS + (tid & 3) * 4) = 0u;

    // act fragment LDS offsets per dx (relative to act slot base)
    int aA[3][MF];
#pragma unroll
    for (int dxi = 0; dxi < 3; ++dxi) {
        const int dx = dxi - 1;
#pragma unroll
        for (int mf = 0; mf < MF; ++mf) {
            int pr = wpx + mf * 16 + l15 + dx;
            bool ok = (TAPS == 1) ? true : (pr >= 0 && pr < BM);
            aA[dxi][mf] = ok ? (((pr >> 4) << 10) + (lhi << 8) + ((pr & 15) << 4))
                             : (ZS - ((TAPS == 9) ? 0 : 0));
            if (TAPS == 9 && !ok) aA[dxi][mf] = ZS;   // relative to lb (act at 0)
        }
    }
    int wA[NF];
#pragma unroll
    for (int nf = 0; nf < NF; ++nf)
        wA[nf] = (lhi * BN + cw0 + nf * 16 + l15) * 16;  // within a wt tile

    f32x4 acc[NF][MF];
#pragma unroll
    for (int nf = 0; nf < NF; ++nf)
#pragma unroll
        for (int mf = 0; mf < MF; ++mf)
            acc[nf][mf] = (f32x4){0.f, 0.f, 0.f, 0.f};

    auto stage = [&](int p, int bsel) {
        char* lb = lds + bsel * BUF;
        if constexpr (TAPS == 9) {
            const int dyi = p / KCT, kc = p - dyi * KCT;
            const int dy = dyi - 1;
            const bool isA = (kc < KCA);
            const int kcs = isA ? kc : kc - KCA;
            const int CI  = isA ? CIA : CIB;
            const unsigned offS = isA ? offA : offB;
            const bool rowv = (yb + dy >= 0) && (yb + dy < H);
#pragma unroll
            for (int i = 0; i < A4; ++i) {
                int u = i * 4 + w;
                unsigned s = rowv
                    ? offS + (unsigned)((int)pxc0 + dy * ACHUNK + u) * (unsigned)(CI * 16)
                           + (unsigned)(kcs * 512) + (unsigned)(lane * 8)
                    : E_ZP + (unsigned)(lane * 8);
                glds16(ws0 + s, lb + u * 1024);
            }
#pragma unroll
            for (int i = 0; i < W4; ++i) {
                int t3 = (i * 4 + w) % TWU;
                int tl = t3 / WUNIT, uu = t3 - tl * WUNIT;
                unsigned wsrc = offW + (unsigned)((dyi * 3 + tl) * KCT + kc)
                                       * (unsigned)(COT * 32);
                int el  = uu * 512 + lane * 8;
                int q   = el >> LBN3;
                int col = (el & ((1 << LBN3) - 1)) >> 3;
                glds16(ws0 + wsrc + q * (COT * 8) + (co_blk + col) * 8,
                       lb + WOFF + tl * (BN * 64) + uu * 1024);
            }
        } else {
#pragma unroll
            for (int i = 0; i < A4; ++i) {
                int lin = i * 4 + w;
                int gc = lin / ACHUNK, u = lin - gc * ACHUNK;
                unsigned s = offA + (unsigned)(pxc0 + u) * (unsigned)(CIA * 16)
                           + (unsigned)((p * G + gc) * 512) + (unsigned)(lane * 8);
                glds16(ws0 + s, lb + gc * (BM * 64) + u * 1024);
            }
#pragma unroll
            for (int i = 0; i < W4; ++i) {
                int t3 = (i * 4 + w) % TWU;
                int tl = t3 / WUNIT, uu = t3 - tl * WUNIT;
                unsigned wsrc = offW + (unsigned)(p * G + tl) * (unsigned)(COT * 32);
                int el  = uu * 512 + lane * 8;
                int q   = el >> LBN3;
                int col = (el & ((1 << LBN3) - 1)) >> 3;
                glds16(ws0 + wsrc + q * (COT * 8) + (co_blk + col) * 8,
                       lb + WOFF + tl * (BN * 64) + uu * 1024);
            }
        }
    };

    auto step = [&](int p, int bsel) {
        const char* lb = lds + bsel * BUF;
#pragma unroll
        for (int t = 0; t < NW; ++t) {
            const int dxi = (TAPS == 9) ? t : 1;
            const char* ab = lb + ((TAPS == 9) ? 0 : t * (BM * 64));
            bf16x8 af[MF], wf[NF];
#pragma unroll
            for (int mf = 0; mf < MF; ++mf)
                af[mf] = *reinterpret_cast<const bf16x8*>(ab + aA[dxi][mf]);
#pragma unroll
            for (int nf = 0; nf < NF; ++nf)
                wf[nf] = *reinterpret_cast<const bf16x8*>(
                    lb + WOFF + t * (BN * 64) + wA[nf]);
#pragma unroll
            for (int nf = 0; nf < NF; ++nf)
#pragma unroll
                for (int mf = 0; mf < MF; ++mf)
                    acc[nf][mf] = __builtin_amdgcn_mfma_f32_16x16x32_bf16(
                        wf[nf], af[mf], acc[nf][mf], 0, 0, 0);
        }
    };

    stage(0, 0);
#pragma unroll
    for (int p = 0; p < NPH; ++p) {
        if (p + 1 < NPH) stage(p + 1, (p + 1) & 1);   // keep SS loads in flight
        if (p == 0) { if (p + 1 < NPH) wait_v<SS, true >(); else wait_v<0, true >(); }
        else        { if (p + 1 < NPH) wait_v<SS, false>(); else wait_v<0, false>(); }
        __builtin_amdgcn_s_barrier();
        __builtin_amdgcn_sched_barrier(0);
        step(p, p & 1);
        __builtin_amdgcn_sched_barrier(0);
        if (p + 1 < NPH) __builtin_amdgcn_s_barrier();
    }

    // ---------------- epilogue ----------------
    if constexpr (EPI == 0) {
        ushort_t* o1 = (ushort_t*)outp;
#pragma unroll
        for (int nf = 0; nf < NF; ++nf) {
            const int cg = co_blk + cw0 + nf * 16 + (lhi << 2);  // first of 4 co
            float sc[4], bi[4];
#pragma unroll
            for (int r = 0; r < 4; r++) {
                int c = min(cg + r, COclamp - 1);
                sc[r] = g[c] * BNS; bi[r] = bia[c];
            }
#pragma unroll
            for (int mf = 0; mf < MF; ++mf) {
                f32x4 a = acc[nf][mf];
                u16x4 ov;
#pragma unroll
                for (int r = 0; r < 4; r++) {
                    float v = fmaf(a[r], sc[r], bi[r]);
                    if (relu) v = fmaxf(v, 0.f);
                    ov[r] = f2b(v);
                }
                int px = (int)bx * BM + wpx + mf * 16 + l15;
                unsigned off = (unsigned)(px >> 4) * (COT * 16)
                             + (unsigned)(cg >> 3) * 128
                             + (unsigned)(px & 15) * 8 + (unsigned)(cg & 7);
                *reinterpret_cast<u16x4*>(o1 + off) = ov;
            }
        }
    } else if constexpr (EPI == 1) {
        float* o1 = (float*)outp;
        const int HW = 1 << LHW;
#pragma unroll
        for (int nf = 0; nf < NF; ++nf) {
            const int cg = co_blk + cw0 + nf * 16 + (lhi << 2);
            float sc[4], bi[4];
#pragma unroll
            for (int r = 0; r < 4; r++) {
                int c = min(cg + r, COclamp - 1);
                sc[r] = g[c] * BNS; bi[r] = bia[c];
            }
#pragma unroll
            for (int mf = 0; mf < MF; ++mf) {
                int px = (int)bx * BM + wpx + mf * 16 + l15;
                int b = px >> LHW, phw = px & (HW - 1);
#pragma unroll
                for (int r = 0; r < 4; r++) {
                    float v = fmaf(acc[nf][mf][r], sc[r], bi[r]);
                    if (relu) v = fmaxf(v, 0.f);
                    o1[((size_t)(b * COT + cg + r)) * HW + phw] = v;
                }
            }
        }
    } else {
        // EPI == 2: fused channel-25 softmax (BN == COT == 32, one block = row)
        __syncthreads();                     // all waves done with staging LDS
        float* sf = (float*)lds;             // [32 co][136 f32]
#pragma unroll
        for (int mf = 0; mf < MF; ++mf) {
            const int cg = cw0 + (lhi << 2);
            int pxl = wpx + mf * 16 + l15;
            f32x4 a = acc[0][mf];
#pragma unroll
            for (int r = 0; r < 4; r++) {
                int c = min(cg + r, COclamp - 1);
                sf[(cg + r) * 136 + pxl] = fmaf(a[r], g[c] * BNS, bia[c]);
            }
        }
        __syncthreads();
        if (tid < BM) {
            int gpx = (int)bx * BM + tid;
            float v[25];
#pragma unroll
            for (int c = 0; c < 25; ++c) v[c] = sf[c * 136 + tid];
            float m = v[0];
#pragma unroll
            for (int c = 1; c < 25; ++c) m = fmaxf(m, v[c]);
            float s = 0.f;
#pragma unroll
            for (int c = 0; c < 25; ++c) { v[c] = __expf(v[c] - m); s += v[c]; }
            float inv = 1.f / s;
            ushort_t* o1 = (ushort_t*)outp;
            unsigned base = (unsigned)(gpx >> 4) * (COT * 16) + (unsigned)(gpx & 15) * 8;
#pragma unroll
            for (int q = 0; q < 3; ++q) {
                u16x8 ov;
#pragma unroll
                for (int k = 0; k < 8; k++) ov[k] = f2b(v[q * 8 + k] * inv);
                *reinterpret_cast<u16x8*>(o1 + base + q * 128) = ov;
            }
            o1[base + 384] = f2b(v[24] * inv);
        }
    }
}

// ============================================================================
// 2x bilinear resize (align-corners linspace), T16 bf16, C=64, 64x64 -> 128x128
// ============================================================================
__global__ __launch_bounds__(256)
void resize2x_t16(const ushort_t* __restrict__ in, ushort_t* __restrict__ out)
{
    int t = blockIdx.x * 256 + threadIdx.x;
    int cg = t & 7;
    int opx = t >> 3;
    int xo = opx & 127;
    int rest = opx >> 7;
    int yo = rest & 127;
    int b  = rest >> 7;
    float fy = (float)yo * 63.f / 127.f;
    float fx = (float)xo * 63.f / 127.f;
    int y0 = (int)fy, x0 = (int)fx;
    float wy = fy - (float)y0, wx = fx - (float)x0;
    int y1 = min(y0 + 1, 63), x1 = min(x0 + 1, 63);
    int qb = b * 4096;
#define RD(Y, X) (*reinterpret_cast<const bf16x8*>(in + \
    (unsigned)(((qb + (Y) * 64 + (X)) >> 4) * 1024) + cg * 128 + ((qb + (Y) * 64 + (X)) & 15) * 8))
    bf16x8 v00 = RD(y0, x0), v01 = RD(y0, x1), v10 = RD(y1, x0), v11 = RD(y1, x1);
#undef RD
    u16x8 o;
#pragma unroll
    for (int k = 0; k < 8; k++) {
        float l = b2f((ushort_t)v00[k]) * (1.f - wy) + b2f((ushort_t)v10[k]) * wy;
        float r = b2f((ushort_t)v01[k]) * (1.f - wy) + b2f((ushort_t)v11[k]) * wy;
        o[k] = f2b(l * (1.f - wx) + r * wx);
    }
    *reinterpret_cast<u16x8*>(out + (unsigned)(opx >> 4) * 1024 + cg * 128 + (opx & 15) * 8) = o;
}

// ============================================================================
// CARAFE combine (T16 bf16, C=64, H=W=128)
// ============================================================================
__global__ __launch_bounds__(256)
void carafe25(const ushort_t* __restrict__ wm, const ushort_t* __restrict__ xu,
              ushort_t* __restrict__ out)
{
    int t = blockIdx.x * 256 + threadIdx.x;
    int cg = t & 7;
    int px = t >> 3;
    int x = px & 127;
    int y = (px >> 7) & 127;
    const ushort_t* wp = wm + (unsigned)(px >> 4) * 512 + (px & 15) * 8;
    u16x8 r0 = *reinterpret_cast<const u16x8*>(wp);
    u16x8 r1 = *reinterpret_cast<const u16x8*>(wp + 128);
    u16x8 r2 = *reinterpret_cast<const u16x8*>(wp + 256);
    float v[25];
#pragma unroll
    for (int k = 0; k < 8; k++) v[k]      = b2f(r0[k]);
#pragma unroll
    for (int k = 0; k < 8; k++) v[8 + k]  = b2f(r1[k]);
#pragma unroll
    for (int k = 0; k < 8; k++) v[16 + k] = b2f(r2[k]);
    v[24] = b2f(wp[384]);

    float acc[8];
#pragma unroll
    for (int k = 0; k < 8; k++) acc[k] = 0.f;
#pragma unroll
    for (int i = 0; i < 5; i++) {
        int yy = y + 2 * i - 4;
#pragma unroll
        for (int j = 0; j < 5; j++) {
            int xx = x + 2 * j - 4;
            if (yy >= 0 && yy < 128 && xx >= 0 && xx < 128) {
                int q = px + (2 * i - 4) * 128 + (2 * j - 4);
                bf16x8 xv = *reinterpret_cast<const bf16x8*>(
                    xu + (unsigned)(q >> 4) * 1024 + cg * 128 + (q & 15) * 8);
                float wv = v[i * 5 + j];
#pragma unroll
                for (int k = 0; k < 8; k++)
                    acc[k] = fmaf(wv, b2f((ushort_t)xv[k]), acc[k]);
            }
        }
    }
    u16x8 o;
#pragma unroll
    for (int k = 0; k < 8; k++) o[k] = f2b(acc[k]);
    *reinterpret_cast<u16x8*>(out + (unsigned)(px >> 4) * 1024 + cg * 128 + (px & 15) * 8) = o;
}

// ============================================================================
extern "C" void kernel_launch(void* const* d_in, const int* in_sizes, int n_in,
                              void* d_out, int out_size, void* d_ws, size_t ws_size,
                              hipStream_t stream)
{
    const float* x_h      = (const float*)d_in[0];
    const float* x_l      = (const float*)d_in[1];
    const float* w_reduce = (const float*)d_in[2];
    const float* g_reduce = (const float*)d_in[3];
    const float* b_reduce = (const float*)d_in[4];
    const float* w1       = (const float*)d_in[5];
    const float* g1       = (const float*)d_in[6];
    const float* b1       = (const float*)d_in[7];
    const float* w2       = (const float*)d_in[8];
    const float* g2       = (const float*)d_in[9];
    const float* b2       = (const float*)d_in[10];
    const float* w_enc    = (const float*)d_in[11];
    const float* g_enc    = (const float*)d_in[12];
    const float* b_enc    = (const float*)d_in[13];
    const float* w_out1   = (const float*)d_in[14];
    const float* g_out1   = (const float*)d_in[15];
    const float* b_out1   = (const float*)d_in[16];
    const float* w_out2   = (const float*)d_in[17];
    const float* g_out2   = (const float*)d_in[18];
    const float* b_out2   = (const float*)d_in[19];

    ushort_t* ws0 = (ushort_t*)d_ws;

    const unsigned oXHC = OFF_R1;   // (16384, 256) T16
    const unsigned oC1  = OFF_R2;   // (16384, 64)
    const unsigned oXR  = OFF_R3;   // (16384, 64)
    const unsigned oX1  = OFF_R4;   // (65536, 64)
    const unsigned oXLC = OFF_R5;   // (65536, 128)
    const unsigned oX2  = OFF_R1;   // (65536, 64)   xh_c dead
    const unsigned oWM  = OFF_R6;   // (65536, 32)
    const unsigned oXU  = OFF_R4;   // (65536, 64)   x1 dead
    const unsigned oXB  = OFF_R1;   // (65536, 64)   x2 dead
    const unsigned oY1  = OFF_R4;   // (65536, 128)

    // 0) weights -> bf16 [kt][ci_oct][co][8] + zero page
    prep_weights<<<1872, 256, 0, stream>>>(w_reduce, w1, w2, w_enc, w_out1, w_out2, ws0);
    // 1) x_h -> T16 bf16
    nchw2t16<<<64, 256, 0, stream>>>(x_h, ws0 + oXHC, 256, 12, 16384);
    // 2) c1 = cbr1x1(xh_c, w1): M=16384 K=256 CO=64
    conv_lds<1, 64, 256, 0, 64, 32, 2, 0><<<dim3(256, 2), 256, 0, stream>>>(
        ws0, oXHC, 0u, E_BW1, g1, b1, 64, ws0 + oC1, 64, 12, 1);
    // 3) xr = cbr3x3(xh_c, w_reduce): M=16384 K=2304 CO=64
    conv_lds<9, 64, 256, 0, 64, 32, 1, 0><<<dim3(256, 2), 256, 0, stream>>>(
        ws0, oXHC, 0u, E_BWR, g_reduce, b_reduce, 64, ws0 + oXR, 64, 12, 1);
    // 4) x1 = resize2x(c1)
    resize2x_t16<<<2048, 256, 0, stream>>>(ws0 + oC1, ws0 + oX1);
    // 5) x_l -> T16 bf16
    nchw2t16<<<256, 256, 0, stream>>>(x_l, ws0 + oXLC, 128, 14, 65536);
    // 6) x2 = cbr1x1(xl_c, w2): M=65536 K=128 CO=64
    conv_lds<1, 128, 128, 0, 64, 32, 2, 0><<<dim3(512, 2), 256, 0, stream>>>(
        ws0, oXLC, 0u, E_BW2, g2, b2, 64, ws0 + oX2, 128, 14, 1);
    // 7) wm = conv3x3(concat(x1,x2), w_enc) + fused softmax-25 (EPI=2)
    conv_lds<9, 128, 64, 64, 32, 32, 1, 2><<<dim3(512, 1), 256, 0, stream>>>(
        ws0, oX1, oX2, E_BWE, g_enc, b_enc, 25, ws0 + oWM, 128, 14, 0);
    // 8) xu = resize2x(xr)
    resize2x_t16<<<2048, 256, 0, stream>>>(ws0 + oXR, ws0 + oXU);
    // 9) X = carafe(wm, xu)
    carafe25<<<2048, 256, 0, stream>>>(ws0 + oWM, ws0 + oXU, ws0 + oXB);
    // 10) y1 = cbr3x3(concat(X, xl_c), w_out1): CO=128, co split across grid.y
    conv_lds<9, 128, 64, 128, 128, 64, 1, 0><<<dim3(512, 2), 256, 0, stream>>>(
        ws0, oXB, oXLC, E_BWO1, g_out1, b_out1, 128, ws0 + oY1, 128, 14, 1);
    // 11) out = cbr1x1(y1, w_out2) -> d_out NCHW f32, co split across grid.y
    conv_lds<1, 128, 128, 0, 128, 64, 2, 1><<<dim3(512, 2), 256, 0, stream>>>(
        ws0, oY1, 0u, E_BWO2, g_out2, b_out2, 128, d_out, 128, 14, 1);
}

// Round 9
// 148.436 us; speedup vs baseline: 1.4210x; 1.0466x over previous
//
#include <hip/hip_runtime.h>
#include <math.h>

#define BNS 0.99999500003749981f  // 1/sqrt(1+1e-5)

typedef short          bf16x8  __attribute__((ext_vector_type(8)));
typedef float          f32x4   __attribute__((ext_vector_type(4)));
typedef unsigned short u16x8   __attribute__((ext_vector_type(8)));
typedef unsigned short u16x4   __attribute__((ext_vector_type(4)));
typedef unsigned short ushort_t;

__device__ inline ushort_t f2b(float f) {
    union { float f; unsigned int u; } x; x.f = f;
    unsigned int u = x.u;
    unsigned int r = (u + 0x7FFFu + ((u >> 16) & 1u)) >> 16;   // RNE
    return (ushort_t)r;
}
__device__ inline float b2f(ushort_t s) {
    union { unsigned int u; float f; } x; x.u = ((unsigned int)s) << 16;
    return x.f;
}

// async global->LDS, 16B per lane; LDS dest is wave-uniform base (+lane*16 by HW)
__device__ inline void glds16(const ushort_t* gp, void* lp) {
    __builtin_amdgcn_global_load_lds(
        (const __attribute__((address_space(1))) unsigned int*)gp,
        (__attribute__((address_space(3))) unsigned int*)lp, 16, 0, 0);
}

// counted waitcnt (T4): wait until <=N vmem outstanding; optional lgkm drain
template<int N, bool LG0>
__device__ __forceinline__ void wait_v() {
    static_assert(N >= 0 && N <= 8, "vmcnt literal table");
    if constexpr (LG0) {
        if constexpr (N == 0) asm volatile("s_waitcnt vmcnt(0) lgkmcnt(0)" ::: "memory");
        if constexpr (N == 2) asm volatile("s_waitcnt vmcnt(2) lgkmcnt(0)" ::: "memory");
        if constexpr (N == 3) asm volatile("s_waitcnt vmcnt(3) lgkmcnt(0)" ::: "memory");
        if constexpr (N == 4) asm volatile("s_waitcnt vmcnt(4) lgkmcnt(0)" ::: "memory");
        if constexpr (N == 5) asm volatile("s_waitcnt vmcnt(5) lgkmcnt(0)" ::: "memory");
        if constexpr (N == 6) asm volatile("s_waitcnt vmcnt(6) lgkmcnt(0)" ::: "memory");
        if constexpr (N == 7) asm volatile("s_waitcnt vmcnt(7) lgkmcnt(0)" ::: "memory");
        if constexpr (N == 8) asm volatile("s_waitcnt vmcnt(8) lgkmcnt(0)" ::: "memory");
    } else {
        if constexpr (N == 0) asm volatile("s_waitcnt vmcnt(0)" ::: "memory");
        if constexpr (N == 2) asm volatile("s_waitcnt vmcnt(2)" ::: "memory");
        if constexpr (N == 3) asm volatile("s_waitcnt vmcnt(3)" ::: "memory");
        if constexpr (N == 4) asm volatile("s_waitcnt vmcnt(4)" ::: "memory");
        if constexpr (N == 5) asm volatile("s_waitcnt vmcnt(5)" ::: "memory");
        if constexpr (N == 6) asm volatile("s_waitcnt vmcnt(6)" ::: "memory");
        if constexpr (N == 7) asm volatile("s_waitcnt vmcnt(7)" ::: "memory");
        if constexpr (N == 8) asm volatile("s_waitcnt vmcnt(8)" ::: "memory");
    }
}

// ---------------- workspace element offsets (ushort units) ----------------
#define E_BWR   0u
#define E_BW1   147456u
#define E_BW2   163840u
#define E_BWE   172032u
#define E_BWO1  208896u
#define E_BWO2  430080u
#define E_ZP    446464u      // 64KB zero page (32768 el)
#define OFF_R1  524288u      // 8MB region   (byte 1048576)
#define OFF_R4  4718592u     // 8MB          (byte 9437184)
#define OFF_R2  8912896u     // 2MB          (byte 17825792)
#define OFF_R3  9961472u     // 2MB          (byte 19922944)
#define OFF_R6  11010048u    // 4MB          (byte 22020096)
#define OFF_R5  13107200u    // 16MB         (byte 26214400) end byte 42991616

// T16 activation layout: element (px, ci) of a CI-channel tensor lives at
//   (px>>4)*(CI*16) + (ci>>3)*128 + (px&15)*8 + (ci&7)

// ============================================================================
// Weight prep: OIHW f32 -> [kt][ci_oct(4)][co][8] bf16.
// ============================================================================
__device__ inline void wseg3(int idx, const float* src, ushort_t* dst,
                             int TAPS, int COT, int CIT, int CO_real) {
    int kt  = idx / (COT * 32);
    int r   = idx - kt * (COT * 32);
    int q   = r / (COT * 8);
    int r2  = r - q * (COT * 8);
    int co  = r2 >> 3;
    int e   = r2 & 7;
    int KCT = CIT >> 5;
    int tap = kt / KCT, j = kt - tap * KCT;
    int ci  = j * 32 + q * 8 + e;
    float v = (co < CO_real) ? src[((size_t)co * CIT + ci) * TAPS + tap] : 0.f;
    dst[idx] = f2b(v);
}

__global__ __launch_bounds__(256)
void prep_weights(const float* wr, const float* w1, const float* w2,
                  const float* we, const float* wo1, const float* wo2,
                  ushort_t* ws0)
{
    int idx = blockIdx.x * 256 + threadIdx.x;
    const int n0 = 9*64*256;    // reduce   147456
    const int n1 = 64*256;      // w1        16384
    const int n2 = 64*128;      // w2         8192
    const int n3 = 9*32*128;    // enc       36864
    const int n4 = 9*128*192;   // out1     221184
    const int n5 = 128*128;     // out2      16384
    if (idx < n0) { wseg3(idx, wr,  ws0 + E_BWR,  9, 64, 256, 64);  return; } idx -= n0;
    if (idx < n1) { wseg3(idx, w1,  ws0 + E_BW1,  1, 64, 256, 64);  return; } idx -= n1;
    if (idx < n2) { wseg3(idx, w2,  ws0 + E_BW2,  1, 64, 128, 64);  return; } idx -= n2;
    if (idx < n3) { wseg3(idx, we,  ws0 + E_BWE,  9, 32, 128, 25);  return; } idx -= n3;
    if (idx < n4) { wseg3(idx, wo1, ws0 + E_BWO1, 9, 128, 192, 128); return; } idx -= n4;
    if (idx < n5) { wseg3(idx, wo2, ws0 + E_BWO2, 1, 128, 128, 128); return; } idx -= n5;
    if (idx < 32768) ws0[E_ZP + idx] = 0;   // zero page
}

// ============================================================================
// NCHW f32 -> T16 bf16
// ============================================================================
__global__ __launch_bounds__(256)
void nchw2t16(const float* __restrict__ in, ushort_t* __restrict__ out,
              int C, int LHW, int npx)
{
    int px = blockIdx.x * 256 + threadIdx.x;
    if (px >= npx) return;
    int HW = 1 << LHW;
    int b = px >> LHW, phw = px & (HW - 1);
    const float* src = in + (size_t)b * C * HW + phw;
    unsigned base = (unsigned)(px >> 4) * (C * 16) + (unsigned)(px & 15) * 8;
    for (int c0 = 0; c0 < C; c0 += 8) {
        u16x8 o;
#pragma unroll
        for (int j = 0; j < 8; j++) o[j] = f2b(src[(size_t)(c0 + j) * HW]);
        *reinterpret_cast<u16x8*>(out + base + (c0 >> 3) * 128) = o;
    }
}

// ============================================================================
// LDS-staged implicit-GEMM conv, counted-vmcnt double-buffer (T4), dy-major
// phases, full-CO blocks (max ds_read reuse: MF=4/NF=4 on the big convs),
// s_setprio(1) around the MFMA cluster (T5).
// Pipeline: stage(0); loop p { stage(p+1); s_waitcnt vmcnt(SS); s_barrier;
//                              MFMA(p); s_barrier }  (never drains in-loop)
// Block = one image row (BM=W px) x BN co.  XCD swizzle over blockIdx.x only.
// EPI: 0 = T16 bf16 out, 1 = NCHW f32 out, 2 = T16 bf16 + fused softmax-25.
// ============================================================================
template<int TAPS, int BM, int CIA, int CIB, int COT, int BN, int G, int EPI>
__global__ __launch_bounds__(256)
void conv_lds(const ushort_t* __restrict__ ws0,
              unsigned offA, unsigned offB, unsigned offW,
              const float* __restrict__ g, const float* __restrict__ bia,
              int COclamp, void* __restrict__ outp,
              int H, int LHW, int relu)
{
    constexpr int KCA = CIA / 32, KCB = CIB / 32;
    constexpr int KCT = KCA + KCB;
    constexpr int NW  = (TAPS == 9) ? 3 : G;       // weight tiles per phase
    constexpr int ACP = (TAPS == 9) ? 1 : G;       // act 32ci-chunks per phase
    constexpr int NPH = (TAPS == 9) ? 3 * KCT : KCT / G;
    constexpr int MF = BM / 32, NF = BN / 32;      // per-wave fragments
    constexpr int ACHUNK = BM / 16;                // 1KB units per act chunk
    constexpr int A4 = ACP * ACHUNK / 4;           // act loads per wave/phase
    constexpr int WUNIT = BN / 16;                 // 1KB units per wt tile
    constexpr int TWU = NW * WUNIT;
    constexpr int W4 = (TWU + 3) / 4;              // wt loads per wave/phase
    constexpr int SS = A4 + W4;                    // uniform loads/wave/phase
    constexpr int WOFF = ACP * BM * 64;            // bytes: act region size
    constexpr int ZS   = WOFF + NW * BN * 64;      // per-buffer zero slot
    constexpr int BUF  = ZS + 16;
    constexpr int LBN3 = (BN == 128) ? 10 : (BN == 64) ? 9 : 8;  // log2(BN*8)
    __shared__ __align__(16) char lds[2 * BUF];

    // XCD-chunked swizzle: real XCD = blockIdx.x % 8 (gridDim.x % 8 == 0).
    const unsigned nx = gridDim.x, ox = blockIdx.x;
    const unsigned qq = nx >> 3, xcd = ox & 7, k0 = ox >> 3;
    const unsigned bx = xcd * qq + k0;
    const int co_blk = blockIdx.y * BN;

    const int tid = threadIdx.x, w = tid >> 6, lane = tid & 63;
    const int l15 = lane & 15, lhi = lane >> 4;
    const int wpx = (w & 1) * (BM / 2), cw0 = (w >> 1) * (BN / 2);
    const int yb = (int)(bx & (unsigned)(H - 1));      // BM == W: block = row yb
    const unsigned pxc0 = bx * ACHUNK;

    // per-buffer zero slots (drained by phase-0's lgkmcnt(0))
    if (tid < 8) *(unsigned*)(lds + (tid >> 2) * BUF + ZS + (tid & 3) * 4) = 0u;

    // act fragment LDS offsets per dx (relative to act slot base)
    int aA[3][MF];
#pragma unroll
    for (int dxi = 0; dxi < 3; ++dxi) {
        const int dx = dxi - 1;
#pragma unroll
        for (int mf = 0; mf < MF; ++mf) {
            int pr = wpx + mf * 16 + l15 + dx;
            bool ok = (TAPS == 1) ? true : (pr >= 0 && pr < BM);
            aA[dxi][mf] = ok ? (((pr >> 4) << 10) + (lhi << 8) + ((pr & 15) << 4)) : ZS;
        }
    }
    int wA[NF];
#pragma unroll
    for (int nf = 0; nf < NF; ++nf)
        wA[nf] = (lhi * BN + cw0 + nf * 16 + l15) * 16;  // within a wt tile

    f32x4 acc[NF][MF];
#pragma unroll
    for (int nf = 0; nf < NF; ++nf)
#pragma unroll
        for (int mf = 0; mf < MF; ++mf)
            acc[nf][mf] = (f32x4){0.f, 0.f, 0.f, 0.f};

    auto stage = [&](int p, int bsel) {
        char* lb = lds + bsel * BUF;
        if constexpr (TAPS == 9) {
            const int dyi = p / KCT, kc = p - dyi * KCT;
            const int dy = dyi - 1;
            const bool isA = (kc < KCA);
            const int kcs = isA ? kc : kc - KCA;
            const int CI  = isA ? CIA : CIB;
            const unsigned offS = isA ? offA : offB;
            const bool rowv = (yb + dy >= 0) && (yb + dy < H);
#pragma unroll
            for (int i = 0; i < A4; ++i) {
                int u = i * 4 + w;
                unsigned s = rowv
                    ? offS + (unsigned)((int)pxc0 + dy * ACHUNK + u) * (unsigned)(CI * 16)
                           + (unsigned)(kcs * 512) + (unsigned)(lane * 8)
                    : E_ZP + (unsigned)(lane * 8);
                glds16(ws0 + s, lb + u * 1024);
            }
#pragma unroll
            for (int i = 0; i < W4; ++i) {
                int t3 = (i * 4 + w) % TWU;
                int tl = t3 / WUNIT, uu = t3 - tl * WUNIT;
                unsigned wsrc = offW + (unsigned)((dyi * 3 + tl) * KCT + kc)
                                       * (unsigned)(COT * 32);
                int el  = uu * 512 + lane * 8;
                int q   = el >> LBN3;
                int col = (el & ((1 << LBN3) - 1)) >> 3;
                glds16(ws0 + wsrc + q * (COT * 8) + (co_blk + col) * 8,
                       lb + WOFF + tl * (BN * 64) + uu * 1024);
            }
        } else {
#pragma unroll
            for (int i = 0; i < A4; ++i) {
                int lin = i * 4 + w;
                int gc = lin / ACHUNK, u = lin - gc * ACHUNK;
                unsigned s = offA + (unsigned)(pxc0 + u) * (unsigned)(CIA * 16)
                           + (unsigned)((p * G + gc) * 512) + (unsigned)(lane * 8);
                glds16(ws0 + s, lb + gc * (BM * 64) + u * 1024);
            }
#pragma unroll
            for (int i = 0; i < W4; ++i) {
                int t3 = (i * 4 + w) % TWU;
                int tl = t3 / WUNIT, uu = t3 - tl * WUNIT;
                unsigned wsrc = offW + (unsigned)(p * G + tl) * (unsigned)(COT * 32);
                int el  = uu * 512 + lane * 8;
                int q   = el >> LBN3;
                int col = (el & ((1 << LBN3) - 1)) >> 3;
                glds16(ws0 + wsrc + q * (COT * 8) + (co_blk + col) * 8,
                       lb + WOFF + tl * (BN * 64) + uu * 1024);
            }
        }
    };

    auto step = [&](int p, int bsel) {
        const char* lb = lds + bsel * BUF;
        __builtin_amdgcn_s_setprio(1);                  // T5: favor MFMA waves
#pragma unroll
        for (int t = 0; t < NW; ++t) {
            const int dxi = (TAPS == 9) ? t : 1;
            const char* ab = lb + ((TAPS == 9) ? 0 : t * (BM * 64));
            bf16x8 af[MF], wf[NF];
#pragma unroll
            for (int mf = 0; mf < MF; ++mf)
                af[mf] = *reinterpret_cast<const bf16x8*>(ab + aA[dxi][mf]);
#pragma unroll
            for (int nf = 0; nf < NF; ++nf)
                wf[nf] = *reinterpret_cast<const bf16x8*>(
                    lb + WOFF + t * (BN * 64) + wA[nf]);
#pragma unroll
            for (int nf = 0; nf < NF; ++nf)
#pragma unroll
                for (int mf = 0; mf < MF; ++mf)
                    acc[nf][mf] = __builtin_amdgcn_mfma_f32_16x16x32_bf16(
                        wf[nf], af[mf], acc[nf][mf], 0, 0, 0);
        }
        __builtin_amdgcn_s_setprio(0);
    };

    stage(0, 0);
#pragma unroll
    for (int p = 0; p < NPH; ++p) {
        if (p + 1 < NPH) stage(p + 1, (p + 1) & 1);   // keep SS loads in flight
        if (p == 0) { if (p + 1 < NPH) wait_v<SS, true >(); else wait_v<0, true >(); }
        else        { if (p + 1 < NPH) wait_v<SS, false>(); else wait_v<0, false>(); }
        __builtin_amdgcn_s_barrier();
        __builtin_amdgcn_sched_barrier(0);
        step(p, p & 1);
        __builtin_amdgcn_sched_barrier(0);
        if (p + 1 < NPH) __builtin_amdgcn_s_barrier();
    }

    // ---------------- epilogue ----------------
    if constexpr (EPI == 0) {
        ushort_t* o1 = (ushort_t*)outp;
#pragma unroll
        for (int nf = 0; nf < NF; ++nf) {
            const int cg = co_blk + cw0 + nf * 16 + (lhi << 2);  // first of 4 co
            float sc[4], bi[4];
#pragma unroll
            for (int r = 0; r < 4; r++) {
                int c = min(cg + r, COclamp - 1);
                sc[r] = g[c] * BNS; bi[r] = bia[c];
            }
#pragma unroll
            for (int mf = 0; mf < MF; ++mf) {
                f32x4 a = acc[nf][mf];
                u16x4 ov;
#pragma unroll
                for (int r = 0; r < 4; r++) {
                    float v = fmaf(a[r], sc[r], bi[r]);
                    if (relu) v = fmaxf(v, 0.f);
                    ov[r] = f2b(v);
                }
                int px = (int)bx * BM + wpx + mf * 16 + l15;
                unsigned off = (unsigned)(px >> 4) * (COT * 16)
                             + (unsigned)(cg >> 3) * 128
                             + (unsigned)(px & 15) * 8 + (unsigned)(cg & 7);
                *reinterpret_cast<u16x4*>(o1 + off) = ov;
            }
        }
    } else if constexpr (EPI == 1) {
        float* o1 = (float*)outp;
        const int HW = 1 << LHW;
#pragma unroll
        for (int nf = 0; nf < NF; ++nf) {
            const int cg = co_blk + cw0 + nf * 16 + (lhi << 2);
            float sc[4], bi[4];
#pragma unroll
            for (int r = 0; r < 4; r++) {
                int c = min(cg + r, COclamp - 1);
                sc[r] = g[c] * BNS; bi[r] = bia[c];
            }
#pragma unroll
            for (int mf = 0; mf < MF; ++mf) {
                int px = (int)bx * BM + wpx + mf * 16 + l15;
                int b = px >> LHW, phw = px & (HW - 1);
#pragma unroll
                for (int r = 0; r < 4; r++) {
                    float v = fmaf(acc[nf][mf][r], sc[r], bi[r]);
                    if (relu) v = fmaxf(v, 0.f);
                    o1[((size_t)(b * COT + cg + r)) * HW + phw] = v;
                }
            }
        }
    } else {
        // EPI == 2: fused channel-25 softmax (BN == COT == 32, one block = row)
        __syncthreads();                     // all waves done with staging LDS
        float* sf = (float*)lds;             // [32 co][136 f32]
#pragma unroll
        for (int mf = 0; mf < MF; ++mf) {
            const int cg = cw0 + (lhi << 2);
            int pxl = wpx + mf * 16 + l15;
            f32x4 a = acc[0][mf];
#pragma unroll
            for (int r = 0; r < 4; r++) {
                int c = min(cg + r, COclamp - 1);
                sf[(cg + r) * 136 + pxl] = fmaf(a[r], g[c] * BNS, bia[c]);
            }
        }
        __syncthreads();
        if (tid < BM) {
            int gpx = (int)bx * BM + tid;
            float v[25];
#pragma unroll
            for (int c = 0; c < 25; ++c) v[c] = sf[c * 136 + tid];
            float m = v[0];
#pragma unroll
            for (int c = 1; c < 25; ++c) m = fmaxf(m, v[c]);
            float s = 0.f;
#pragma unroll
            for (int c = 0; c < 25; ++c) { v[c] = __expf(v[c] - m); s += v[c]; }
            float inv = 1.f / s;
            ushort_t* o1 = (ushort_t*)outp;
            unsigned base = (unsigned)(gpx >> 4) * (COT * 16) + (unsigned)(gpx & 15) * 8;
#pragma unroll
            for (int q = 0; q < 3; ++q) {
                u16x8 ov;
#pragma unroll
                for (int k = 0; k < 8; k++) ov[k] = f2b(v[q * 8 + k] * inv);
                *reinterpret_cast<u16x8*>(o1 + base + q * 128) = ov;
            }
            o1[base + 384] = f2b(v[24] * inv);
        }
    }
}

// ============================================================================
// 2x bilinear resize (align-corners linspace), T16 bf16, C=64, 64x64 -> 128x128
// ============================================================================
__global__ __launch_bounds__(256)
void resize2x_t16(const ushort_t* __restrict__ in, ushort_t* __restrict__ out)
{
    int t = blockIdx.x * 256 + threadIdx.x;
    int cg = t & 7;
    int opx = t >> 3;
    int xo = opx & 127;
    int rest = opx >> 7;
    int yo = rest & 127;
    int b  = rest >> 7;
    float fy = (float)yo * 63.f / 127.f;
    float fx = (float)xo * 63.f / 127.f;
    int y0 = (int)fy, x0 = (int)fx;
    float wy = fy - (float)y0, wx = fx - (float)x0;
    int y1 = min(y0 + 1, 63), x1 = min(x0 + 1, 63);
    int qb = b * 4096;
#define RD(Y, X) (*reinterpret_cast<const bf16x8*>(in + \
    (unsigned)(((qb + (Y) * 64 + (X)) >> 4) * 1024) + cg * 128 + ((qb + (Y) * 64 + (X)) & 15) * 8))
    bf16x8 v00 = RD(y0, x0), v01 = RD(y0, x1), v10 = RD(y1, x0), v11 = RD(y1, x1);
#undef RD
    u16x8 o;
#pragma unroll
    for (int k = 0; k < 8; k++) {
        float l = b2f((ushort_t)v00[k]) * (1.f - wy) + b2f((ushort_t)v10[k]) * wy;
        float r = b2f((ushort_t)v01[k]) * (1.f - wy) + b2f((ushort_t)v11[k]) * wy;
        o[k] = f2b(l * (1.f - wx) + r * wx);
    }
    *reinterpret_cast<u16x8*>(out + (unsigned)(opx >> 4) * 1024 + cg * 128 + (opx & 15) * 8) = o;
}

// ============================================================================
// CARAFE combine (T16 bf16, C=64, H=W=128)
// ============================================================================
__global__ __launch_bounds__(256)
void carafe25(const ushort_t* __restrict__ wm, const ushort_t* __restrict__ xu,
              ushort_t* __restrict__ out)
{
    int t = blockIdx.x * 256 + threadIdx.x;
    int cg = t & 7;
    int px = t >> 3;
    int x = px & 127;
    int y = (px >> 7) & 127;
    const ushort_t* wp = wm + (unsigned)(px >> 4) * 512 + (px & 15) * 8;
    u16x8 r0 = *reinterpret_cast<const u16x8*>(wp);
    u16x8 r1 = *reinterpret_cast<const u16x8*>(wp + 128);
    u16x8 r2 = *reinterpret_cast<const u16x8*>(wp + 256);
    float v[25];
#pragma unroll
    for (int k = 0; k < 8; k++) v[k]      = b2f(r0[k]);
#pragma unroll
    for (int k = 0; k < 8; k++) v[8 + k]  = b2f(r1[k]);
#pragma unroll
    for (int k = 0; k < 8; k++) v[16 + k] = b2f(r2[k]);
    v[24] = b2f(wp[384]);

    float acc[8];
#pragma unroll
    for (int k = 0; k < 8; k++) acc[k] = 0.f;
#pragma unroll
    for (int i = 0; i < 5; i++) {
        int yy = y + 2 * i - 4;
#pragma unroll
        for (int j = 0; j < 5; j++) {
            int xx = x + 2 * j - 4;
            if (yy >= 0 && yy < 128 && xx >= 0 && xx < 128) {
                int q = px + (2 * i - 4) * 128 + (2 * j - 4);
                bf16x8 xv = *reinterpret_cast<const bf16x8*>(
                    xu + (unsigned)(q >> 4) * 1024 + cg * 128 + (q & 15) * 8);
                float wv = v[i * 5 + j];
#pragma unroll
                for (int k = 0; k < 8; k++)
                    acc[k] = fmaf(wv, b2f((ushort_t)xv[k]), acc[k]);
            }
        }
    }
    u16x8 o;
#pragma unroll
    for (int k = 0; k < 8; k++) o[k] = f2b(acc[k]);
    *reinterpret_cast<u16x8*>(out + (unsigned)(px >> 4) * 1024 + cg * 128 + (px & 15) * 8) = o;
}

// ============================================================================
extern "C" void kernel_launch(void* const* d_in, const int* in_sizes, int n_in,
                              void* d_out, int out_size, void* d_ws, size_t ws_size,
                              hipStream_t stream)
{
    const float* x_h      = (const float*)d_in[0];
    const float* x_l      = (const float*)d_in[1];
    const float* w_reduce = (const float*)d_in[2];
    const float* g_reduce = (const float*)d_in[3];
    const float* b_reduce = (const float*)d_in[4];
    const float* w1       = (const float*)d_in[5];
    const float* g1       = (const float*)d_in[6];
    const float* b1       = (const float*)d_in[7];
    const float* w2       = (const float*)d_in[8];
    const float* g2       = (const float*)d_in[9];
    const float* b2       = (const float*)d_in[10];
    const float* w_enc    = (const float*)d_in[11];
    const float* g_enc    = (const float*)d_in[12];
    const float* b_enc    = (const float*)d_in[13];
    const float* w_out1   = (const float*)d_in[14];
    const float* g_out1   = (const float*)d_in[15];
    const float* b_out1   = (const float*)d_in[16];
    const float* w_out2   = (const float*)d_in[17];
    const float* g_out2   = (const float*)d_in[18];
    const float* b_out2   = (const float*)d_in[19];

    ushort_t* ws0 = (ushort_t*)d_ws;

    const unsigned oXHC = OFF_R1;   // (16384, 256) T16
    const unsigned oC1  = OFF_R2;   // (16384, 64)
    const unsigned oXR  = OFF_R3;   // (16384, 64)
    const unsigned oX1  = OFF_R4;   // (65536, 64)
    const unsigned oXLC = OFF_R5;   // (65536, 128)
    const unsigned oX2  = OFF_R1;   // (65536, 64)   xh_c dead
    const unsigned oWM  = OFF_R6;   // (65536, 32)
    const unsigned oXU  = OFF_R4;   // (65536, 64)   x1 dead
    const unsigned oXB  = OFF_R1;   // (65536, 64)   x2 dead
    const unsigned oY1  = OFF_R4;   // (65536, 128)

    // 0) weights -> bf16 [kt][ci_oct][co][8] + zero page
    prep_weights<<<1872, 256, 0, stream>>>(w_reduce, w1, w2, w_enc, w_out1, w_out2, ws0);
    // 1) x_h -> T16 bf16
    nchw2t16<<<64, 256, 0, stream>>>(x_h, ws0 + oXHC, 256, 12, 16384);
    // 2) c1 = cbr1x1(xh_c, w1): M=16384 K=256 CO=64  (full-CO block)
    conv_lds<1, 64, 256, 0, 64, 64, 2, 0><<<dim3(256, 1), 256, 0, stream>>>(
        ws0, oXHC, 0u, E_BW1, g1, b1, 64, ws0 + oC1, 64, 12, 1);
    // 3) xr = cbr3x3(xh_c, w_reduce): M=16384 K=2304 CO=64  (full-CO block)
    conv_lds<9, 64, 256, 0, 64, 64, 1, 0><<<dim3(256, 1), 256, 0, stream>>>(
        ws0, oXHC, 0u, E_BWR, g_reduce, b_reduce, 64, ws0 + oXR, 64, 12, 1);
    // 4) x1 = resize2x(c1)
    resize2x_t16<<<2048, 256, 0, stream>>>(ws0 + oC1, ws0 + oX1);
    // 5) x_l -> T16 bf16
    nchw2t16<<<256, 256, 0, stream>>>(x_l, ws0 + oXLC, 128, 14, 65536);
    // 6) x2 = cbr1x1(xl_c, w2): M=65536 K=128 CO=64  (full-CO block)
    conv_lds<1, 128, 128, 0, 64, 64, 2, 0><<<dim3(512, 1), 256, 0, stream>>>(
        ws0, oXLC, 0u, E_BW2, g2, b2, 64, ws0 + oX2, 128, 14, 1);
    // 7) wm = conv3x3(concat(x1,x2), w_enc) + fused softmax-25 (EPI=2)
    conv_lds<9, 128, 64, 64, 32, 32, 1, 2><<<dim3(512, 1), 256, 0, stream>>>(
        ws0, oX1, oX2, E_BWE, g_enc, b_enc, 25, ws0 + oWM, 128, 14, 0);
    // 8) xu = resize2x(xr)
    resize2x_t16<<<2048, 256, 0, stream>>>(ws0 + oXR, ws0 + oXU);
    // 9) X = carafe(wm, xu)
    carafe25<<<2048, 256, 0, stream>>>(ws0 + oWM, ws0 + oXU, ws0 + oXB);
    // 10) y1 = cbr3x3(concat(X, xl_c), w_out1): CO=128, full-CO (MF=4/NF=4)
    conv_lds<9, 128, 64, 128, 128, 128, 1, 0><<<dim3(512, 1), 256, 0, stream>>>(
        ws0, oXB, oXLC, E_BWO1, g_out1, b_out1, 128, ws0 + oY1, 128, 14, 1);
    // 11) out = cbr1x1(y1, w_out2) -> d_out NCHW f32, full-CO (MF=4/NF=4)
    conv_lds<1, 128, 128, 0, 128, 128, 2, 1><<<dim3(512, 1), 256, 0, stream>>>(
        ws0, oY1, 0u, E_BWO2, g_out2, b_out2, 128, d_out, 128, 14, 1);
}

// Round 10
// 135.565 us; speedup vs baseline: 1.5559x; 1.0949x over previous
//
#include <hip/hip_runtime.h>
#include <math.h>

#define BNS 0.99999500003749981f  // 1/sqrt(1+1e-5)

typedef short          bf16x8  __attribute__((ext_vector_type(8)));
typedef float          f32x4   __attribute__((ext_vector_type(4)));
typedef unsigned short u16x8   __attribute__((ext_vector_type(8)));
typedef unsigned short u16x4   __attribute__((ext_vector_type(4)));
typedef unsigned short ushort_t;

__device__ inline ushort_t f2b(float f) {
    union { float f; unsigned int u; } x; x.f = f;
    unsigned int u = x.u;
    unsigned int r = (u + 0x7FFFu + ((u >> 16) & 1u)) >> 16;   // RNE
    return (ushort_t)r;
}
__device__ inline float b2f(ushort_t s) {
    union { unsigned int u; float f; } x; x.u = ((unsigned int)s) << 16;
    return x.f;
}

// async global->LDS, 16B per lane; LDS dest is wave-uniform base (+lane*16 by HW)
__device__ inline void glds16(const ushort_t* gp, void* lp) {
    __builtin_amdgcn_global_load_lds(
        (const __attribute__((address_space(1))) unsigned int*)gp,
        (__attribute__((address_space(3))) unsigned int*)lp, 16, 0, 0);
}

// counted waitcnt (T4): wait until <=N vmem outstanding; optional lgkm drain
template<int N, bool LG0>
__device__ __forceinline__ void wait_v() {
    static_assert(N >= 0 && N <= 16, "vmcnt literal table");
    if constexpr (LG0) {
        if constexpr (N == 0)  asm volatile("s_waitcnt vmcnt(0) lgkmcnt(0)" ::: "memory");
        if constexpr (N == 3)  asm volatile("s_waitcnt vmcnt(3) lgkmcnt(0)" ::: "memory");
        if constexpr (N == 4)  asm volatile("s_waitcnt vmcnt(4) lgkmcnt(0)" ::: "memory");
        if constexpr (N == 6)  asm volatile("s_waitcnt vmcnt(6) lgkmcnt(0)" ::: "memory");
        if constexpr (N == 8)  asm volatile("s_waitcnt vmcnt(8) lgkmcnt(0)" ::: "memory");
    } else {
        if constexpr (N == 0)  asm volatile("s_waitcnt vmcnt(0)" ::: "memory");
        if constexpr (N == 3)  asm volatile("s_waitcnt vmcnt(3)" ::: "memory");
        if constexpr (N == 4)  asm volatile("s_waitcnt vmcnt(4)" ::: "memory");
        if constexpr (N == 6)  asm volatile("s_waitcnt vmcnt(6)" ::: "memory");
        if constexpr (N == 8)  asm volatile("s_waitcnt vmcnt(8)" ::: "memory");
    }
}

// ---------------- workspace element offsets (ushort units) ----------------
#define E_BWR   0u
#define E_BW1   147456u
#define E_BW2   163840u
#define E_BWE   172032u
#define E_BWO1  208896u
#define E_BWO2  430080u
#define E_ZP    446464u      // 64KB zero page (32768 el)
#define OFF_R1  524288u      // 8MB region   (byte 1048576)
#define OFF_R4  4718592u     // 8MB          (byte 9437184)
#define OFF_R2  8912896u     // 2MB          (byte 17825792)
#define OFF_R3  9961472u     // 2MB          (byte 19922944)
#define OFF_R6  11010048u    // 4MB          (byte 22020096)
#define OFF_R5  13107200u    // 16MB         (byte 26214400) end byte 42991616

// T16 activation layout: element (px, ci) of a CI-channel tensor lives at
//   (px>>4)*(CI*16) + (ci>>3)*128 + (px&15)*8 + (ci&7)

// ============================================================================
// prep_all: weight repack (OIHW f32 -> [kt][ci_oct][co][8] bf16) + zero page
//           + both NCHW->T16 activation conversions, one dispatch.
// ============================================================================
__device__ inline void wseg3(int idx, const float* src, ushort_t* dst,
                             int TAPS, int COT, int CIT, int CO_real) {
    int kt  = idx / (COT * 32);
    int r   = idx - kt * (COT * 32);
    int q   = r / (COT * 8);
    int r2  = r - q * (COT * 8);
    int co  = r2 >> 3;
    int e   = r2 & 7;
    int KCT = CIT >> 5;
    int tap = kt / KCT, j = kt - tap * KCT;
    int ci  = j * 32 + q * 8 + e;
    float v = (co < CO_real) ? src[((size_t)co * CIT + ci) * TAPS + tap] : 0.f;
    dst[idx] = f2b(v);
}

__device__ inline void cvt_t16(const float* __restrict__ in,
                               ushort_t* __restrict__ out,
                               int C, int LHW, int px, int npx) {
    if (px >= npx) return;
    int HW = 1 << LHW;
    int b = px >> LHW, phw = px & (HW - 1);
    const float* src = in + (size_t)b * C * HW + phw;
    unsigned base = (unsigned)(px >> 4) * (C * 16) + (unsigned)(px & 15) * 8;
    for (int c0 = 0; c0 < C; c0 += 8) {
        u16x8 o;
#pragma unroll
        for (int j = 0; j < 8; j++) o[j] = f2b(src[(size_t)(c0 + j) * HW]);
        *reinterpret_cast<u16x8*>(out + base + (c0 >> 3) * 128) = o;
    }
}

__global__ __launch_bounds__(256)
void prep_all(const float* wr, const float* w1, const float* w2,
              const float* we, const float* wo1, const float* wo2,
              const float* xh, const float* xl, ushort_t* ws0)
{
    int bx = blockIdx.x;
    int tid = threadIdx.x;
    if (bx < 1872) {
        int idx = bx * 256 + tid;
        const int n0 = 9*64*256;    // reduce   147456
        const int n1 = 64*256;      // w1        16384
        const int n2 = 64*128;      // w2         8192
        const int n3 = 9*32*128;    // enc       36864
        const int n4 = 9*128*192;   // out1     221184
        const int n5 = 128*128;     // out2      16384
        if (idx < n0) { wseg3(idx, wr,  ws0 + E_BWR,  9, 64, 256, 64);  return; } idx -= n0;
        if (idx < n1) { wseg3(idx, w1,  ws0 + E_BW1,  1, 64, 256, 64);  return; } idx -= n1;
        if (idx < n2) { wseg3(idx, w2,  ws0 + E_BW2,  1, 64, 128, 64);  return; } idx -= n2;
        if (idx < n3) { wseg3(idx, we,  ws0 + E_BWE,  9, 32, 128, 25);  return; } idx -= n3;
        if (idx < n4) { wseg3(idx, wo1, ws0 + E_BWO1, 9, 128, 192, 128); return; } idx -= n4;
        if (idx < n5) { wseg3(idx, wo2, ws0 + E_BWO2, 1, 128, 128, 128); return; } idx -= n5;
        if (idx < 32768) ws0[E_ZP + idx] = 0;   // zero page
        return;
    }
    bx -= 1872;
    if (bx < 64) { cvt_t16(xh, ws0 + OFF_R1, 256, 12, bx * 256 + tid, 16384); return; }
    bx -= 64;
    cvt_t16(xl, ws0 + OFF_R5, 128, 14, bx * 256 + tid, 65536);
}

// ============================================================================
// LDS-staged implicit-GEMM conv, counted-vmcnt DEP-buffer pipeline (T4),
// dy-major phases, s_setprio around MFMA (T5), WSX-way px wave split.
//  3x3: phase = (dy, 32ci-chunk): 1 act row-chunk + 3 dx weight tiles.
//  1x1: phase = G consecutive 32ci-chunks.
// Pipeline keeps (DEP-1) phases of loads in flight across barriers.
// Block = one image row (BM=W px) x BN co. XCD swizzle over blockIdx.x only.
// EPI: 0 = T16 bf16 out, 1 = NCHW f32 out, 2 = T16 bf16 + fused softmax-25.
// ============================================================================
template<int TAPS, int BM, int CIA, int CIB, int COT, int BN, int G,
         int WSX, int DEP, int EPI>
__global__ __launch_bounds__(256)
void conv_lds(const ushort_t* __restrict__ ws0,
              unsigned offA, unsigned offB, unsigned offW,
              const float* __restrict__ g, const float* __restrict__ bia,
              int COclamp, void* __restrict__ outp,
              int H, int LHW, int relu)
{
    constexpr int KCA = CIA / 32, KCB = CIB / 32;
    constexpr int KCT = KCA + KCB;
    constexpr int NW  = (TAPS == 9) ? 3 : G;       // weight tiles per phase
    constexpr int ACP = (TAPS == 9) ? 1 : G;       // act 32ci-chunks per phase
    constexpr int NPH = (TAPS == 9) ? 3 * KCT : KCT / G;
    constexpr int WSY = 4 / WSX;
    constexpr int MF = BM / WSX / 16;              // px frags per wave
    constexpr int NF = BN / WSY / 16;              // co frags per wave
    constexpr int ACHUNK = BM / 16;                // 1KB units per act chunk
    constexpr int A4 = (ACP * ACHUNK + 3) / 4;     // act loads per wave/phase
    constexpr int WUNIT = BN / 16;                 // 1KB units per wt tile
    constexpr int TWU = NW * WUNIT;
    constexpr int W4 = (TWU + 3) / 4;              // wt loads per wave/phase
    constexpr int SS = A4 + W4;                    // uniform loads/wave/phase
    constexpr int WOFF = ACP * BM * 64;            // bytes: act region size
    constexpr int ZS   = WOFF + NW * BN * 64;      // per-buffer zero slot
    constexpr int BUF  = ZS + 16;
    constexpr int LBN3 = (BN == 128) ? 10 : (BN == 64) ? 9 : 8;  // log2(BN*8)
    __shared__ __align__(16) char lds[DEP * BUF];

    // XCD-chunked swizzle: real XCD = blockIdx.x % 8 (gridDim.x % 8 == 0).
    const unsigned nx = gridDim.x, ox = blockIdx.x;
    const unsigned qq = nx >> 3, xcd = ox & 7, k0 = ox >> 3;
    const unsigned bx = xcd * qq + k0;
    const int co_blk = blockIdx.y * BN;

    const int tid = threadIdx.x, w = tid >> 6, lane = tid & 63;
    const int l15 = lane & 15, lhi = lane >> 4;
    const int wpx = (w % WSX) * (BM / WSX);
    const int cw0 = (w / WSX) * (BN / WSY);
    const int yb = (int)(bx & (unsigned)(H - 1));      // BM == W: block = row yb
    const unsigned pxc0 = bx * ACHUNK;

    // per-buffer zero slots (drained by phase-0's lgkmcnt(0))
    if (tid < 4 * DEP) *(unsigned*)(lds + (tid >> 2) * BUF + ZS + (tid & 3) * 4) = 0u;

    // act fragment LDS offsets per dx (relative to act slot base)
    int aA[3][MF];
#pragma unroll
    for (int dxi = 0; dxi < 3; ++dxi) {
        const int dx = dxi - 1;
#pragma unroll
        for (int mf = 0; mf < MF; ++mf) {
            int pr = wpx + mf * 16 + l15 + dx;
            bool ok = (TAPS == 1) ? true : (pr >= 0 && pr < BM);
            aA[dxi][mf] = ok ? (((pr >> 4) << 10) + (lhi << 8) + ((pr & 15) << 4)) : ZS;
        }
    }
    int wA[NF];
#pragma unroll
    for (int nf = 0; nf < NF; ++nf)
        wA[nf] = (lhi * BN + cw0 + nf * 16 + l15) * 16;  // within a wt tile

    f32x4 acc[NF][MF];
#pragma unroll
    for (int nf = 0; nf < NF; ++nf)
#pragma unroll
        for (int mf = 0; mf < MF; ++mf)
            acc[nf][mf] = (f32x4){0.f, 0.f, 0.f, 0.f};

    auto stage = [&](int p, int bsel) {
        char* lb = lds + bsel * BUF;
        if constexpr (TAPS == 9) {
            const int dyi = p / KCT, kc = p - dyi * KCT;
            const int dy = dyi - 1;
            const bool isA = (kc < KCA);
            const int kcs = isA ? kc : kc - KCA;
            const int CI  = isA ? CIA : CIB;
            const unsigned offS = isA ? offA : offB;
            const bool rowv = (yb + dy >= 0) && (yb + dy < H);
#pragma unroll
            for (int i = 0; i < A4; ++i) {
                int u = (i * 4 + w) % ACHUNK;
                unsigned s = rowv
                    ? offS + (unsigned)((int)pxc0 + dy * ACHUNK + u) * (unsigned)(CI * 16)
                           + (unsigned)(kcs * 512) + (unsigned)(lane * 8)
                    : E_ZP + (unsigned)(lane * 8);
                glds16(ws0 + s, lb + u * 1024);
            }
#pragma unroll
            for (int i = 0; i < W4; ++i) {
                int t3 = (i * 4 + w) % TWU;
                int tl = t3 / WUNIT, uu = t3 - tl * WUNIT;
                unsigned wsrc = offW + (unsigned)((dyi * 3 + tl) * KCT + kc)
                                       * (unsigned)(COT * 32);
                int el  = uu * 512 + lane * 8;
                int q   = el >> LBN3;
                int col = (el & ((1 << LBN3) - 1)) >> 3;
                glds16(ws0 + wsrc + q * (COT * 8) + (co_blk + col) * 8,
                       lb + WOFF + tl * (BN * 64) + uu * 1024);
            }
        } else {
#pragma unroll
            for (int i = 0; i < A4; ++i) {
                int lin = (i * 4 + w) % (ACP * ACHUNK);
                int gc = lin / ACHUNK, u = lin - gc * ACHUNK;
                unsigned s = offA + (unsigned)(pxc0 + u) * (unsigned)(CIA * 16)
                           + (unsigned)((p * G + gc) * 512) + (unsigned)(lane * 8);
                glds16(ws0 + s, lb + gc * (BM * 64) + u * 1024);
            }
#pragma unroll
            for (int i = 0; i < W4; ++i) {
                int t3 = (i * 4 + w) % TWU;
                int tl = t3 / WUNIT, uu = t3 - tl * WUNIT;
                unsigned wsrc = offW + (unsigned)(p * G + tl) * (unsigned)(COT * 32);
                int el  = uu * 512 + lane * 8;
                int q   = el >> LBN3;
                int col = (el & ((1 << LBN3) - 1)) >> 3;
                glds16(ws0 + wsrc + q * (COT * 8) + (co_blk + col) * 8,
                       lb + WOFF + tl * (BN * 64) + uu * 1024);
            }
        }
    };

    auto step = [&](int p, int bsel) {
        const char* lb = lds + bsel * BUF;
        __builtin_amdgcn_s_setprio(1);                  // T5: favor MFMA waves
#pragma unroll
        for (int t = 0; t < NW; ++t) {
            const int dxi = (TAPS == 9) ? t : 1;
            const char* ab = lb + ((TAPS == 9) ? 0 : t * (BM * 64));
            bf16x8 af[MF], wf[NF];
#pragma unroll
            for (int mf = 0; mf < MF; ++mf)
                af[mf] = *reinterpret_cast<const bf16x8*>(ab + aA[dxi][mf]);
#pragma unroll
            for (int nf = 0; nf < NF; ++nf)
                wf[nf] = *reinterpret_cast<const bf16x8*>(
                    lb + WOFF + t * (BN * 64) + wA[nf]);
#pragma unroll
            for (int nf = 0; nf < NF; ++nf)
#pragma unroll
                for (int mf = 0; mf < MF; ++mf)
                    acc[nf][mf] = __builtin_amdgcn_mfma_f32_16x16x32_bf16(
                        wf[nf], af[mf], acc[nf][mf], 0, 0, 0);
        }
        __builtin_amdgcn_s_setprio(0);
    };

    stage(0, 0);
    if constexpr (DEP == 3) { if (1 < NPH) stage(1, 1); }
#pragma unroll
    for (int p = 0; p < NPH; ++p) {
        if (p + DEP - 1 < NPH) stage(p + DEP - 1, (p + DEP - 1) % DEP);
        if constexpr (DEP == 3) {
            if (p == 0) {
                if (p + 2 < NPH)      wait_v<2 * SS, true >();
                else if (p + 1 < NPH) wait_v<SS,     true >();
                else                  wait_v<0,      true >();
            } else {
                if (p + 2 < NPH)      wait_v<2 * SS, false>();
                else if (p + 1 < NPH) wait_v<SS,     false>();
                else                  wait_v<0,      false>();
            }
        } else {
            if (p == 0) { if (p + 1 < NPH) wait_v<SS, true >(); else wait_v<0, true >(); }
            else        { if (p + 1 < NPH) wait_v<SS, false>(); else wait_v<0, false>(); }
        }
        __builtin_amdgcn_s_barrier();
        __builtin_amdgcn_sched_barrier(0);
        step(p, p % DEP);
        __builtin_amdgcn_sched_barrier(0);
        if (p + 1 < NPH) __builtin_amdgcn_s_barrier();
    }

    // ---------------- epilogue ----------------
    if constexpr (EPI == 0) {
        ushort_t* o1 = (ushort_t*)outp;
#pragma unroll
        for (int nf = 0; nf < NF; ++nf) {
            const int cg = co_blk + cw0 + nf * 16 + (lhi << 2);  // first of 4 co
            float sc[4], bi[4];
#pragma unroll
            for (int r = 0; r < 4; r++) {
                int c = min(cg + r, COclamp - 1);
                sc[r] = g[c] * BNS; bi[r] = bia[c];
            }
#pragma unroll
            for (int mf = 0; mf < MF; ++mf) {
                f32x4 a = acc[nf][mf];
                u16x4 ov;
#pragma unroll
                for (int r = 0; r < 4; r++) {
                    float v = fmaf(a[r], sc[r], bi[r]);
                    if (relu) v = fmaxf(v, 0.f);
                    ov[r] = f2b(v);
                }
                int px = (int)bx * BM + wpx + mf * 16 + l15;
                unsigned off = (unsigned)(px >> 4) * (COT * 16)
                             + (unsigned)(cg >> 3) * 128
                             + (unsigned)(px & 15) * 8 + (unsigned)(cg & 7);
                *reinterpret_cast<u16x4*>(o1 + off) = ov;
            }
        }
    } else if constexpr (EPI == 1) {
        float* o1 = (float*)outp;
        const int HW = 1 << LHW;
#pragma unroll
        for (int nf = 0; nf < NF; ++nf) {
            const int cg = co_blk + cw0 + nf * 16 + (lhi << 2);
            float sc[4], bi[4];
#pragma unroll
            for (int r = 0; r < 4; r++) {
                int c = min(cg + r, COclamp - 1);
                sc[r] = g[c] * BNS; bi[r] = bia[c];
            }
#pragma unroll
            for (int mf = 0; mf < MF; ++mf) {
                int px = (int)bx * BM + wpx + mf * 16 + l15;
                int b = px >> LHW, phw = px & (HW - 1);
#pragma unroll
                for (int r = 0; r < 4; r++) {
                    float v = fmaf(acc[nf][mf][r], sc[r], bi[r]);
                    if (relu) v = fmaxf(v, 0.f);
                    o1[((size_t)(b * COT + cg + r)) * HW + phw] = v;
                }
            }
        }
    } else {
        // EPI == 2: fused channel-25 softmax (COT == 32, one block = row)
        __syncthreads();                     // all waves done with staging LDS
        float* sf = (float*)lds;             // [32 co][136 f32]
#pragma unroll
        for (int nf = 0; nf < NF; ++nf) {
            const int cg = cw0 + nf * 16 + (lhi << 2);
#pragma unroll
            for (int mf = 0; mf < MF; ++mf) {
                int pxl = wpx + mf * 16 + l15;
                f32x4 a = acc[nf][mf];
#pragma unroll
                for (int r = 0; r < 4; r++) {
                    int c = min(cg + r, COclamp - 1);
                    sf[(cg + r) * 136 + pxl] = fmaf(a[r], g[c] * BNS, bia[c]);
                }
            }
        }
        __syncthreads();
        if (tid < BM) {
            int gpx = (int)bx * BM + tid;
            float v[25];
#pragma unroll
            for (int c = 0; c < 25; ++c) v[c] = sf[c * 136 + tid];
            float m = v[0];
#pragma unroll
            for (int c = 1; c < 25; ++c) m = fmaxf(m, v[c]);
            float s = 0.f;
#pragma unroll
            for (int c = 0; c < 25; ++c) { v[c] = __expf(v[c] - m); s += v[c]; }
            float inv = 1.f / s;
            ushort_t* o1 = (ushort_t*)outp;
            unsigned base = (unsigned)(gpx >> 4) * (32 * 16) + (unsigned)(gpx & 15) * 8;
#pragma unroll
            for (int q = 0; q < 3; ++q) {
                u16x8 ov;
#pragma unroll
                for (int k = 0; k < 8; k++) ov[k] = f2b(v[q * 8 + k] * inv);
                *reinterpret_cast<u16x8*>(o1 + base + q * 128) = ov;
            }
            o1[base + 384] = f2b(v[24] * inv);
        }
    }
}

// ============================================================================
// 2x bilinear resize (align-corners linspace), T16 bf16, C=64, 64x64 -> 128x128
// ============================================================================
__global__ __launch_bounds__(256)
void resize2x_t16(const ushort_t* __restrict__ in, ushort_t* __restrict__ out)
{
    int t = blockIdx.x * 256 + threadIdx.x;
    int cg = t & 7;
    int opx = t >> 3;
    int xo = opx & 127;
    int rest = opx >> 7;
    int yo = rest & 127;
    int b  = rest >> 7;
    float fy = (float)yo * 63.f / 127.f;
    float fx = (float)xo * 63.f / 127.f;
    int y0 = (int)fy, x0 = (int)fx;
    float wy = fy - (float)y0, wx = fx - (float)x0;
    int y1 = min(y0 + 1, 63), x1 = min(x0 + 1, 63);
    int qb = b * 4096;
#define RD(Y, X) (*reinterpret_cast<const bf16x8*>(in + \
    (unsigned)(((qb + (Y) * 64 + (X)) >> 4) * 1024) + cg * 128 + ((qb + (Y) * 64 + (X)) & 15) * 8))
    bf16x8 v00 = RD(y0, x0), v01 = RD(y0, x1), v10 = RD(y1, x0), v11 = RD(y1, x1);
#undef RD
    u16x8 o;
#pragma unroll
    for (int k = 0; k < 8; k++) {
        float l = b2f((ushort_t)v00[k]) * (1.f - wy) + b2f((ushort_t)v10[k]) * wy;
        float r = b2f((ushort_t)v01[k]) * (1.f - wy) + b2f((ushort_t)v11[k]) * wy;
        o[k] = f2b(l * (1.f - wx) + r * wx);
    }
    *reinterpret_cast<u16x8*>(out + (unsigned)(opx >> 4) * 1024 + cg * 128 + (opx & 15) * 8) = o;
}

// ============================================================================
// CARAFE combine (T16 bf16, C=64, H=W=128)
// ============================================================================
__global__ __launch_bounds__(256)
void carafe25(const ushort_t* __restrict__ wm, const ushort_t* __restrict__ xu,
              ushort_t* __restrict__ out)
{
    int t = blockIdx.x * 256 + threadIdx.x;
    int cg = t & 7;
    int px = t >> 3;
    int x = px & 127;
    int y = (px >> 7) & 127;
    const ushort_t* wp = wm + (unsigned)(px >> 4) * 512 + (px & 15) * 8;
    u16x8 r0 = *reinterpret_cast<const u16x8*>(wp);
    u16x8 r1 = *reinterpret_cast<const u16x8*>(wp + 128);
    u16x8 r2 = *reinterpret_cast<const u16x8*>(wp + 256);
    float v[25];
#pragma unroll
    for (int k = 0; k < 8; k++) v[k]      = b2f(r0[k]);
#pragma unroll
    for (int k = 0; k < 8; k++) v[8 + k]  = b2f(r1[k]);
#pragma unroll
    for (int k = 0; k < 8; k++) v[16 + k] = b2f(r2[k]);
    v[24] = b2f(wp[384]);

    float acc[8];
#pragma unroll
    for (int k = 0; k < 8; k++) acc[k] = 0.f;
#pragma unroll
    for (int i = 0; i < 5; i++) {
        int yy = y + 2 * i - 4;
#pragma unroll
        for (int j = 0; j < 5; j++) {
            int xx = x + 2 * j - 4;
            if (yy >= 0 && yy < 128 && xx >= 0 && xx < 128) {
                int q = px + (2 * i - 4) * 128 + (2 * j - 4);
                bf16x8 xv = *reinterpret_cast<const bf16x8*>(
                    xu + (unsigned)(q >> 4) * 1024 + cg * 128 + (q & 15) * 8);
                float wv = v[i * 5 + j];
#pragma unroll
                for (int k = 0; k < 8; k++)
                    acc[k] = fmaf(wv, b2f((ushort_t)xv[k]), acc[k]);
            }
        }
    }
    u16x8 o;
#pragma unroll
    for (int k = 0; k < 8; k++) o[k] = f2b(acc[k]);
    *reinterpret_cast<u16x8*>(out + (unsigned)(px >> 4) * 1024 + cg * 128 + (px & 15) * 8) = o;
}

// ============================================================================
extern "C" void kernel_launch(void* const* d_in, const int* in_sizes, int n_in,
                              void* d_out, int out_size, void* d_ws, size_t ws_size,
                              hipStream_t stream)
{
    const float* x_h      = (const float*)d_in[0];
    const float* x_l      = (const float*)d_in[1];
    const float* w_reduce = (const float*)d_in[2];
    const float* g_reduce = (const float*)d_in[3];
    const float* b_reduce = (const float*)d_in[4];
    const float* w1       = (const float*)d_in[5];
    const float* g1       = (const float*)d_in[6];
    const float* b1       = (const float*)d_in[7];
    const float* w2       = (const float*)d_in[8];
    const float* g2       = (const float*)d_in[9];
    const float* b2       = (const float*)d_in[10];
    const float* w_enc    = (const float*)d_in[11];
    const float* g_enc    = (const float*)d_in[12];
    const float* b_enc    = (const float*)d_in[13];
    const float* w_out1   = (const float*)d_in[14];
    const float* g_out1   = (const float*)d_in[15];
    const float* b_out1   = (const float*)d_in[16];
    const float* w_out2   = (const float*)d_in[17];
    const float* g_out2   = (const float*)d_in[18];
    const float* b_out2   = (const float*)d_in[19];

    ushort_t* ws0 = (ushort_t*)d_ws;

    const unsigned oXHC = OFF_R1;   // (16384, 256) T16
    const unsigned oC1  = OFF_R2;   // (16384, 64)
    const unsigned oXR  = OFF_R3;   // (16384, 64)
    const unsigned oX1  = OFF_R4;   // (65536, 64)
    const unsigned oXLC = OFF_R5;   // (65536, 128)
    const unsigned oX2  = OFF_R1;   // (65536, 64)   xh_c dead
    const unsigned oWM  = OFF_R6;   // (65536, 32)
    const unsigned oXU  = OFF_R4;   // (65536, 64)   x1 dead
    const unsigned oXB  = OFF_R1;   // (65536, 64)   x2 dead
    const unsigned oY1  = OFF_R4;   // (65536, 128)  R4+R2+R3+R6 contiguous

    // 0) weights + zero page + both activation conversions, ONE dispatch
    prep_all<<<2192, 256, 0, stream>>>(w_reduce, w1, w2, w_enc, w_out1, w_out2,
                                       x_h, x_l, ws0);
    // 1) c1 = cbr1x1(xh_c, w1): M=16384 K=256 CO=64, DEP=3
    conv_lds<1, 64, 256, 0, 64, 64, 2, 2, 3, 0><<<dim3(256, 1), 256, 0, stream>>>(
        ws0, oXHC, 0u, E_BW1, g1, b1, 64, ws0 + oC1, 64, 12, 1);
    // 2) xr = cbr3x3(xh_c, w_reduce): M=16384 K=2304 CO=64, DEP=3
    conv_lds<9, 64, 256, 0, 64, 64, 1, 2, 3, 0><<<dim3(256, 1), 256, 0, stream>>>(
        ws0, oXHC, 0u, E_BWR, g_reduce, b_reduce, 64, ws0 + oXR, 64, 12, 1);
    // 3) x1 = resize2x(c1)
    resize2x_t16<<<2048, 256, 0, stream>>>(ws0 + oC1, ws0 + oX1);
    // 4) x2 = cbr1x1(xl_c, w2): M=65536 K=128 CO=64, G=1 DEP=3
    conv_lds<1, 128, 128, 0, 64, 64, 1, 2, 3, 0><<<dim3(512, 1), 256, 0, stream>>>(
        ws0, oXLC, 0u, E_BW2, g2, b2, 64, ws0 + oX2, 128, 14, 1);
    // 5) wm = conv3x3(concat(x1,x2), w_enc) + fused softmax-25, WSX=4 DEP=3
    conv_lds<9, 128, 64, 64, 32, 32, 1, 4, 3, 2><<<dim3(512, 1), 256, 0, stream>>>(
        ws0, oX1, oX2, E_BWE, g_enc, b_enc, 25, ws0 + oWM, 128, 14, 0);
    // 6) xu = resize2x(xr)
    resize2x_t16<<<2048, 256, 0, stream>>>(ws0 + oXR, ws0 + oXU);
    // 7) X = carafe(wm, xu)
    carafe25<<<2048, 256, 0, stream>>>(ws0 + oWM, ws0 + oXU, ws0 + oXB);
    // 8) y1 = cbr3x3(concat(X, xl_c), w_out1): CO=128, full-CO, DEP=2
    conv_lds<9, 128, 64, 128, 128, 128, 1, 2, 2, 0><<<dim3(512, 1), 256, 0, stream>>>(
        ws0, oXB, oXLC, E_BWO1, g_out1, b_out1, 128, ws0 + oY1, 128, 14, 1);
    // 9) out = cbr1x1(y1, w_out2) -> d_out NCHW f32, full-CO, DEP=2
    conv_lds<1, 128, 128, 0, 128, 128, 2, 2, 2, 1><<<dim3(512, 1), 256, 0, stream>>>(
        ws0, oY1, 0u, E_BWO2, g_out2, b_out2, 128, d_out, 128, 14, 1);
}

// Round 11
// 133.910 us; speedup vs baseline: 1.5751x; 1.0124x over previous
//
#include <hip/hip_runtime.h>
#include <math.h>

#define BNS 0.99999500003749981f  // 1/sqrt(1+1e-5)

typedef short          bf16x8  __attribute__((ext_vector_type(8)));
typedef float          f32x4   __attribute__((ext_vector_type(4)));
typedef unsigned short u16x8   __attribute__((ext_vector_type(8)));
typedef unsigned short u16x4   __attribute__((ext_vector_type(4)));
typedef unsigned short ushort_t;

__device__ inline ushort_t f2b(float f) {
    union { float f; unsigned int u; } x; x.f = f;
    unsigned int u = x.u;
    unsigned int r = (u + 0x7FFFu + ((u >> 16) & 1u)) >> 16;   // RNE
    return (ushort_t)r;
}
__device__ inline float b2f(ushort_t s) {
    union { unsigned int u; float f; } x; x.u = ((unsigned int)s) << 16;
    return x.f;
}

// async global->LDS, 16B per lane; LDS dest is wave-uniform base (+lane*16 by HW)
__device__ inline void glds16(const ushort_t* gp, void* lp) {
    __builtin_amdgcn_global_load_lds(
        (const __attribute__((address_space(1))) unsigned int*)gp,
        (__attribute__((address_space(3))) unsigned int*)lp, 16, 0, 0);
}

// counted waitcnt (T4): wait until <=N vmem outstanding; optional lgkm drain
template<int N, bool LG0>
__device__ __forceinline__ void wait_v() {
    if constexpr (LG0) {
        if constexpr (N == 0)  asm volatile("s_waitcnt vmcnt(0) lgkmcnt(0)" ::: "memory");
        if constexpr (N == 2)  asm volatile("s_waitcnt vmcnt(2) lgkmcnt(0)" ::: "memory");
        if constexpr (N == 3)  asm volatile("s_waitcnt vmcnt(3) lgkmcnt(0)" ::: "memory");
        if constexpr (N == 4)  asm volatile("s_waitcnt vmcnt(4) lgkmcnt(0)" ::: "memory");
        if constexpr (N == 5)  asm volatile("s_waitcnt vmcnt(5) lgkmcnt(0)" ::: "memory");
        if constexpr (N == 6)  asm volatile("s_waitcnt vmcnt(6) lgkmcnt(0)" ::: "memory");
        if constexpr (N == 8)  asm volatile("s_waitcnt vmcnt(8) lgkmcnt(0)" ::: "memory");
        if constexpr (N == 9)  asm volatile("s_waitcnt vmcnt(9) lgkmcnt(0)" ::: "memory");
        if constexpr (N == 10) asm volatile("s_waitcnt vmcnt(10) lgkmcnt(0)" ::: "memory");
        if constexpr (N == 12) asm volatile("s_waitcnt vmcnt(12) lgkmcnt(0)" ::: "memory");
        if constexpr (N == 16) asm volatile("s_waitcnt vmcnt(16) lgkmcnt(0)" ::: "memory");
    } else {
        if constexpr (N == 0)  asm volatile("s_waitcnt vmcnt(0)" ::: "memory");
        if constexpr (N == 2)  asm volatile("s_waitcnt vmcnt(2)" ::: "memory");
        if constexpr (N == 3)  asm volatile("s_waitcnt vmcnt(3)" ::: "memory");
        if constexpr (N == 4)  asm volatile("s_waitcnt vmcnt(4)" ::: "memory");
        if constexpr (N == 5)  asm volatile("s_waitcnt vmcnt(5)" ::: "memory");
        if constexpr (N == 6)  asm volatile("s_waitcnt vmcnt(6)" ::: "memory");
        if constexpr (N == 8)  asm volatile("s_waitcnt vmcnt(8)" ::: "memory");
        if constexpr (N == 9)  asm volatile("s_waitcnt vmcnt(9)" ::: "memory");
        if constexpr (N == 10) asm volatile("s_waitcnt vmcnt(10)" ::: "memory");
        if constexpr (N == 12) asm volatile("s_waitcnt vmcnt(12)" ::: "memory");
        if constexpr (N == 16) asm volatile("s_waitcnt vmcnt(16)" ::: "memory");
    }
}
// runtime->template dispatch; folds to one call per unrolled iteration
#define WAITSW(nn, LG) do { switch (nn) {                       \
    case 0:  wait_v<0,  LG>(); break;                           \
    case 2:  wait_v<2,  LG>(); break;                           \
    case 3:  wait_v<3,  LG>(); break;                           \
    case 4:  wait_v<4,  LG>(); break;                           \
    case 5:  wait_v<5,  LG>(); break;                           \
    case 6:  wait_v<6,  LG>(); break;                           \
    case 8:  wait_v<8,  LG>(); break;                           \
    case 9:  wait_v<9,  LG>(); break;                           \
    case 10: wait_v<10, LG>(); break;                           \
    case 12: wait_v<12, LG>(); break;                           \
    default: wait_v<16, LG>(); break; } } while (0)

// ---------------- workspace element offsets (ushort units) ----------------
#define E_BWR   0u
#define E_BW1   147456u
#define E_BW2   163840u
#define E_BWE   172032u
#define E_BWO1  208896u
#define E_BWO2  430080u
#define E_ZP    446464u      // 64KB zero page (32768 el)
#define OFF_R1  524288u      // 8MB region   (byte 1048576)
#define OFF_R4  4718592u     // 8MB          (byte 9437184)
#define OFF_R2  8912896u     // 2MB          (byte 17825792)
#define OFF_R3  9961472u     // 2MB          (byte 19922944)
#define OFF_R6  11010048u    // 4MB          (byte 22020096)
#define OFF_R5  13107200u    // 16MB         (byte 26214400) end byte 42991616

// T16 activation layout: element (px, ci) of a CI-channel tensor lives at
//   (px>>4)*(CI*16) + (ci>>3)*128 + (px&15)*8 + (ci&7)

// ============================================================================
// prep_all: weight repack (OIHW f32 -> [kt][ci_oct][co][8] bf16) + zero page
//           + both NCHW->T16 activation conversions, one dispatch.
// ============================================================================
__device__ inline void wseg3(int idx, const float* src, ushort_t* dst,
                             int TAPS, int COT, int CIT, int CO_real) {
    int kt  = idx / (COT * 32);
    int r   = idx - kt * (COT * 32);
    int q   = r / (COT * 8);
    int r2  = r - q * (COT * 8);
    int co  = r2 >> 3;
    int e   = r2 & 7;
    int KCT = CIT >> 5;
    int tap = kt / KCT, j = kt - tap * KCT;
    int ci  = j * 32 + q * 8 + e;
    float v = (co < CO_real) ? src[((size_t)co * CIT + ci) * TAPS + tap] : 0.f;
    dst[idx] = f2b(v);
}

__device__ inline void cvt_t16(const float* __restrict__ in,
                               ushort_t* __restrict__ out,
                               int C, int LHW, int px, int npx) {
    if (px >= npx) return;
    int HW = 1 << LHW;
    int b = px >> LHW, phw = px & (HW - 1);
    const float* src = in + (size_t)b * C * HW + phw;
    unsigned base = (unsigned)(px >> 4) * (C * 16) + (unsigned)(px & 15) * 8;
    for (int c0 = 0; c0 < C; c0 += 8) {
        u16x8 o;
#pragma unroll
        for (int j = 0; j < 8; j++) o[j] = f2b(src[(size_t)(c0 + j) * HW]);
        *reinterpret_cast<u16x8*>(out + base + (c0 >> 3) * 128) = o;
    }
}

__global__ __launch_bounds__(256)
void prep_all(const float* wr, const float* w1, const float* w2,
              const float* we, const float* wo1, const float* wo2,
              const float* xh, const float* xl, ushort_t* ws0)
{
    int bx = blockIdx.x;
    int tid = threadIdx.x;
    if (bx < 1872) {
        int idx = bx * 256 + tid;
        const int n0 = 9*64*256;    // reduce   147456
        const int n1 = 64*256;      // w1        16384
        const int n2 = 64*128;      // w2         8192
        const int n3 = 9*32*128;    // enc       36864
        const int n4 = 9*128*192;   // out1     221184
        const int n5 = 128*128;     // out2      16384
        if (idx < n0) { wseg3(idx, wr,  ws0 + E_BWR,  9, 64, 256, 64);  return; } idx -= n0;
        if (idx < n1) { wseg3(idx, w1,  ws0 + E_BW1,  1, 64, 256, 64);  return; } idx -= n1;
        if (idx < n2) { wseg3(idx, w2,  ws0 + E_BW2,  1, 64, 128, 64);  return; } idx -= n2;
        if (idx < n3) { wseg3(idx, we,  ws0 + E_BWE,  9, 32, 128, 25);  return; } idx -= n3;
        if (idx < n4) { wseg3(idx, wo1, ws0 + E_BWO1, 9, 128, 192, 128); return; } idx -= n4;
        if (idx < n5) { wseg3(idx, wo2, ws0 + E_BWO2, 1, 128, 128, 128); return; } idx -= n5;
        if (idx < 32768) ws0[E_ZP + idx] = 0;   // zero page
        return;
    }
    bx -= 1872;
    if (bx < 64) { cvt_t16(xh, ws0 + OFF_R1, 256, 12, bx * 256 + tid, 16384); return; }
    bx -= 64;
    cvt_t16(xl, ws0 + OFF_R5, 128, 14, bx * 256 + tid, 65536);
}

// ============================================================================
// DUAL conv: xr = 3x3(xh_c, w_reduce) AND c1 = 1x1(xh_c, w1) in one kernel.
// dy-major phases (3 dy x 8 kc). dy=0 phases carry a 4th weight tile (w1) and
// a second accumulator. Counted-vmcnt depth-3 pipeline, mixed SS (4 or 5).
// Block = one 64px row x 64co; 4 waves = 2px x 2co split (MF=2, NF=2).
// ============================================================================
__global__ __launch_bounds__(256)
void conv_dual(const ushort_t* __restrict__ ws0,
               unsigned offA, unsigned offWr, unsigned offW1,
               const float* __restrict__ gR, const float* __restrict__ bR,
               const float* __restrict__ g1, const float* __restrict__ b1,
               ushort_t* __restrict__ outR, ushort_t* __restrict__ outC)
{
    constexpr int BM = 64, BN = 64, KCT = 8, DEP = 3, NPH = 24;
    constexpr int MF = 2, NF = 2;
    constexpr int WOFF = BM * 64;              // 4096 B act region
    constexpr int ZS   = WOFF + 4 * BN * 64;   // 4 wt tiles (16KB)
    constexpr int BUF  = ZS + 16;
    __shared__ __align__(16) char lds[DEP * BUF];

    const unsigned nx = gridDim.x, ox = blockIdx.x;
    const unsigned qq = nx >> 3, xcd = ox & 7, k0 = ox >> 3;
    const unsigned bx = xcd * qq + k0;

    const int tid = threadIdx.x, w = tid >> 6, lane = tid & 63;
    const int l15 = lane & 15, lhi = lane >> 4;
    const int wpx = (w & 1) * 32, cw0 = (w >> 1) * 32;
    const int yb = (int)(bx & 63u);            // block = image row yb
    const unsigned pxc0 = bx * 4;              // 1KB act chunks

    if (tid < 4 * DEP) *(unsigned*)(lds + (tid >> 2) * BUF + ZS + (tid & 3) * 4) = 0u;

    int aA[3][MF];
#pragma unroll
    for (int dxi = 0; dxi < 3; ++dxi)
#pragma unroll
        for (int mf = 0; mf < MF; ++mf) {
            int pr = wpx + mf * 16 + l15 + dxi - 1;
            bool ok = (pr >= 0) && (pr < BM);
            aA[dxi][mf] = ok ? (((pr >> 4) << 10) + (lhi << 8) + ((pr & 15) << 4)) : ZS;
        }
    int wA[NF];
#pragma unroll
    for (int nf = 0; nf < NF; ++nf)
        wA[nf] = lhi * 1024 + (cw0 + nf * 16 + l15) * 16;

    f32x4 acc[NF][MF], acc2[NF][MF];
#pragma unroll
    for (int nf = 0; nf < NF; ++nf)
#pragma unroll
        for (int mf = 0; mf < MF; ++mf) {
            acc[nf][mf]  = (f32x4){0.f, 0.f, 0.f, 0.f};
            acc2[nf][mf] = (f32x4){0.f, 0.f, 0.f, 0.f};
        }

    auto stage = [&](int p, int bsel) {
        char* lb = lds + bsel * BUF;
        const int dyi = p >> 3, kc = p & 7;
        const int dy = dyi - 1;
        const bool rowv = (yb + dy >= 0) && (yb + dy < 64);
        // act: 1 load/wave (4 x 1KB chunks)
        unsigned s = rowv
            ? offA + (unsigned)((int)pxc0 + dy * 4 + w) * 4096u
                   + (unsigned)(kc * 512) + (unsigned)(lane * 8)
            : E_ZP + (unsigned)(lane * 8);
        glds16(ws0 + s, lb + w * 1024);
        // 3 reduce dx weight tiles: 12 units over 4 waves x 3 iters
#pragma unroll
        for (int i = 0; i < 3; ++i) {
            int t3 = i * 4 + w;                 // 0..11 exactly once
            int tl = t3 >> 2, uu = t3 & 3;
            unsigned wsrc = offWr + (unsigned)(((dyi * 3 + tl) * KCT + kc) * 2048)
                          + (unsigned)(uu * 512) + (unsigned)(lane * 8);
            glds16(ws0 + wsrc, lb + WOFF + tl * 4096 + uu * 1024);
        }
        if (dyi == 1) {                         // c1 (w1) tile: 1 load/wave
            unsigned wsrc = offW1 + (unsigned)(kc * 2048)
                          + (unsigned)(w * 512) + (unsigned)(lane * 8);
            glds16(ws0 + wsrc, lb + WOFF + 3 * 4096 + w * 1024);
        }
    };

    auto step = [&](int p, int bsel) {
        const char* lb = lds + bsel * BUF;
        const int dyi = p >> 3;
        __builtin_amdgcn_s_setprio(1);
#pragma unroll
        for (int t = 0; t < 3; ++t) {
            bf16x8 af[MF], wf[NF];
#pragma unroll
            for (int mf = 0; mf < MF; ++mf)
                af[mf] = *reinterpret_cast<const bf16x8*>(lb + aA[t][mf]);
#pragma unroll
            for (int nf = 0; nf < NF; ++nf)
                wf[nf] = *reinterpret_cast<const bf16x8*>(lb + WOFF + t * 4096 + wA[nf]);
#pragma unroll
            for (int nf = 0; nf < NF; ++nf)
#pragma unroll
                for (int mf = 0; mf < MF; ++mf)
                    acc[nf][mf] = __builtin_amdgcn_mfma_f32_16x16x32_bf16(
                        wf[nf], af[mf], acc[nf][mf], 0, 0, 0);
        }
        if (dyi == 1) {
            bf16x8 af[MF], wf[NF];
#pragma unroll
            for (int mf = 0; mf < MF; ++mf)
                af[mf] = *reinterpret_cast<const bf16x8*>(lb + aA[1][mf]);
#pragma unroll
            for (int nf = 0; nf < NF; ++nf)
                wf[nf] = *reinterpret_cast<const bf16x8*>(lb + WOFF + 3 * 4096 + wA[nf]);
#pragma unroll
            for (int nf = 0; nf < NF; ++nf)
#pragma unroll
                for (int mf = 0; mf < MF; ++mf)
                    acc2[nf][mf] = __builtin_amdgcn_mfma_f32_16x16x32_bf16(
                        wf[nf], af[mf], acc2[nf][mf], 0, 0, 0);
        }
        __builtin_amdgcn_s_setprio(0);
    };

    stage(0, 0); stage(1, 1);
#pragma unroll
    for (int p = 0; p < NPH; ++p) {
        if (p + 2 < NPH) stage(p + 2, (p + 2) % 3);
        int n1 = (p + 1 < NPH) ? ((((p + 1) >> 3) == 1) ? 5 : 4) : 0;
        int n2 = (p + 2 < NPH) ? ((((p + 2) >> 3) == 1) ? 5 : 4) : 0;
        int nn = n1 + n2;
        if (p == 0) WAITSW(nn, true); else WAITSW(nn, false);
        __builtin_amdgcn_s_barrier();
        __builtin_amdgcn_sched_barrier(0);
        step(p, p % 3);
        __builtin_amdgcn_sched_barrier(0);
        if (p + 1 < NPH) __builtin_amdgcn_s_barrier();
    }

    // epilogue: two T16 bf16 outputs (ldo = 64)
#pragma unroll
    for (int which = 0; which < 2; ++which) {
        const float* gg = which ? g1 : gR;
        const float* bb = which ? b1 : bR;
        ushort_t* oo = which ? outC : outR;
#pragma unroll
        for (int nf = 0; nf < NF; ++nf) {
            const int cg = cw0 + nf * 16 + (lhi << 2);
            float sc[4], bi[4];
#pragma unroll
            for (int r = 0; r < 4; r++) { sc[r] = gg[cg + r] * BNS; bi[r] = bb[cg + r]; }
#pragma unroll
            for (int mf = 0; mf < MF; ++mf) {
                f32x4 a = which ? acc2[nf][mf] : acc[nf][mf];
                u16x4 ov;
#pragma unroll
                for (int r = 0; r < 4; r++)
                    ov[r] = f2b(fmaxf(fmaf(a[r], sc[r], bi[r]), 0.f));
                int px = (int)bx * BM + wpx + mf * 16 + l15;
                unsigned off = (unsigned)(px >> 4) * 1024
                             + (unsigned)(cg >> 3) * 128
                             + (unsigned)(px & 15) * 8 + (unsigned)(cg & 7);
                *reinterpret_cast<u16x4*>(oo + off) = ov;
            }
        }
    }
}

// ============================================================================
// LDS-staged implicit-GEMM conv, counted-vmcnt DEP-buffer pipeline (T4),
// dy-major phases, s_setprio around MFMA (T5), WSX-way px wave split.
// EPI: 0 = T16 bf16, 1 = NCHW f32 direct, 2 = T16 + fused softmax-25,
//      3 = NCHW f32 via LDS exchange -> 512B-coalesced float4 stores.
// ============================================================================
template<int TAPS, int BM, int CIA, int CIB, int COT, int BN, int G,
         int WSX, int DEP, int EPI>
__global__ __launch_bounds__(256)
void conv_lds(const ushort_t* __restrict__ ws0,
              unsigned offA, unsigned offB, unsigned offW,
              const float* __restrict__ g, const float* __restrict__ bia,
              int COclamp, void* __restrict__ outp,
              int H, int LHW, int relu)
{
    constexpr int KCA = CIA / 32, KCB = CIB / 32;
    constexpr int KCT = KCA + KCB;
    constexpr int NW  = (TAPS == 9) ? 3 : G;       // weight tiles per phase
    constexpr int ACP = (TAPS == 9) ? 1 : G;       // act 32ci-chunks per phase
    constexpr int NPH = (TAPS == 9) ? 3 * KCT : KCT / G;
    constexpr int WSY = 4 / WSX;
    constexpr int MF = BM / WSX / 16;              // px frags per wave
    constexpr int NF = BN / WSY / 16;              // co frags per wave
    constexpr int ACHUNK = BM / 16;                // 1KB units per act chunk
    constexpr int A4 = (ACP * ACHUNK + 3) / 4;     // act loads per wave/phase
    constexpr int WUNIT = BN / 16;                 // 1KB units per wt tile
    constexpr int TWU = NW * WUNIT;
    constexpr int W4 = (TWU + 3) / 4;              // wt loads per wave/phase
    constexpr int SS = A4 + W4;                    // uniform loads/wave/phase
    constexpr int WOFF = ACP * BM * 64;            // bytes: act region size
    constexpr int ZS   = WOFF + NW * BN * 64;      // per-buffer zero slot
    constexpr int BUF  = ZS + 16;
    constexpr int LBN3 = (BN == 128) ? 10 : (BN == 64) ? 9 : 8;  // log2(BN*8)
    __shared__ __align__(16) char lds[DEP * BUF];

    // XCD-chunked swizzle: real XCD = blockIdx.x % 8 (gridDim.x % 8 == 0).
    const unsigned nx = gridDim.x, ox = blockIdx.x;
    const unsigned qq = nx >> 3, xcd = ox & 7, k0 = ox >> 3;
    const unsigned bx = xcd * qq + k0;
    const int co_blk = blockIdx.y * BN;

    const int tid = threadIdx.x, w = tid >> 6, lane = tid & 63;
    const int l15 = lane & 15, lhi = lane >> 4;
    const int wpx = (w % WSX) * (BM / WSX);
    const int cw0 = (w / WSX) * (BN / WSY);
    const int yb = (int)(bx & (unsigned)(H - 1));      // BM == W: block = row yb
    const unsigned pxc0 = bx * ACHUNK;

    if (tid < 4 * DEP) *(unsigned*)(lds + (tid >> 2) * BUF + ZS + (tid & 3) * 4) = 0u;

    int aA[3][MF];
#pragma unroll
    for (int dxi = 0; dxi < 3; ++dxi) {
        const int dx = dxi - 1;
#pragma unroll
        for (int mf = 0; mf < MF; ++mf) {
            int pr = wpx + mf * 16 + l15 + dx;
            bool ok = (TAPS == 1) ? true : (pr >= 0 && pr < BM);
            aA[dxi][mf] = ok ? (((pr >> 4) << 10) + (lhi << 8) + ((pr & 15) << 4)) : ZS;
        }
    }
    int wA[NF];
#pragma unroll
    for (int nf = 0; nf < NF; ++nf)
        wA[nf] = (lhi * BN + cw0 + nf * 16 + l15) * 16;  // within a wt tile

    f32x4 acc[NF][MF];
#pragma unroll
    for (int nf = 0; nf < NF; ++nf)
#pragma unroll
        for (int mf = 0; mf < MF; ++mf)
            acc[nf][mf] = (f32x4){0.f, 0.f, 0.f, 0.f};

    auto stage = [&](int p, int bsel) {
        char* lb = lds + bsel * BUF;
        if constexpr (TAPS == 9) {
            const int dyi = p / KCT, kc = p - dyi * KCT;
            const int dy = dyi - 1;
            const bool isA = (kc < KCA);
            const int kcs = isA ? kc : kc - KCA;
            const int CI  = isA ? CIA : CIB;
            const unsigned offS = isA ? offA : offB;
            const bool rowv = (yb + dy >= 0) && (yb + dy < H);
#pragma unroll
            for (int i = 0; i < A4; ++i) {
                int u = (i * 4 + w) % ACHUNK;
                unsigned s = rowv
                    ? offS + (unsigned)((int)pxc0 + dy * ACHUNK + u) * (unsigned)(CI * 16)
                           + (unsigned)(kcs * 512) + (unsigned)(lane * 8)
                    : E_ZP + (unsigned)(lane * 8);
                glds16(ws0 + s, lb + u * 1024);
            }
#pragma unroll
            for (int i = 0; i < W4; ++i) {
                int t3 = (i * 4 + w) % TWU;
                int tl = t3 / WUNIT, uu = t3 - tl * WUNIT;
                unsigned wsrc = offW + (unsigned)((dyi * 3 + tl) * KCT + kc)
                                       * (unsigned)(COT * 32);
                int el  = uu * 512 + lane * 8;
                int q   = el >> LBN3;
                int col = (el & ((1 << LBN3) - 1)) >> 3;
                glds16(ws0 + wsrc + q * (COT * 8) + (co_blk + col) * 8,
                       lb + WOFF + tl * (BN * 64) + uu * 1024);
            }
        } else {
#pragma unroll
            for (int i = 0; i < A4; ++i) {
                int lin = (i * 4 + w) % (ACP * ACHUNK);
                int gc = lin / ACHUNK, u = lin - gc * ACHUNK;
                unsigned s = offA + (unsigned)(pxc0 + u) * (unsigned)(CIA * 16)
                           + (unsigned)((p * G + gc) * 512) + (unsigned)(lane * 8);
                glds16(ws0 + s, lb + gc * (BM * 64) + u * 1024);
            }
#pragma unroll
            for (int i = 0; i < W4; ++i) {
                int t3 = (i * 4 + w) % TWU;
                int tl = t3 / WUNIT, uu = t3 - tl * WUNIT;
                unsigned wsrc = offW + (unsigned)(p * G + tl) * (unsigned)(COT * 32);
                int el  = uu * 512 + lane * 8;
                int q   = el >> LBN3;
                int col = (el & ((1 << LBN3) - 1)) >> 3;
                glds16(ws0 + wsrc + q * (COT * 8) + (co_blk + col) * 8,
                       lb + WOFF + tl * (BN * 64) + uu * 1024);
            }
        }
    };

    auto step = [&](int p, int bsel) {
        const char* lb = lds + bsel * BUF;
        __builtin_amdgcn_s_setprio(1);                  // T5: favor MFMA waves
#pragma unroll
        for (int t = 0; t < NW; ++t) {
            const int dxi = (TAPS == 9) ? t : 1;
            const char* ab = lb + ((TAPS == 9) ? 0 : t * (BM * 64));
            bf16x8 af[MF], wf[NF];
#pragma unroll
            for (int mf = 0; mf < MF; ++mf)
                af[mf] = *reinterpret_cast<const bf16x8*>(ab + aA[dxi][mf]);
#pragma unroll
            for (int nf = 0; nf < NF; ++nf)
                wf[nf] = *reinterpret_cast<const bf16x8*>(
                    lb + WOFF + t * (BN * 64) + wA[nf]);
#pragma unroll
            for (int nf = 0; nf < NF; ++nf)
#pragma unroll
                for (int mf = 0; mf < MF; ++mf)
                    acc[nf][mf] = __builtin_amdgcn_mfma_f32_16x16x32_bf16(
                        wf[nf], af[mf], acc[nf][mf], 0, 0, 0);
        }
        __builtin_amdgcn_s_setprio(0);
    };

    stage(0, 0);
    if constexpr (DEP == 3) { if (1 < NPH) stage(1, 1); }
#pragma unroll
    for (int p = 0; p < NPH; ++p) {
        if (p + DEP - 1 < NPH) stage(p + DEP - 1, (p + DEP - 1) % DEP);
        int rem = NPH - 1 - p;
        int nn = (rem >= DEP - 1 ? DEP - 1 : rem) * SS;
        if (p == 0) WAITSW(nn, true); else WAITSW(nn, false);
        __builtin_amdgcn_s_barrier();
        __builtin_amdgcn_sched_barrier(0);
        step(p, p % DEP);
        __builtin_amdgcn_sched_barrier(0);
        if (p + 1 < NPH) __builtin_amdgcn_s_barrier();
    }

    // ---------------- epilogue ----------------
    if constexpr (EPI == 0) {
        ushort_t* o1 = (ushort_t*)outp;
#pragma unroll
        for (int nf = 0; nf < NF; ++nf) {
            const int cg = co_blk + cw0 + nf * 16 + (lhi << 2);  // first of 4 co
            float sc[4], bi[4];
#pragma unroll
            for (int r = 0; r < 4; r++) {
                int c = min(cg + r, COclamp - 1);
                sc[r] = g[c] * BNS; bi[r] = bia[c];
            }
#pragma unroll
            for (int mf = 0; mf < MF; ++mf) {
                f32x4 a = acc[nf][mf];
                u16x4 ov;
#pragma unroll
                for (int r = 0; r < 4; r++) {
                    float v = fmaf(a[r], sc[r], bi[r]);
                    if (relu) v = fmaxf(v, 0.f);
                    ov[r] = f2b(v);
                }
                int px = (int)bx * BM + wpx + mf * 16 + l15;
                unsigned off = (unsigned)(px >> 4) * (COT * 16)
                             + (unsigned)(cg >> 3) * 128
                             + (unsigned)(px & 15) * 8 + (unsigned)(cg & 7);
                *reinterpret_cast<u16x4*>(o1 + off) = ov;
            }
        }
    } else if constexpr (EPI == 1) {
        float* o1 = (float*)outp;
        const int HW = 1 << LHW;
#pragma unroll
        for (int nf = 0; nf < NF; ++nf) {
            const int cg = co_blk + cw0 + nf * 16 + (lhi << 2);
            float sc[4], bi[4];
#pragma unroll
            for (int r = 0; r < 4; r++) {
                int c = min(cg + r, COclamp - 1);
                sc[r] = g[c] * BNS; bi[r] = bia[c];
            }
#pragma unroll
            for (int mf = 0; mf < MF; ++mf) {
                int px = (int)bx * BM + wpx + mf * 16 + l15;
                int b = px >> LHW, phw = px & (HW - 1);
#pragma unroll
                for (int r = 0; r < 4; r++) {
                    float v = fmaf(acc[nf][mf][r], sc[r], bi[r]);
                    if (relu) v = fmaxf(v, 0.f);
                    o1[((size_t)(b * COT + cg + r)) * HW + phw] = v;
                }
            }
        }
    } else if constexpr (EPI == 2) {
        // fused channel-25 softmax (COT == 32, one block = row)
        __syncthreads();                     // all waves done with staging LDS
        float* sf = (float*)lds;             // [32 co][136 f32]
#pragma unroll
        for (int nf = 0; nf < NF; ++nf) {
            const int cg = cw0 + nf * 16 + (lhi << 2);
#pragma unroll
            for (int mf = 0; mf < MF; ++mf) {
                int pxl = wpx + mf * 16 + l15;
                f32x4 a = acc[nf][mf];
#pragma unroll
                for (int r = 0; r < 4; r++) {
                    int c = min(cg + r, COclamp - 1);
                    sf[(cg + r) * 136 + pxl] = fmaf(a[r], g[c] * BNS, bia[c]);
                }
            }
        }
        __syncthreads();
        if (tid < BM) {
            int gpx = (int)bx * BM + tid;
            float v[25];
#pragma unroll
            for (int c = 0; c < 25; ++c) v[c] = sf[c * 136 + tid];
            float m = v[0];
#pragma unroll
            for (int c = 1; c < 25; ++c) m = fmaxf(m, v[c]);
            float s = 0.f;
#pragma unroll
            for (int c = 0; c < 25; ++c) { v[c] = __expf(v[c] - m); s += v[c]; }
            float inv = 1.f / s;
            ushort_t* o1 = (ushort_t*)outp;
            unsigned base = (unsigned)(gpx >> 4) * (32 * 16) + (unsigned)(gpx & 15) * 8;
#pragma unroll
            for (int q = 0; q < 3; ++q) {
                u16x8 ov;
#pragma unroll
                for (int k = 0; k < 8; k++) ov[k] = f2b(v[q * 8 + k] * inv);
                *reinterpret_cast<u16x8*>(o1 + base + q * 128) = ov;
            }
            o1[base + 384] = f2b(v[24] * inv);
        }
    } else {
        // EPI == 3: f32 NCHW via LDS exchange -> float4 stores, 512B segments.
        // Requires BM==128, BN==COT==128, WSX==2.
        float* o1 = (float*)outp;
        float* sf = (float*)lds;                 // [64 co][132 f32] per chunk
        const int phw_base = (int)((bx & 127u) * 128);
        const int bimg = (int)(bx >> 7);
        const int lane32 = tid & 31, cog = tid >> 5;
#pragma unroll
        for (int c = 0; c < 2; ++c) {
            __syncthreads();                     // LDS free / prev chunk done
            if (cw0 == c * 64) {
#pragma unroll
                for (int nf = 0; nf < NF; ++nf) {
                    const int cgl = nf * 16 + (lhi << 2);     // 0..63 local
                    const int cg  = c * 64 + cgl;
                    float sc[4], bi[4];
#pragma unroll
                    for (int r = 0; r < 4; r++) { sc[r] = g[cg + r] * BNS; bi[r] = bia[cg + r]; }
#pragma unroll
                    for (int mf = 0; mf < MF; ++mf) {
                        int pxl = wpx + mf * 16 + l15;
                        f32x4 a = acc[nf][mf];
#pragma unroll
                        for (int r = 0; r < 4; r++) {
                            float v = fmaf(a[r], sc[r], bi[r]);
                            if (relu) v = fmaxf(v, 0.f);
                            sf[(cgl + r) * 132 + pxl] = v;
                        }
                    }
                }
            }
            __syncthreads();
#pragma unroll
            for (int j = 0; j < 8; ++j) {
                int col = cog + j * 8;           // 0..63
                f32x4 v = *reinterpret_cast<const f32x4*>(sf + col * 132 + lane32 * 4);
                *reinterpret_cast<f32x4*>(
                    o1 + (((size_t)bimg * 128 + c * 64 + col) << 14)
                       + phw_base + lane32 * 4) = v;
            }
        }
    }
}

// ============================================================================
// 2x bilinear resize (align-corners linspace), T16 bf16, C=64, 64x64 -> 128x128
// ============================================================================
__global__ __launch_bounds__(256)
void resize2x_t16(const ushort_t* __restrict__ in, ushort_t* __restrict__ out)
{
    int t = blockIdx.x * 256 + threadIdx.x;
    int cg = t & 7;
    int opx = t >> 3;
    int xo = opx & 127;
    int rest = opx >> 7;
    int yo = rest & 127;
    int b  = rest >> 7;
    float fy = (float)yo * 63.f / 127.f;
    float fx = (float)xo * 63.f / 127.f;
    int y0 = (int)fy, x0 = (int)fx;
    float wy = fy - (float)y0, wx = fx - (float)x0;
    int y1 = min(y0 + 1, 63), x1 = min(x0 + 1, 63);
    int qb = b * 4096;
#define RD(Y, X) (*reinterpret_cast<const bf16x8*>(in + \
    (unsigned)(((qb + (Y) * 64 + (X)) >> 4) * 1024) + cg * 128 + ((qb + (Y) * 64 + (X)) & 15) * 8))
    bf16x8 v00 = RD(y0, x0), v01 = RD(y0, x1), v10 = RD(y1, x0), v11 = RD(y1, x1);
#undef RD
    u16x8 o;
#pragma unroll
    for (int k = 0; k < 8; k++) {
        float l = b2f((ushort_t)v00[k]) * (1.f - wy) + b2f((ushort_t)v10[k]) * wy;
        float r = b2f((ushort_t)v01[k]) * (1.f - wy) + b2f((ushort_t)v11[k]) * wy;
        o[k] = f2b(l * (1.f - wx) + r * wx);
    }
    *reinterpret_cast<u16x8*>(out + (unsigned)(opx >> 4) * 1024 + cg * 128 + (opx & 15) * 8) = o;
}

// ============================================================================
// CARAFE combine (T16 bf16, C=64, H=W=128)
// ============================================================================
__global__ __launch_bounds__(256)
void carafe25(const ushort_t* __restrict__ wm, const ushort_t* __restrict__ xu,
              ushort_t* __restrict__ out)
{
    int t = blockIdx.x * 256 + threadIdx.x;
    int cg = t & 7;
    int px = t >> 3;
    int x = px & 127;
    int y = (px >> 7) & 127;
    const ushort_t* wp = wm + (unsigned)(px >> 4) * 512 + (px & 15) * 8;
    u16x8 r0 = *reinterpret_cast<const u16x8*>(wp);
    u16x8 r1 = *reinterpret_cast<const u16x8*>(wp + 128);
    u16x8 r2 = *reinterpret_cast<const u16x8*>(wp + 256);
    float v[25];
#pragma unroll
    for (int k = 0; k < 8; k++) v[k]      = b2f(r0[k]);
#pragma unroll
    for (int k = 0; k < 8; k++) v[8 + k]  = b2f(r1[k]);
#pragma unroll
    for (int k = 0; k < 8; k++) v[16 + k] = b2f(r2[k]);
    v[24] = b2f(wp[384]);

    float acc[8];
#pragma unroll
    for (int k = 0; k < 8; k++) acc[k] = 0.f;
#pragma unroll
    for (int i = 0; i < 5; i++) {
        int yy = y + 2 * i - 4;
#pragma unroll
        for (int j = 0; j < 5; j++) {
            int xx = x + 2 * j - 4;
            if (yy >= 0 && yy < 128 && xx >= 0 && xx < 128) {
                int q = px + (2 * i - 4) * 128 + (2 * j - 4);
                bf16x8 xv = *reinterpret_cast<const bf16x8*>(
                    xu + (unsigned)(q >> 4) * 1024 + cg * 128 + (q & 15) * 8);
                float wv = v[i * 5 + j];
#pragma unroll
                for (int k = 0; k < 8; k++)
                    acc[k] = fmaf(wv, b2f((ushort_t)xv[k]), acc[k]);
            }
        }
    }
    u16x8 o;
#pragma unroll
    for (int k = 0; k < 8; k++) o[k] = f2b(acc[k]);
    *reinterpret_cast<u16x8*>(out + (unsigned)(px >> 4) * 1024 + cg * 128 + (px & 15) * 8) = o;
}

// ============================================================================
extern "C" void kernel_launch(void* const* d_in, const int* in_sizes, int n_in,
                              void* d_out, int out_size, void* d_ws, size_t ws_size,
                              hipStream_t stream)
{
    const float* x_h      = (const float*)d_in[0];
    const float* x_l      = (const float*)d_in[1];
    const float* w_reduce = (const float*)d_in[2];
    const float* g_reduce = (const float*)d_in[3];
    const float* b_reduce = (const float*)d_in[4];
    const float* w1       = (const float*)d_in[5];
    const float* g1       = (const float*)d_in[6];
    const float* b1       = (const float*)d_in[7];
    const float* w2       = (const float*)d_in[8];
    const float* g2       = (const float*)d_in[9];
    const float* b2       = (const float*)d_in[10];
    const float* w_enc    = (const float*)d_in[11];
    const float* g_enc    = (const float*)d_in[12];
    const float* b_enc    = (const float*)d_in[13];
    const float* w_out1   = (const float*)d_in[14];
    const float* g_out1   = (const float*)d_in[15];
    const float* b_out1   = (const float*)d_in[16];
    const float* w_out2   = (const float*)d_in[17];
    const float* g_out2   = (const float*)d_in[18];
    const float* b_out2   = (const float*)d_in[19];

    ushort_t* ws0 = (ushort_t*)d_ws;

    const unsigned oXHC = OFF_R1;   // (16384, 256) T16
    const unsigned oC1  = OFF_R2;   // (16384, 64)
    const unsigned oXR  = OFF_R3;   // (16384, 64)
    const unsigned oX1  = OFF_R4;   // (65536, 64)
    const unsigned oXLC = OFF_R5;   // (65536, 128)
    const unsigned oX2  = OFF_R1;   // (65536, 64)   xh_c dead
    const unsigned oWM  = OFF_R6;   // (65536, 32)
    const unsigned oXU  = OFF_R4;   // (65536, 64)   x1 dead
    const unsigned oXB  = OFF_R1;   // (65536, 64)   x2 dead
    const unsigned oY1  = OFF_R4;   // (65536, 128)

    // 0) weights + zero page + both activation conversions, ONE dispatch
    prep_all<<<2192, 256, 0, stream>>>(w_reduce, w1, w2, w_enc, w_out1, w_out2,
                                       x_h, x_l, ws0);
    // 1) DUAL: xr = cbr3x3(xh_c, w_reduce) AND c1 = cbr1x1(xh_c, w1)
    conv_dual<<<256, 256, 0, stream>>>(
        ws0, oXHC, E_BWR, E_BW1, g_reduce, b_reduce, g1, b1,
        ws0 + oXR, ws0 + oC1);
    // 2) x1 = resize2x(c1)
    resize2x_t16<<<2048, 256, 0, stream>>>(ws0 + oC1, ws0 + oX1);
    // 3) x2 = cbr1x1(xl_c, w2): M=65536 K=128 CO=64, G=1 DEP=3
    conv_lds<1, 128, 128, 0, 64, 64, 1, 2, 3, 0><<<dim3(512, 1), 256, 0, stream>>>(
        ws0, oXLC, 0u, E_BW2, g2, b2, 64, ws0 + oX2, 128, 14, 1);
    // 4) wm = conv3x3(concat(x1,x2), w_enc) + fused softmax-25, WSX=4 DEP=3
    conv_lds<9, 128, 64, 64, 32, 32, 1, 4, 3, 2><<<dim3(512, 1), 256, 0, stream>>>(
        ws0, oX1, oX2, E_BWE, g_enc, b_enc, 25, ws0 + oWM, 128, 14, 0);
    // 5) xu = resize2x(xr)
    resize2x_t16<<<2048, 256, 0, stream>>>(ws0 + oXR, ws0 + oXU);
    // 6) X = carafe(wm, xu)
    carafe25<<<2048, 256, 0, stream>>>(ws0 + oWM, ws0 + oXU, ws0 + oXB);
    // 7) y1 = cbr3x3(concat(X, xl_c), w_out1): CO=128, full-CO, DEP=2
    conv_lds<9, 128, 64, 128, 128, 128, 1, 2, 2, 0><<<dim3(512, 1), 256, 0, stream>>>(
        ws0, oXB, oXLC, E_BWO1, g_out1, b_out1, 128, ws0 + oY1, 128, 14, 1);
    // 8) out = cbr1x1(y1, w_out2) -> d_out f32, coalesced LDS-exchange stores
    conv_lds<1, 128, 128, 0, 128, 128, 2, 2, 2, 3><<<dim3(512, 1), 256, 0, stream>>>(
        ws0, oY1, 0u, E_BWO2, g_out2, b_out2, 128, d_out, 128, 14, 1);
}

// Round 12
// 128.671 us; speedup vs baseline: 1.6392x; 1.0407x over previous
//
#include <hip/hip_runtime.h>
#include <math.h>

#define BNS 0.99999500003749981f  // 1/sqrt(1+1e-5)

typedef short          bf16x8  __attribute__((ext_vector_type(8)));
typedef float          f32x4   __attribute__((ext_vector_type(4)));
typedef unsigned short u16x8   __attribute__((ext_vector_type(8)));
typedef unsigned short u16x4   __attribute__((ext_vector_type(4)));
typedef unsigned short ushort_t;

__device__ inline ushort_t f2b(float f) {
    union { float f; unsigned int u; } x; x.f = f;
    unsigned int u = x.u;
    unsigned int r = (u + 0x7FFFu + ((u >> 16) & 1u)) >> 16;   // RNE
    return (ushort_t)r;
}
__device__ inline float b2f(ushort_t s) {
    union { unsigned int u; float f; } x; x.u = ((unsigned int)s) << 16;
    return x.f;
}

// async global->LDS, 16B per lane; LDS dest is wave-uniform base (+lane*16 by HW)
__device__ inline void glds16(const ushort_t* gp, void* lp) {
    __builtin_amdgcn_global_load_lds(
        (const __attribute__((address_space(1))) unsigned int*)gp,
        (__attribute__((address_space(3))) unsigned int*)lp, 16, 0, 0);
}

// counted waitcnt (T4): wait until <=N vmem outstanding; optional lgkm drain
template<int N, bool LG0>
__device__ __forceinline__ void wait_v() {
    if constexpr (LG0) {
        if constexpr (N == 0)  asm volatile("s_waitcnt vmcnt(0) lgkmcnt(0)" ::: "memory");
        if constexpr (N == 2)  asm volatile("s_waitcnt vmcnt(2) lgkmcnt(0)" ::: "memory");
        if constexpr (N == 3)  asm volatile("s_waitcnt vmcnt(3) lgkmcnt(0)" ::: "memory");
        if constexpr (N == 4)  asm volatile("s_waitcnt vmcnt(4) lgkmcnt(0)" ::: "memory");
        if constexpr (N == 5)  asm volatile("s_waitcnt vmcnt(5) lgkmcnt(0)" ::: "memory");
        if constexpr (N == 6)  asm volatile("s_waitcnt vmcnt(6) lgkmcnt(0)" ::: "memory");
        if constexpr (N == 8)  asm volatile("s_waitcnt vmcnt(8) lgkmcnt(0)" ::: "memory");
        if constexpr (N == 9)  asm volatile("s_waitcnt vmcnt(9) lgkmcnt(0)" ::: "memory");
        if constexpr (N == 10) asm volatile("s_waitcnt vmcnt(10) lgkmcnt(0)" ::: "memory");
        if constexpr (N == 12) asm volatile("s_waitcnt vmcnt(12) lgkmcnt(0)" ::: "memory");
        if constexpr (N == 16) asm volatile("s_waitcnt vmcnt(16) lgkmcnt(0)" ::: "memory");
    } else {
        if constexpr (N == 0)  asm volatile("s_waitcnt vmcnt(0)" ::: "memory");
        if constexpr (N == 2)  asm volatile("s_waitcnt vmcnt(2)" ::: "memory");
        if constexpr (N == 3)  asm volatile("s_waitcnt vmcnt(3)" ::: "memory");
        if constexpr (N == 4)  asm volatile("s_waitcnt vmcnt(4)" ::: "memory");
        if constexpr (N == 5)  asm volatile("s_waitcnt vmcnt(5)" ::: "memory");
        if constexpr (N == 6)  asm volatile("s_waitcnt vmcnt(6)" ::: "memory");
        if constexpr (N == 8)  asm volatile("s_waitcnt vmcnt(8)" ::: "memory");
        if constexpr (N == 9)  asm volatile("s_waitcnt vmcnt(9)" ::: "memory");
        if constexpr (N == 10) asm volatile("s_waitcnt vmcnt(10)" ::: "memory");
        if constexpr (N == 12) asm volatile("s_waitcnt vmcnt(12)" ::: "memory");
        if constexpr (N == 16) asm volatile("s_waitcnt vmcnt(16)" ::: "memory");
    }
}
// runtime->template dispatch; folds to one call per unrolled iteration
#define WAITSW(nn, LG) do { switch (nn) {                       \
    case 0:  wait_v<0,  LG>(); break;                           \
    case 2:  wait_v<2,  LG>(); break;                           \
    case 3:  wait_v<3,  LG>(); break;                           \
    case 4:  wait_v<4,  LG>(); break;                           \
    case 5:  wait_v<5,  LG>(); break;                           \
    case 6:  wait_v<6,  LG>(); break;                           \
    case 8:  wait_v<8,  LG>(); break;                           \
    case 9:  wait_v<9,  LG>(); break;                           \
    case 10: wait_v<10, LG>(); break;                           \
    case 12: wait_v<12, LG>(); break;                           \
    default: wait_v<16, LG>(); break; } } while (0)

// ---------------- workspace element offsets (ushort units) ----------------
#define E_BWR   0u
#define E_BW1   147456u
#define E_BW2   163840u
#define E_BWE   172032u
#define E_BWO1  208896u
#define E_BWO2  430080u
#define E_ZP    446464u      // 64KB zero page (32768 el)
#define OFF_R1  524288u      // 8MB region   (byte 1048576)
#define OFF_R4  4718592u     // 8MB          (byte 9437184)
#define OFF_R2  8912896u     // 2MB          (byte 17825792)
#define OFF_R3  9961472u     // 2MB          (byte 19922944)
#define OFF_R6  11010048u    // 4MB          (byte 22020096)
#define OFF_R5  13107200u    // 16MB         (byte 26214400) end byte 42991616

// T16 activation layout: element (px, ci) of a CI-channel tensor lives at
//   (px>>4)*(CI*16) + (ci>>3)*128 + (px&15)*8 + (ci&7)

// ============================================================================
// prep_all: weight repack (OIHW f32 -> [kt][ci_oct][co][8] bf16) + zero page
//           + both NCHW->T16 activation conversions, one dispatch.
// ============================================================================
__device__ inline void wseg3(int idx, const float* src, ushort_t* dst,
                             int TAPS, int COT, int CIT, int CO_real) {
    int kt  = idx / (COT * 32);
    int r   = idx - kt * (COT * 32);
    int q   = r / (COT * 8);
    int r2  = r - q * (COT * 8);
    int co  = r2 >> 3;
    int e   = r2 & 7;
    int KCT = CIT >> 5;
    int tap = kt / KCT, j = kt - tap * KCT;
    int ci  = j * 32 + q * 8 + e;
    float v = (co < CO_real) ? src[((size_t)co * CIT + ci) * TAPS + tap] : 0.f;
    dst[idx] = f2b(v);
}

__device__ inline void cvt_t16(const float* __restrict__ in,
                               ushort_t* __restrict__ out,
                               int C, int LHW, int px, int npx) {
    if (px >= npx) return;
    int HW = 1 << LHW;
    int b = px >> LHW, phw = px & (HW - 1);
    const float* src = in + (size_t)b * C * HW + phw;
    unsigned base = (unsigned)(px >> 4) * (C * 16) + (unsigned)(px & 15) * 8;
    for (int c0 = 0; c0 < C; c0 += 8) {
        u16x8 o;
#pragma unroll
        for (int j = 0; j < 8; j++) o[j] = f2b(src[(size_t)(c0 + j) * HW]);
        *reinterpret_cast<u16x8*>(out + base + (c0 >> 3) * 128) = o;
    }
}

__global__ __launch_bounds__(256)
void prep_all(const float* wr, const float* w1, const float* w2,
              const float* we, const float* wo1, const float* wo2,
              const float* xh, const float* xl, ushort_t* ws0)
{
    int bx = blockIdx.x;
    int tid = threadIdx.x;
    if (bx < 1872) {
        int idx = bx * 256 + tid;
        const int n0 = 9*64*256;    // reduce   147456
        const int n1 = 64*256;      // w1        16384
        const int n2 = 64*128;      // w2         8192
        const int n3 = 9*32*128;    // enc       36864
        const int n4 = 9*128*192;   // out1     221184
        const int n5 = 128*128;     // out2      16384
        if (idx < n0) { wseg3(idx, wr,  ws0 + E_BWR,  9, 64, 256, 64);  return; } idx -= n0;
        if (idx < n1) { wseg3(idx, w1,  ws0 + E_BW1,  1, 64, 256, 64);  return; } idx -= n1;
        if (idx < n2) { wseg3(idx, w2,  ws0 + E_BW2,  1, 64, 128, 64);  return; } idx -= n2;
        if (idx < n3) { wseg3(idx, we,  ws0 + E_BWE,  9, 32, 128, 25);  return; } idx -= n3;
        if (idx < n4) { wseg3(idx, wo1, ws0 + E_BWO1, 9, 128, 192, 128); return; } idx -= n4;
        if (idx < n5) { wseg3(idx, wo2, ws0 + E_BWO2, 1, 128, 128, 128); return; } idx -= n5;
        if (idx < 32768) ws0[E_ZP + idx] = 0;   // zero page
        return;
    }
    bx -= 1872;
    if (bx < 64) { cvt_t16(xh, ws0 + OFF_R1, 256, 12, bx * 256 + tid, 16384); return; }
    bx -= 64;
    cvt_t16(xl, ws0 + OFF_R5, 128, 14, bx * 256 + tid, 65536);
}

// ============================================================================
// DUAL conv: xr = 3x3(xh_c, w_reduce) AND c1 = 1x1(xh_c, w1) in one kernel.
// ============================================================================
__global__ __launch_bounds__(256)
void conv_dual(const ushort_t* __restrict__ ws0,
               unsigned offA, unsigned offWr, unsigned offW1,
               const float* __restrict__ gR, const float* __restrict__ bR,
               const float* __restrict__ g1, const float* __restrict__ b1,
               ushort_t* __restrict__ outR, ushort_t* __restrict__ outC)
{
    constexpr int BM = 64, BN = 64, KCT = 8, DEP = 3, NPH = 24;
    constexpr int MF = 2, NF = 2;
    constexpr int WOFF = BM * 64;              // 4096 B act region
    constexpr int ZS   = WOFF + 4 * BN * 64;   // 4 wt tiles (16KB)
    constexpr int BUF  = ZS + 16;
    __shared__ __align__(16) char lds[DEP * BUF];

    const unsigned nx = gridDim.x, ox = blockIdx.x;
    const unsigned qq = nx >> 3, xcd = ox & 7, k0 = ox >> 3;
    const unsigned bx = xcd * qq + k0;

    const int tid = threadIdx.x, w = tid >> 6, lane = tid & 63;
    const int l15 = lane & 15, lhi = lane >> 4;
    const int wpx = (w & 1) * 32, cw0 = (w >> 1) * 32;
    const int yb = (int)(bx & 63u);            // block = image row yb
    const unsigned pxc0 = bx * 4;              // 1KB act chunks

    if (tid < 4 * DEP) *(unsigned*)(lds + (tid >> 2) * BUF + ZS + (tid & 3) * 4) = 0u;

    int aA[3][MF];
#pragma unroll
    for (int dxi = 0; dxi < 3; ++dxi)
#pragma unroll
        for (int mf = 0; mf < MF; ++mf) {
            int pr = wpx + mf * 16 + l15 + dxi - 1;
            bool ok = (pr >= 0) && (pr < BM);
            aA[dxi][mf] = ok ? (((pr >> 4) << 10) + (lhi << 8) + ((pr & 15) << 4)) : ZS;
        }
    int wA[NF];
#pragma unroll
    for (int nf = 0; nf < NF; ++nf)
        wA[nf] = lhi * 1024 + (cw0 + nf * 16 + l15) * 16;

    f32x4 acc[NF][MF], acc2[NF][MF];
#pragma unroll
    for (int nf = 0; nf < NF; ++nf)
#pragma unroll
        for (int mf = 0; mf < MF; ++mf) {
            acc[nf][mf]  = (f32x4){0.f, 0.f, 0.f, 0.f};
            acc2[nf][mf] = (f32x4){0.f, 0.f, 0.f, 0.f};
        }

    auto stage = [&](int p, int bsel) {
        char* lb = lds + bsel * BUF;
        const int dyi = p >> 3, kc = p & 7;
        const int dy = dyi - 1;
        const bool rowv = (yb + dy >= 0) && (yb + dy < 64);
        unsigned s = rowv
            ? offA + (unsigned)((int)pxc0 + dy * 4 + w) * 4096u
                   + (unsigned)(kc * 512) + (unsigned)(lane * 8)
            : E_ZP + (unsigned)(lane * 8);
        glds16(ws0 + s, lb + w * 1024);
#pragma unroll
        for (int i = 0; i < 3; ++i) {
            int t3 = i * 4 + w;                 // 0..11 exactly once
            int tl = t3 >> 2, uu = t3 & 3;
            unsigned wsrc = offWr + (unsigned)(((dyi * 3 + tl) * KCT + kc) * 2048)
                          + (unsigned)(uu * 512) + (unsigned)(lane * 8);
            glds16(ws0 + wsrc, lb + WOFF + tl * 4096 + uu * 1024);
        }
        if (dyi == 1) {
            unsigned wsrc = offW1 + (unsigned)(kc * 2048)
                          + (unsigned)(w * 512) + (unsigned)(lane * 8);
            glds16(ws0 + wsrc, lb + WOFF + 3 * 4096 + w * 1024);
        }
    };

    auto step = [&](int p, int bsel) {
        const char* lb = lds + bsel * BUF;
        const int dyi = p >> 3;
        __builtin_amdgcn_s_setprio(1);
#pragma unroll
        for (int t = 0; t < 3; ++t) {
            bf16x8 af[MF], wf[NF];
#pragma unroll
            for (int mf = 0; mf < MF; ++mf)
                af[mf] = *reinterpret_cast<const bf16x8*>(lb + aA[t][mf]);
#pragma unroll
            for (int nf = 0; nf < NF; ++nf)
                wf[nf] = *reinterpret_cast<const bf16x8*>(lb + WOFF + t * 4096 + wA[nf]);
#pragma unroll
            for (int nf = 0; nf < NF; ++nf)
#pragma unroll
                for (int mf = 0; mf < MF; ++mf)
                    acc[nf][mf] = __builtin_amdgcn_mfma_f32_16x16x32_bf16(
                        wf[nf], af[mf], acc[nf][mf], 0, 0, 0);
        }
        if (dyi == 1) {
            bf16x8 af[MF], wf[NF];
#pragma unroll
            for (int mf = 0; mf < MF; ++mf)
                af[mf] = *reinterpret_cast<const bf16x8*>(lb + aA[1][mf]);
#pragma unroll
            for (int nf = 0; nf < NF; ++nf)
                wf[nf] = *reinterpret_cast<const bf16x8*>(lb + WOFF + 3 * 4096 + wA[nf]);
#pragma unroll
            for (int nf = 0; nf < NF; ++nf)
#pragma unroll
                for (int mf = 0; mf < MF; ++mf)
                    acc2[nf][mf] = __builtin_amdgcn_mfma_f32_16x16x32_bf16(
                        wf[nf], af[mf], acc2[nf][mf], 0, 0, 0);
        }
        __builtin_amdgcn_s_setprio(0);
    };

    stage(0, 0); stage(1, 1);
#pragma unroll
    for (int p = 0; p < NPH; ++p) {
        if (p + 2 < NPH) stage(p + 2, (p + 2) % 3);
        int n1 = (p + 1 < NPH) ? ((((p + 1) >> 3) == 1) ? 5 : 4) : 0;
        int n2 = (p + 2 < NPH) ? ((((p + 2) >> 3) == 1) ? 5 : 4) : 0;
        int nn = n1 + n2;
        if (p == 0) WAITSW(nn, true); else WAITSW(nn, false);
        __builtin_amdgcn_s_barrier();
        __builtin_amdgcn_sched_barrier(0);
        step(p, p % 3);
        __builtin_amdgcn_sched_barrier(0);
        if (p + 1 < NPH) __builtin_amdgcn_s_barrier();
    }

    // epilogue: two T16 bf16 outputs (ldo = 64)
#pragma unroll
    for (int which = 0; which < 2; ++which) {
        const float* gg = which ? g1 : gR;
        const float* bb = which ? b1 : bR;
        ushort_t* oo = which ? outC : outR;
#pragma unroll
        for (int nf = 0; nf < NF; ++nf) {
            const int cg = cw0 + nf * 16 + (lhi << 2);
            float sc[4], bi[4];
#pragma unroll
            for (int r = 0; r < 4; r++) { sc[r] = gg[cg + r] * BNS; bi[r] = bb[cg + r]; }
#pragma unroll
            for (int mf = 0; mf < MF; ++mf) {
                f32x4 a = which ? acc2[nf][mf] : acc[nf][mf];
                u16x4 ov;
#pragma unroll
                for (int r = 0; r < 4; r++)
                    ov[r] = f2b(fmaxf(fmaf(a[r], sc[r], bi[r]), 0.f));
                int px = (int)bx * BM + wpx + mf * 16 + l15;
                unsigned off = (unsigned)(px >> 4) * 1024
                             + (unsigned)(cg >> 3) * 128
                             + (unsigned)(px & 15) * 8 + (unsigned)(cg & 7);
                *reinterpret_cast<u16x4*>(oo + off) = ov;
            }
        }
    }
}

// ============================================================================
// LDS-staged implicit-GEMM conv, counted-vmcnt DEP-buffer pipeline (T4),
// dy-major phases, s_setprio around MFMA (T5), WSX-way px wave split.
// EPI: 0 = T16 bf16, 1 = NCHW f32 direct, 2 = T16 + fused softmax-25,
//      4 = FUSED second 1x1 GEMM (w2 at offW2, 128ch) + bn2 + relu
//          + f32 NCHW out via LDS-exchange coalesced stores.
// ============================================================================
template<int TAPS, int BM, int CIA, int CIB, int COT, int BN, int G,
         int WSX, int DEP, int EPI>
__global__ __launch_bounds__(256)
void conv_lds(const ushort_t* __restrict__ ws0,
              unsigned offA, unsigned offB, unsigned offW,
              const float* __restrict__ g, const float* __restrict__ bia,
              int COclamp, void* __restrict__ outp,
              int H, int LHW, int relu,
              unsigned offW2, const float* __restrict__ g2,
              const float* __restrict__ bia2)
{
    constexpr int KCA = CIA / 32, KCB = CIB / 32;
    constexpr int KCT = KCA + KCB;
    constexpr int NW  = (TAPS == 9) ? 3 : G;       // weight tiles per phase
    constexpr int ACP = (TAPS == 9) ? 1 : G;       // act 32ci-chunks per phase
    constexpr int NPH = (TAPS == 9) ? 3 * KCT : KCT / G;
    constexpr int WSY = 4 / WSX;
    constexpr int MF = BM / WSX / 16;              // px frags per wave
    constexpr int NF = BN / WSY / 16;              // co frags per wave
    constexpr int ACHUNK = BM / 16;                // 1KB units per act chunk
    constexpr int A4 = (ACP * ACHUNK + 3) / 4;     // act loads per wave/phase
    constexpr int WUNIT = BN / 16;                 // 1KB units per wt tile
    constexpr int TWU = NW * WUNIT;
    constexpr int W4 = (TWU + 3) / 4;              // wt loads per wave/phase
    constexpr int SS = A4 + W4;                    // uniform loads/wave/phase
    constexpr int WOFF = ACP * BM * 64;            // bytes: act region size
    constexpr int ZS   = WOFF + NW * BN * 64;      // per-buffer zero slot
    constexpr int BUF  = ZS + 16;
    constexpr int LBN3 = (BN == 128) ? 10 : (BN == 64) ? 9 : 8;  // log2(BN*8)
    __shared__ __align__(16) char lds[DEP * BUF];

    // XCD-chunked swizzle: real XCD = blockIdx.x % 8 (gridDim.x % 8 == 0).
    const unsigned nx = gridDim.x, ox = blockIdx.x;
    const unsigned qq = nx >> 3, xcd = ox & 7, k0 = ox >> 3;
    const unsigned bx = xcd * qq + k0;
    const int co_blk = blockIdx.y * BN;

    const int tid = threadIdx.x, w = tid >> 6, lane = tid & 63;
    const int l15 = lane & 15, lhi = lane >> 4;
    const int wpx = (w % WSX) * (BM / WSX);
    const int cw0 = (w / WSX) * (BN / WSY);
    const int yb = (int)(bx & (unsigned)(H - 1));      // BM == W: block = row yb
    const unsigned pxc0 = bx * ACHUNK;

    if (tid < 4 * DEP) *(unsigned*)(lds + (tid >> 2) * BUF + ZS + (tid & 3) * 4) = 0u;

    int aA[3][MF];
#pragma unroll
    for (int dxi = 0; dxi < 3; ++dxi) {
        const int dx = dxi - 1;
#pragma unroll
        for (int mf = 0; mf < MF; ++mf) {
            int pr = wpx + mf * 16 + l15 + dx;
            bool ok = (TAPS == 1) ? true : (pr >= 0 && pr < BM);
            aA[dxi][mf] = ok ? (((pr >> 4) << 10) + (lhi << 8) + ((pr & 15) << 4)) : ZS;
        }
    }
    int wA[NF];
#pragma unroll
    for (int nf = 0; nf < NF; ++nf)
        wA[nf] = (lhi * BN + cw0 + nf * 16 + l15) * 16;  // within a wt tile

    f32x4 acc[NF][MF];
#pragma unroll
    for (int nf = 0; nf < NF; ++nf)
#pragma unroll
        for (int mf = 0; mf < MF; ++mf)
            acc[nf][mf] = (f32x4){0.f, 0.f, 0.f, 0.f};

    auto stage = [&](int p, int bsel) {
        char* lb = lds + bsel * BUF;
        if constexpr (TAPS == 9) {
            const int dyi = p / KCT, kc = p - dyi * KCT;
            const int dy = dyi - 1;
            const bool isA = (kc < KCA);
            const int kcs = isA ? kc : kc - KCA;
            const int CI  = isA ? CIA : CIB;
            const unsigned offS = isA ? offA : offB;
            const bool rowv = (yb + dy >= 0) && (yb + dy < H);
#pragma unroll
            for (int i = 0; i < A4; ++i) {
                int u = (i * 4 + w) % ACHUNK;
                unsigned s = rowv
                    ? offS + (unsigned)((int)pxc0 + dy * ACHUNK + u) * (unsigned)(CI * 16)
                           + (unsigned)(kcs * 512) + (unsigned)(lane * 8)
                    : E_ZP + (unsigned)(lane * 8);
                glds16(ws0 + s, lb + u * 1024);
            }
#pragma unroll
            for (int i = 0; i < W4; ++i) {
                int t3 = (i * 4 + w) % TWU;
                int tl = t3 / WUNIT, uu = t3 - tl * WUNIT;
                unsigned wsrc = offW + (unsigned)((dyi * 3 + tl) * KCT + kc)
                                       * (unsigned)(COT * 32);
                int el  = uu * 512 + lane * 8;
                int q   = el >> LBN3;
                int col = (el & ((1 << LBN3) - 1)) >> 3;
                glds16(ws0 + wsrc + q * (COT * 8) + (co_blk + col) * 8,
                       lb + WOFF + tl * (BN * 64) + uu * 1024);
            }
        } else {
#pragma unroll
            for (int i = 0; i < A4; ++i) {
                int lin = (i * 4 + w) % (ACP * ACHUNK);
                int gc = lin / ACHUNK, u = lin - gc * ACHUNK;
                unsigned s = offA + (unsigned)(pxc0 + u) * (unsigned)(CIA * 16)
                           + (unsigned)((p * G + gc) * 512) + (unsigned)(lane * 8);
                glds16(ws0 + s, lb + gc * (BM * 64) + u * 1024);
            }
#pragma unroll
            for (int i = 0; i < W4; ++i) {
                int t3 = (i * 4 + w) % TWU;
                int tl = t3 / WUNIT, uu = t3 - tl * WUNIT;
                unsigned wsrc = offW + (unsigned)(p * G + tl) * (unsigned)(COT * 32);
                int el  = uu * 512 + lane * 8;
                int q   = el >> LBN3;
                int col = (el & ((1 << LBN3) - 1)) >> 3;
                glds16(ws0 + wsrc + q * (COT * 8) + (co_blk + col) * 8,
                       lb + WOFF + tl * (BN * 64) + uu * 1024);
            }
        }
    };

    auto step = [&](int p, int bsel) {
        const char* lb = lds + bsel * BUF;
        __builtin_amdgcn_s_setprio(1);                  // T5: favor MFMA waves
#pragma unroll
        for (int t = 0; t < NW; ++t) {
            const int dxi = (TAPS == 9) ? t : 1;
            const char* ab = lb + ((TAPS == 9) ? 0 : t * (BM * 64));
            bf16x8 af[MF], wf[NF];
#pragma unroll
            for (int mf = 0; mf < MF; ++mf)
                af[mf] = *reinterpret_cast<const bf16x8*>(ab + aA[dxi][mf]);
#pragma unroll
            for (int nf = 0; nf < NF; ++nf)
                wf[nf] = *reinterpret_cast<const bf16x8*>(
                    lb + WOFF + t * (BN * 64) + wA[nf]);
#pragma unroll
            for (int nf = 0; nf < NF; ++nf)
#pragma unroll
                for (int mf = 0; mf < MF; ++mf)
                    acc[nf][mf] = __builtin_amdgcn_mfma_f32_16x16x32_bf16(
                        wf[nf], af[mf], acc[nf][mf], 0, 0, 0);
        }
        __builtin_amdgcn_s_setprio(0);
    };

    stage(0, 0);
    if constexpr (DEP == 3) { if (1 < NPH) stage(1, 1); }
#pragma unroll
    for (int p = 0; p < NPH; ++p) {
        if (p + DEP - 1 < NPH) stage(p + DEP - 1, (p + DEP - 1) % DEP);
        int rem = NPH - 1 - p;
        int nn = (rem >= DEP - 1 ? DEP - 1 : rem) * SS;
        if (p == 0) WAITSW(nn, true); else WAITSW(nn, false);
        __builtin_amdgcn_s_barrier();
        __builtin_amdgcn_sched_barrier(0);
        step(p, p % DEP);
        __builtin_amdgcn_sched_barrier(0);
        if (p + 1 < NPH) __builtin_amdgcn_s_barrier();
    }

    // ---------------- epilogue ----------------
    if constexpr (EPI == 0) {
        ushort_t* o1 = (ushort_t*)outp;
#pragma unroll
        for (int nf = 0; nf < NF; ++nf) {
            const int cg = co_blk + cw0 + nf * 16 + (lhi << 2);  // first of 4 co
            float sc[4], bi[4];
#pragma unroll
            for (int r = 0; r < 4; r++) {
                int c = min(cg + r, COclamp - 1);
                sc[r] = g[c] * BNS; bi[r] = bia[c];
            }
#pragma unroll
            for (int mf = 0; mf < MF; ++mf) {
                f32x4 a = acc[nf][mf];
                u16x4 ov;
#pragma unroll
                for (int r = 0; r < 4; r++) {
                    float v = fmaf(a[r], sc[r], bi[r]);
                    if (relu) v = fmaxf(v, 0.f);
                    ov[r] = f2b(v);
                }
                int px = (int)bx * BM + wpx + mf * 16 + l15;
                unsigned off = (unsigned)(px >> 4) * (COT * 16)
                             + (unsigned)(cg >> 3) * 128
                             + (unsigned)(px & 15) * 8 + (unsigned)(cg & 7);
                *reinterpret_cast<u16x4*>(o1 + off) = ov;
            }
        }
    } else if constexpr (EPI == 1) {
        float* o1 = (float*)outp;
        const int HW = 1 << LHW;
#pragma unroll
        for (int nf = 0; nf < NF; ++nf) {
            const int cg = co_blk + cw0 + nf * 16 + (lhi << 2);
            float sc[4], bi[4];
#pragma unroll
            for (int r = 0; r < 4; r++) {
                int c = min(cg + r, COclamp - 1);
                sc[r] = g[c] * BNS; bi[r] = bia[c];
            }
#pragma unroll
            for (int mf = 0; mf < MF; ++mf) {
                int px = (int)bx * BM + wpx + mf * 16 + l15;
                int b = px >> LHW, phw = px & (HW - 1);
#pragma unroll
                for (int r = 0; r < 4; r++) {
                    float v = fmaf(acc[nf][mf][r], sc[r], bi[r]);
                    if (relu) v = fmaxf(v, 0.f);
                    o1[((size_t)(b * COT + cg + r)) * HW + phw] = v;
                }
            }
        }
    } else if constexpr (EPI == 2) {
        // fused channel-25 softmax (COT == 32, one block = row)
        __syncthreads();                     // all waves done with staging LDS
        float* sf = (float*)lds;             // [32 co][136 f32]
#pragma unroll
        for (int nf = 0; nf < NF; ++nf) {
            const int cg = cw0 + nf * 16 + (lhi << 2);
#pragma unroll
            for (int mf = 0; mf < MF; ++mf) {
                int pxl = wpx + mf * 16 + l15;
                f32x4 a = acc[nf][mf];
#pragma unroll
                for (int r = 0; r < 4; r++) {
                    int c = min(cg + r, COclamp - 1);
                    sf[(cg + r) * 136 + pxl] = fmaf(a[r], g[c] * BNS, bia[c]);
                }
            }
        }
        __syncthreads();
        if (tid < BM) {
            int gpx = (int)bx * BM + tid;
            float v[25];
#pragma unroll
            for (int c = 0; c < 25; ++c) v[c] = sf[c * 136 + tid];
            float m = v[0];
#pragma unroll
            for (int c = 1; c < 25; ++c) m = fmaxf(m, v[c]);
            float s = 0.f;
#pragma unroll
            for (int c = 0; c < 25; ++c) { v[c] = __expf(v[c] - m); s += v[c]; }
            float inv = 1.f / s;
            ushort_t* o1 = (ushort_t*)outp;
            unsigned base = (unsigned)(gpx >> 4) * (32 * 16) + (unsigned)(gpx & 15) * 8;
#pragma unroll
            for (int q = 0; q < 3; ++q) {
                u16x8 ov;
#pragma unroll
                for (int k = 0; k < 8; k++) ov[k] = f2b(v[q * 8 + k] * inv);
                *reinterpret_cast<u16x8*>(o1 + base + q * 128) = ov;
            }
            o1[base + 384] = f2b(v[24] * inv);
        }
    } else {
        // EPI == 4: fused w2 1x1 GEMM + bn2 + relu + coalesced f32 NCHW out.
        // Requires BM==128, BN==COT==128, WSX==2, NPH even (last phase=buf1).
        // y1 bf16 tile (32KB, act-T16 layout) -> lds[0..); w2 -> lds[BUF..).
#pragma unroll
        for (int nf = 0; nf < NF; ++nf) {
            const int cg = cw0 + nf * 16 + (lhi << 2);
            float sc[4], bi[4];
#pragma unroll
            for (int r = 0; r < 4; r++) { sc[r] = g[cg + r] * BNS; bi[r] = bia[cg + r]; }
#pragma unroll
            for (int mf = 0; mf < MF; ++mf) {
                f32x4 a = acc[nf][mf];
                u16x4 ov;
#pragma unroll
                for (int r = 0; r < 4; r++)
                    ov[r] = f2b(fmaxf(fmaf(a[r], sc[r], bi[r]), 0.f));
                int pxl = wpx + mf * 16 + l15;
                unsigned off = (unsigned)(pxl >> 4) * 4096
                             + (unsigned)(cg >> 5) * 1024
                             + (unsigned)((cg >> 3) & 3) * 256
                             + (unsigned)(pxl & 15) * 16 + (unsigned)(cg & 7) * 2;
                *reinterpret_cast<u16x4*>((char*)lds + off) = ov;
            }
        }
        __syncthreads();                 // buf1 reads done everywhere; y1 visible
        // stage w2 (32 x 1KB units, linear prepped layout) into buf1 area
#pragma unroll
        for (int i = 0; i < 8; ++i) {
            int U = i * 4 + w;
            glds16(ws0 + offW2 + (unsigned)U * 512 + (unsigned)(lane * 8),
                   lds + BUF + U * 1024);
        }
        wait_v<0, true>();
        __builtin_amdgcn_s_barrier();
        __builtin_amdgcn_sched_barrier(0);
        f32x4 acc2[NF][MF];
#pragma unroll
        for (int nf = 0; nf < NF; ++nf)
#pragma unroll
            for (int mf = 0; mf < MF; ++mf)
                acc2[nf][mf] = (f32x4){0.f, 0.f, 0.f, 0.f};
        __builtin_amdgcn_s_setprio(1);
#pragma unroll
        for (int kc = 0; kc < 4; ++kc) {
            bf16x8 af[MF], wf[NF];
#pragma unroll
            for (int mf = 0; mf < MF; ++mf) {
                int pxl = wpx + mf * 16 + l15;
                af[mf] = *reinterpret_cast<const bf16x8*>(
                    (char*)lds + (pxl >> 4) * 4096 + kc * 1024
                               + (lhi << 8) + (pxl & 15) * 16);
            }
#pragma unroll
            for (int nf = 0; nf < NF; ++nf)
                wf[nf] = *reinterpret_cast<const bf16x8*>(
                    (char*)lds + BUF + kc * 8192 + wA[nf]);
#pragma unroll
            for (int nf = 0; nf < NF; ++nf)
#pragma unroll
                for (int mf = 0; mf < MF; ++mf)
                    acc2[nf][mf] = __builtin_amdgcn_mfma_f32_16x16x32_bf16(
                        wf[nf], af[mf], acc2[nf][mf], 0, 0, 0);
        }
        __builtin_amdgcn_s_setprio(0);
        __syncthreads();                 // LDS free for the f32 exchange
        float* o1 = (float*)outp;
        float* sf = (float*)lds;         // [64 co][132 f32] per half
        const int phw_base = (int)((bx & 127u) * 128);
        const int bimg = (int)(bx >> 7);
        const int lane32 = tid & 31, cog = tid >> 5;
#pragma unroll
        for (int c = 0; c < 2; ++c) {
            if (c) __syncthreads();
            if (cw0 == c * 64) {
#pragma unroll
                for (int nf = 0; nf < NF; ++nf) {
                    const int cgl = nf * 16 + (lhi << 2);
                    const int cg  = c * 64 + cgl;
                    float sc[4], bi[4];
#pragma unroll
                    for (int r = 0; r < 4; r++) { sc[r] = g2[cg + r] * BNS; bi[r] = bia2[cg + r]; }
#pragma unroll
                    for (int mf = 0; mf < MF; ++mf) {
                        int pxl = wpx + mf * 16 + l15;
                        f32x4 a = acc2[nf][mf];
#pragma unroll
                        for (int r = 0; r < 4; r++)
                            sf[(cgl + r) * 132 + pxl] =
                                fmaxf(fmaf(a[r], sc[r], bi[r]), 0.f);
                    }
                }
            }
            __syncthreads();
#pragma unroll
            for (int j = 0; j < 8; ++j) {
                int col = cog + j * 8;           // 0..63
                f32x4 v = *reinterpret_cast<const f32x4*>(sf + col * 132 + lane32 * 4);
                *reinterpret_cast<f32x4*>(
                    o1 + (((size_t)bimg * 128 + c * 64 + col) << 14)
                       + phw_base + lane32 * 4) = v;
            }
        }
    }
}

// ============================================================================
// 2x bilinear resize (align-corners linspace), T16 bf16, C=64, 64x64 -> 128x128
// ============================================================================
__global__ __launch_bounds__(256)
void resize2x_t16(const ushort_t* __restrict__ in, ushort_t* __restrict__ out)
{
    int t = blockIdx.x * 256 + threadIdx.x;
    int cg = t & 7;
    int opx = t >> 3;
    int xo = opx & 127;
    int rest = opx >> 7;
    int yo = rest & 127;
    int b  = rest >> 7;
    float fy = (float)yo * 63.f / 127.f;
    float fx = (float)xo * 63.f / 127.f;
    int y0 = (int)fy, x0 = (int)fx;
    float wy = fy - (float)y0, wx = fx - (float)x0;
    int y1 = min(y0 + 1, 63), x1 = min(x0 + 1, 63);
    int qb = b * 4096;
#define RD(Y, X) (*reinterpret_cast<const bf16x8*>(in + \
    (unsigned)(((qb + (Y) * 64 + (X)) >> 4) * 1024) + cg * 128 + ((qb + (Y) * 64 + (X)) & 15) * 8))
    bf16x8 v00 = RD(y0, x0), v01 = RD(y0, x1), v10 = RD(y1, x0), v11 = RD(y1, x1);
#undef RD
    u16x8 o;
#pragma unroll
    for (int k = 0; k < 8; k++) {
        float l = b2f((ushort_t)v00[k]) * (1.f - wy) + b2f((ushort_t)v10[k]) * wy;
        float r = b2f((ushort_t)v01[k]) * (1.f - wy) + b2f((ushort_t)v11[k]) * wy;
        o[k] = f2b(l * (1.f - wx) + r * wx);
    }
    *reinterpret_cast<u16x8*>(out + (unsigned)(opx >> 4) * 1024 + cg * 128 + (opx & 15) * 8) = o;
}

// ============================================================================
// CARAFE combine (T16 bf16, C=64, H=W=128)
// ============================================================================
__global__ __launch_bounds__(256)
void carafe25(const ushort_t* __restrict__ wm, const ushort_t* __restrict__ xu,
              ushort_t* __restrict__ out)
{
    int t = blockIdx.x * 256 + threadIdx.x;
    int cg = t & 7;
    int px = t >> 3;
    int x = px & 127;
    int y = (px >> 7) & 127;
    const ushort_t* wp = wm + (unsigned)(px >> 4) * 512 + (px & 15) * 8;
    u16x8 r0 = *reinterpret_cast<const u16x8*>(wp);
    u16x8 r1 = *reinterpret_cast<const u16x8*>(wp + 128);
    u16x8 r2 = *reinterpret_cast<const u16x8*>(wp + 256);
    float v[25];
#pragma unroll
    for (int k = 0; k < 8; k++) v[k]      = b2f(r0[k]);
#pragma unroll
    for (int k = 0; k < 8; k++) v[8 + k]  = b2f(r1[k]);
#pragma unroll
    for (int k = 0; k < 8; k++) v[16 + k] = b2f(r2[k]);
    v[24] = b2f(wp[384]);

    float acc[8];
#pragma unroll
    for (int k = 0; k < 8; k++) acc[k] = 0.f;
#pragma unroll
    for (int i = 0; i < 5; i++) {
        int yy = y + 2 * i - 4;
#pragma unroll
        for (int j = 0; j < 5; j++) {
            int xx = x + 2 * j - 4;
            if (yy >= 0 && yy < 128 && xx >= 0 && xx < 128) {
                int q = px + (2 * i - 4) * 128 + (2 * j - 4);
                bf16x8 xv = *reinterpret_cast<const bf16x8*>(
                    xu + (unsigned)(q >> 4) * 1024 + cg * 128 + (q & 15) * 8);
                float wv = v[i * 5 + j];
#pragma unroll
                for (int k = 0; k < 8; k++)
                    acc[k] = fmaf(wv, b2f((ushort_t)xv[k]), acc[k]);
            }
        }
    }
    u16x8 o;
#pragma unroll
    for (int k = 0; k < 8; k++) o[k] = f2b(acc[k]);
    *reinterpret_cast<u16x8*>(out + (unsigned)(px >> 4) * 1024 + cg * 128 + (px & 15) * 8) = o;
}

// ============================================================================
extern "C" void kernel_launch(void* const* d_in, const int* in_sizes, int n_in,
                              void* d_out, int out_size, void* d_ws, size_t ws_size,
                              hipStream_t stream)
{
    const float* x_h      = (const float*)d_in[0];
    const float* x_l      = (const float*)d_in[1];
    const float* w_reduce = (const float*)d_in[2];
    const float* g_reduce = (const float*)d_in[3];
    const float* b_reduce = (const float*)d_in[4];
    const float* w1       = (const float*)d_in[5];
    const float* g1       = (const float*)d_in[6];
    const float* b1       = (const float*)d_in[7];
    const float* w2       = (const float*)d_in[8];
    const float* g2       = (const float*)d_in[9];
    const float* b2       = (const float*)d_in[10];
    const float* w_enc    = (const float*)d_in[11];
    const float* g_enc    = (const float*)d_in[12];
    const float* b_enc    = (const float*)d_in[13];
    const float* w_out1   = (const float*)d_in[14];
    const float* g_out1   = (const float*)d_in[15];
    const float* b_out1   = (const float*)d_in[16];
    const float* w_out2   = (const float*)d_in[17];
    const float* g_out2   = (const float*)d_in[18];
    const float* b_out2   = (const float*)d_in[19];

    ushort_t* ws0 = (ushort_t*)d_ws;

    const unsigned oXHC = OFF_R1;   // (16384, 256) T16
    const unsigned oC1  = OFF_R2;   // (16384, 64)
    const unsigned oXR  = OFF_R3;   // (16384, 64)
    const unsigned oX1  = OFF_R4;   // (65536, 64)
    const unsigned oXLC = OFF_R5;   // (65536, 128)
    const unsigned oX2  = OFF_R1;   // (65536, 64)   xh_c dead
    const unsigned oWM  = OFF_R6;   // (65536, 32)
    const unsigned oXU  = OFF_R4;   // (65536, 64)   x1 dead
    const unsigned oXB  = OFF_R1;   // (65536, 64)   x2 dead

    // 0) weights + zero page + both activation conversions, ONE dispatch
    prep_all<<<2192, 256, 0, stream>>>(w_reduce, w1, w2, w_enc, w_out1, w_out2,
                                       x_h, x_l, ws0);
    // 1) DUAL: xr = cbr3x3(xh_c, w_reduce) AND c1 = cbr1x1(xh_c, w1)
    conv_dual<<<256, 256, 0, stream>>>(
        ws0, oXHC, E_BWR, E_BW1, g_reduce, b_reduce, g1, b1,
        ws0 + oXR, ws0 + oC1);
    // 2) x1 = resize2x(c1)
    resize2x_t16<<<2048, 256, 0, stream>>>(ws0 + oC1, ws0 + oX1);
    // 3) x2 = cbr1x1(xl_c, w2): M=65536 K=128 CO=64, G=1 DEP=3
    conv_lds<1, 128, 128, 0, 64, 64, 1, 2, 3, 0><<<dim3(512, 1), 256, 0, stream>>>(
        ws0, oXLC, 0u, E_BW2, g2, b2, 64, ws0 + oX2, 128, 14, 1,
        0u, nullptr, nullptr);
    // 4) wm = conv3x3(concat(x1,x2), w_enc) + fused softmax-25, WSX=4 DEP=3
    conv_lds<9, 128, 64, 64, 32, 32, 1, 4, 3, 2><<<dim3(512, 1), 256, 0, stream>>>(
        ws0, oX1, oX2, E_BWE, g_enc, b_enc, 25, ws0 + oWM, 128, 14, 0,
        0u, nullptr, nullptr);
    // 5) xu = resize2x(xr)
    resize2x_t16<<<2048, 256, 0, stream>>>(ws0 + oXR, ws0 + oXU);
    // 6) X = carafe(wm, xu)
    carafe25<<<2048, 256, 0, stream>>>(ws0 + oWM, ws0 + oXU, ws0 + oXB);
    // 7) FUSED: y1 = cbr3x3(concat(X, xl_c), w_out1) -> (in-LDS) ->
    //           out = cbr1x1(y1, w_out2) -> d_out f32 (coalesced)
    conv_lds<9, 128, 64, 128, 128, 128, 1, 2, 2, 4><<<dim3(512, 1), 256, 0, stream>>>(
        ws0, oXB, oXLC, E_BWO1, g_out1, b_out1, 128, d_out, 128, 14, 1,
        E_BWO2, g_out2, b_out2);
}